// Round 3
// baseline (2261.328 us; speedup 1.0000x reference)
//
#include <hip/hip_runtime.h>

typedef unsigned short u16;
#define EPSV 1e-5f

__device__ __forceinline__ float b2f(u16 u) {
  union { float f; unsigned int i; } v; v.i = ((unsigned int)u) << 16; return v.f;
}
__device__ __forceinline__ u16 f2b(float f) {
  union { float f; unsigned int i; } v; v.f = f;
  unsigned int r = v.i + 0x7FFFu + ((v.i >> 16) & 1u);
  return (u16)(r >> 16);
}
__device__ __forceinline__ float silu_(float z) { return z / (1.f + expf(-z)); }

// Detect whether raw input buffers are fp32 (1) or bf16 (0) by probing x's
// first 256 u16s at even indices. bf16 N(0,1): sane exponents, no 0x0000.
// raw fp32: low mantissa halves -> wild exponents. bf16-rounded fp32: zeros.
__device__ int detect_fp32(const u16* __restrict__ xp) {
  int wild = 0, zeros = 0;
  for (int i = 0; i < 256; i += 2) {
    u16 u = xp[i];
    int e = (u >> 7) & 0xff;
    if (e != 0 && (e < 90 || e > 160)) wild++;
    if (u == 0) zeros++;
  }
  return (wild > 16 || zeros > 64) ? 1 : 0;
}

// ---------------- input conversion: everything -> fp32 in workspace ----------------

struct ConvArgs {
  const void* src[30];
  long dst[30];   // float offset into ws
  int end[30];    // inclusive-scan element counts (exclusive ends)
};

__global__ __launch_bounds__(256) void convert_all(ConvArgs a, float* __restrict__ ws,
                                                   const u16* __restrict__ xp, int total) {
  __shared__ int sflag;
  if (threadIdx.x == 0) sflag = detect_fp32(xp);
  __syncthreads();
  const int flag = sflag;
  int gid = blockIdx.x * 256 + threadIdx.x;
  if (gid >= total) return;
  #pragma unroll 1
  for (int s = 0; s < 30; ++s) {
    if (gid < a.end[s]) {
      int idx = gid - (s ? a.end[s - 1] : 0);
      float v = flag ? ((const float*)a.src[s])[idx] : b2f(((const u16*)a.src[s])[idx]);
      ws[a.dst[s] + idx] = v;
      return;
    }
  }
}

// ---------------- CoordAtt ----------------

__global__ __launch_bounds__(256) void plane_means(const float* __restrict__ x, float* __restrict__ yin) {
  __shared__ float pl[4096];
  int bc = blockIdx.x, t = threadIdx.x;
  const float* xp = x + (long)bc * 4096;
  for (int j = 0; j < 16; ++j) { int id = j * 256 + t; pl[id] = xp[id]; }
  __syncthreads();
  if (t < 64) {
    float s = 0.f;
    for (int w = 0; w < 64; ++w) s += pl[t * 64 + w];
    yin[(long)bc * 128 + t] = s * (1.f / 64.f);
  } else if (t < 128) {
    int w = t - 64; float s = 0.f;
    for (int h = 0; h < 64; ++h) s += pl[h * 64 + w];
    yin[(long)bc * 128 + 64 + w] = s * (1.f / 64.f);
  }
}

__global__ __launch_bounds__(128) void ca_conv1(const float* __restrict__ yin, const float* __restrict__ w1,
                                                const float* __restrict__ b1, const float* __restrict__ bnp,
                                                float* __restrict__ ybn) {
  int b = blockIdx.x, p = threadIdx.x;
  float acc[8] = {0.f,0.f,0.f,0.f,0.f,0.f,0.f,0.f};
  for (int c = 0; c < 256; ++c) {
    float yv = yin[((long)b * 256 + c) * 128 + p];
    #pragma unroll
    for (int o = 0; o < 8; ++o) acc[o] += w1[o * 256 + c] * yv;
  }
  #pragma unroll
  for (int o = 0; o < 8; ++o) {
    float z = acc[o] + b1[o];
    float g = bnp[o], bt = bnp[8 + o], mn = bnp[16 + o], vr = bnp[24 + o];
    float s = g * rsqrtf(vr + EPSV);
    z = z * s + (bt - mn * s);
    float hs = fminf(fmaxf(z + 3.f, 0.f), 6.f) * (1.f / 6.f);
    ybn[((long)b * 8 + o) * 128 + p] = z * hs;
  }
}

__global__ __launch_bounds__(128) void ca_gate(const float* __restrict__ ybn,
    const float* __restrict__ wh, const float* __restrict__ bh,
    const float* __restrict__ ww, const float* __restrict__ bw,
    float* __restrict__ ah, float* __restrict__ aw_) {
  int c = blockIdx.x, b = blockIdx.y, t = threadIdx.x;
  if (t < 64) {
    float d = 0.f;
    #pragma unroll
    for (int o = 0; o < 8; ++o) d += wh[c * 8 + o] * ybn[((long)b * 8 + o) * 128 + t];
    d += bh[c];
    ah[((long)b * 256 + c) * 64 + t] = 1.f / (1.f + expf(-d));
  } else {
    int w = t - 64;
    float d = 0.f;
    #pragma unroll
    for (int o = 0; o < 8; ++o) d += ww[c * 8 + o] * ybn[((long)b * 8 + o) * 128 + 64 + w];
    d += bw[c];
    aw_[((long)b * 256 + c) * 64 + w] = 1.f / (1.f + expf(-d));
  }
}

__global__ __launch_bounds__(256) void apply_ca(const float* __restrict__ x, const float* __restrict__ ah,
                                                const float* __restrict__ aw_, float* __restrict__ r) {
  int idx = blockIdx.x * 256 + threadIdx.x;
  int n = idx & 4095, bc = idx >> 12;
  int h = n >> 6, w = n & 63;
  r[idx] = x[idx] * ah[bc * 64 + h] * aw_[bc * 64 + w];
}

// ---------------- generic 1x1 conv (GEMM) + optional BN/bias + optional SiLU ----------------
// out[b,o,n] = act( (sum_k A[o,k]*In[b,k,n]) * alpha_o + beta_o )

template<int ACT>
__global__ __launch_bounds__(256) void gemm_cbs(
    const float* __restrict__ A, long aBS,
    const float* __restrict__ In, long bBS,
    float* __restrict__ Out, long oBS,
    int O, int K, int N,
    const float* __restrict__ bnp, const float* __restrict__ bias)
{
  __shared__ __align__(16) float As[8][128];
  __shared__ __align__(16) float Bs[8][64];
  const int t = threadIdx.x;
  const int n0 = blockIdx.x * 64;
  const int o0 = blockIdx.y * 128;
  const int b  = blockIdx.z;
  const int tx = t & 15, ty = t >> 4;
  const int ao = t >> 1, ak = (t & 1) * 4;
  const int bk = t >> 5, bn_ = (t & 31) * 2;
  float acc[8][4] = {};
  const float* inb = In + (long)b * bBS + n0;
  const float* Ab = A + (long)b * aBS;
  for (int kc = 0; kc < K; kc += 8) {
    __syncthreads();
    float av[4] = {0.f, 0.f, 0.f, 0.f};
    if (o0 + ao < O) {
      float4 u = *(const float4*)(Ab + (long)(o0 + ao) * K + kc + ak);
      av[0] = u.x; av[1] = u.y; av[2] = u.z; av[3] = u.w;
    }
    #pragma unroll
    for (int j = 0; j < 4; ++j) As[ak + j][ao] = av[j];
    float2 bv = *(const float2*)(inb + (long)(kc + bk) * N + bn_);
    Bs[bk][bn_] = bv.x; Bs[bk][bn_ + 1] = bv.y;
    __syncthreads();
    #pragma unroll
    for (int kk = 0; kk < 8; ++kk) {
      float4 a0 = *(const float4*)&As[kk][ty * 8];
      float4 a1 = *(const float4*)&As[kk][ty * 8 + 4];
      float4 bq = *(const float4*)&Bs[kk][tx * 4];
      float aa[8] = {a0.x, a0.y, a0.z, a0.w, a1.x, a1.y, a1.z, a1.w};
      float bb[4] = {bq.x, bq.y, bq.z, bq.w};
      #pragma unroll
      for (int i = 0; i < 8; ++i) {
        #pragma unroll
        for (int j = 0; j < 4; ++j) acc[i][j] += aa[i] * bb[j];
      }
    }
  }
  float* ob = Out + (long)b * oBS + n0 + tx * 4;
  #pragma unroll
  for (int i = 0; i < 8; ++i) {
    int o = o0 + ty * 8 + i;
    if (o < O) {
      float al = 1.f, be = 0.f;
      if (bnp) {
        float g = bnp[o], bt = bnp[O + o], mn = bnp[2 * O + o], vr = bnp[3 * O + o];
        al = g * rsqrtf(vr + EPSV);
        be = bt - mn * al;
      }
      if (bias) be += bias[o];
      float4 rv;
      rv.x = acc[i][0] * al + be;
      rv.y = acc[i][1] * al + be;
      rv.z = acc[i][2] * al + be;
      rv.w = acc[i][3] * al + be;
      if (ACT) { rv.x = silu_(rv.x); rv.y = silu_(rv.y); rv.z = silu_(rv.z); rv.w = silu_(rv.w); }
      *(float4*)(ob + (long)o * N) = rv;
    }
  }
}

// ---------------- 3x3 conv + BN + SiLU (SAME, zero pad) ----------------
__global__ __launch_bounds__(256) void conv3_cbs(
    const float* __restrict__ W, const float* __restrict__ In, long iBS,
    float* __restrict__ Out, long oBS, int O, int I, const float* __restrict__ bnp)
{
  __shared__ float P[66][66];
  const int t = threadIdx.x;
  const int oa = blockIdx.x, obx = blockIdx.x + (O >> 1);
  const int b = blockIdx.y;
  for (int i = t; i < 66 * 66; i += 256) (&P[0][0])[i] = 0.f;
  const int xg = t & 31, yg = t >> 5;
  const int x0 = xg * 2, y0 = yg * 8;
  float accA[8][2] = {}, accB[8][2] = {};
  const float4* inb = (const float4*)(In + (long)b * iBS);
  for (int i = 0; i < I; ++i) {
    __syncthreads();
    #pragma unroll
    for (int j = 0; j < 4; ++j) {
      int id = j * 256 + t;
      float4 v = inb[i * 1024 + id];
      int row = id >> 4, col = (id & 15) * 4;
      P[row + 1][col + 1] = v.x; P[row + 1][col + 2] = v.y;
      P[row + 1][col + 3] = v.z; P[row + 1][col + 4] = v.w;
    }
    __syncthreads();
    float wa[9], wb[9];
    #pragma unroll
    for (int j = 0; j < 9; ++j) {
      wa[j] = W[((long)oa * I + i) * 9 + j];
      wb[j] = W[((long)obx * I + i) * 9 + j];
    }
    float r0[4], r1[4], r2[4];
    #pragma unroll
    for (int d = 0; d < 4; ++d) { r0[d] = P[y0][x0 + d]; r1[d] = P[y0 + 1][x0 + d]; }
    #pragma unroll
    for (int yy = 0; yy < 8; ++yy) {
      #pragma unroll
      for (int d = 0; d < 4; ++d) r2[d] = P[y0 + yy + 2][x0 + d];
      accA[yy][0] += wa[0]*r0[0]+wa[1]*r0[1]+wa[2]*r0[2]+wa[3]*r1[0]+wa[4]*r1[1]+wa[5]*r1[2]+wa[6]*r2[0]+wa[7]*r2[1]+wa[8]*r2[2];
      accA[yy][1] += wa[0]*r0[1]+wa[1]*r0[2]+wa[2]*r0[3]+wa[3]*r1[1]+wa[4]*r1[2]+wa[5]*r1[3]+wa[6]*r2[1]+wa[7]*r2[2]+wa[8]*r2[3];
      accB[yy][0] += wb[0]*r0[0]+wb[1]*r0[1]+wb[2]*r0[2]+wb[3]*r1[0]+wb[4]*r1[1]+wb[5]*r1[2]+wb[6]*r2[0]+wb[7]*r2[1]+wb[8]*r2[2];
      accB[yy][1] += wb[0]*r0[1]+wb[1]*r0[2]+wb[2]*r0[3]+wb[3]*r1[1]+wb[4]*r1[2]+wb[5]*r1[3]+wb[6]*r2[1]+wb[7]*r2[2]+wb[8]*r2[3];
      #pragma unroll
      for (int d = 0; d < 4; ++d) { r0[d] = r1[d]; r1[d] = r2[d]; }
    }
  }
  {
    float g = bnp[oa], bt = bnp[O + oa], mn = bnp[2 * O + oa], vr = bnp[3 * O + oa];
    float al = g * rsqrtf(vr + EPSV), be = bt - mn * al;
    float* ob = Out + (long)b * oBS + (long)oa * 4096;
    #pragma unroll
    for (int yy = 0; yy < 8; ++yy) {
      float2 st = make_float2(silu_(accA[yy][0] * al + be), silu_(accA[yy][1] * al + be));
      *(float2*)(ob + (y0 + yy) * 64 + x0) = st;
    }
  }
  {
    float g = bnp[obx], bt = bnp[O + obx], mn = bnp[2 * O + obx], vr = bnp[3 * O + obx];
    float al = g * rsqrtf(vr + EPSV), be = bt - mn * al;
    float* ob = Out + (long)b * oBS + (long)obx * 4096;
    #pragma unroll
    for (int yy = 0; yy < 8; ++yy) {
      float2 st = make_float2(silu_(accB[yy][0] * al + be), silu_(accB[yy][1] * al + be));
      *(float2*)(ob + (y0 + yy) * 64 + x0) = st;
    }
  }
}

// ---------------- max pools (separable 5-tap, stride 1) ----------------

__global__ __launch_bounds__(256) void hmax5(const float* __restrict__ src, long sBS,
                                             float* __restrict__ dst, long dBS) {
  int t = blockIdx.x * 256 + threadIdx.x;
  int b = blockIdx.y;
  int n = t & 4095, c = t >> 12;
  int w = n & 63;
  const float* p = src + (long)b * sBS + (long)c * 4096 + (n - w);
  float m = p[w];
  if (w >= 1) m = fmaxf(m, p[w - 1]);
  if (w >= 2) m = fmaxf(m, p[w - 2]);
  if (w <= 62) m = fmaxf(m, p[w + 1]);
  if (w <= 61) m = fmaxf(m, p[w + 2]);
  dst[(long)b * dBS + t] = m;
}

__global__ __launch_bounds__(256) void vmax5(const float* __restrict__ src, long sBS,
                                             float* __restrict__ dst, long dBS) {
  int t = blockIdx.x * 256 + threadIdx.x;
  int b = blockIdx.y;
  int n = t & 4095, c = t >> 12;
  int h = n >> 6, w = n & 63;
  const float* p = src + (long)b * sBS + (long)c * 4096 + w;
  float m = p[h * 64];
  if (h >= 1) m = fmaxf(m, p[(h - 1) * 64]);
  if (h >= 2) m = fmaxf(m, p[(h - 2) * 64]);
  if (h <= 62) m = fmaxf(m, p[(h + 1) * 64]);
  if (h <= 61) m = fmaxf(m, p[(h + 2) * 64]);
  dst[(long)b * dBS + t] = m;
}

// ---------------- transpose (B, R, C) -> (B, C, R) ----------------

__global__ __launch_bounds__(256) void transpose_bk(const float* __restrict__ in, float* __restrict__ out,
                                                    int R, int Cc) {
  __shared__ float tile[32][33];
  int b = blockIdx.z;
  int c0 = blockIdx.x * 32, r0 = blockIdx.y * 32;
  int tx = threadIdx.x & 31, ty = threadIdx.x >> 5;
  const float* ib = in + (long)b * R * Cc;
  float* ob = out + (long)b * R * Cc;
  #pragma unroll
  for (int i = 0; i < 4; ++i) {
    int r = r0 + ty + i * 8;
    tile[ty + i * 8][tx] = ib[(long)r * Cc + c0 + tx];
  }
  __syncthreads();
  #pragma unroll
  for (int i = 0; i < 4; ++i) {
    int c = c0 + ty + i * 8;
    ob[(long)c * R + r0 + tx] = tile[tx][ty + i * 8];
  }
}

// ---------------- PAM pass 1: row max / sum-exp of logits ----------------
__global__ __launch_bounds__(256) void pam_stats(const float* __restrict__ qT, const float* __restrict__ kT,
                                                 float* __restrict__ rowmax, float* __restrict__ rowsum) {
  __shared__ __align__(16) float kch[4][64][32];
  __shared__ float cm[4][64], cs[4][64];
  const int t = threadIdx.x;
  const int b = blockIdx.y, n0 = blockIdx.x * 64;
  const int tn = t & 63, ts = t >> 6;
  float4 qv[8];
  const float4* qrow = (const float4*)(qT + ((long)b * 4096 + n0 + tn) * 32);
  #pragma unroll
  for (int j = 0; j < 8; ++j) qv[j] = qrow[j];
  const float4* k4 = (const float4*)(kT + (long)b * 4096 * 32);
  float mx = -1e30f, sm = 0.f;
  for (int it = 0; it < 16; ++it) {
    __syncthreads();
    #pragma unroll
    for (int j = 0; j < 8; ++j) {
      int id = j * 256 + t;
      int seg = id >> 9, rem = id & 511;
      int mrow = rem >> 3, c4 = rem & 7;
      *(float4*)&kch[seg][mrow][c4 * 4] = k4[(seg * 1024 + it * 64 + mrow) * 8 + c4];
    }
    __syncthreads();
    for (int mm = 0; mm < 64; ++mm) {
      const float4* kr = (const float4*)&kch[ts][mm][0];
      float d = 0.f;
      #pragma unroll
      for (int j = 0; j < 8; ++j) {
        float4 kv = kr[j];
        d += qv[j].x * kv.x + qv[j].y * kv.y + qv[j].z * kv.z + qv[j].w * kv.w;
      }
      float nm = fmaxf(mx, d);
      sm = sm * expf(mx - nm) + expf(d - nm);
      mx = nm;
    }
  }
  cm[ts][tn] = mx; cs[ts][tn] = sm;
  __syncthreads();
  if (t < 64) {
    float M = cm[0][t];
    #pragma unroll
    for (int s = 1; s < 4; ++s) M = fmaxf(M, cm[s][t]);
    float S = 0.f;
    #pragma unroll
    for (int s = 0; s < 4; ++s) S += cs[s][t] * expf(cm[s][t] - M);
    rowmax[(long)b * 4096 + n0 + t] = M;
    rowsum[(long)b * 4096 + n0 + t] = S;
  }
}

// ---------------- PAM pass 2: out[n,c] = sum_m softmax(qk)[n,m] * v[m,c] ----------------
__global__ __launch_bounds__(256) void pam_out(const float* __restrict__ qT, const float* __restrict__ kT,
    const float* __restrict__ vT, const float* __restrict__ rowmax, const float* __restrict__ rowsum,
    float* __restrict__ pamT) {
  __shared__ __align__(16) float qs[32][36];
  __shared__ __align__(16) float ks[32][36];
  __shared__ float ps[32][33];
  __shared__ __align__(16) float vs[32][256];
  __shared__ float rm[32], ri[32];
  const int t = threadIdx.x;
  const int b = blockIdx.y, n0 = blockIdx.x * 32;
  {
    int row = t >> 3, c4 = t & 7;
    *(float4*)&qs[row][c4 * 4] = *(const float4*)(qT + ((long)b * 4096 + n0 + row) * 32 + c4 * 4);
    if (t < 32) {
      rm[t] = rowmax[(long)b * 4096 + n0 + t];
      ri[t] = 1.f / rowsum[(long)b * 4096 + n0 + t];
    }
  }
  __syncthreads();
  const int ln = t >> 3, lm = (t & 7) * 4;
  const int ng = t & 15, cg = t >> 4;
  float4 qv[8];
  #pragma unroll
  for (int j = 0; j < 8; ++j) qv[j] = *(const float4*)&qs[ln][j * 4];
  float acc[2][16] = {};
  for (int ch = 0; ch < 128; ++ch) {
    int m0 = ch * 32;
    __syncthreads();
    {
      int row = t >> 3, c4 = t & 7;
      *(float4*)&ks[row][c4 * 4] = *(const float4*)(kT + ((long)b * 4096 + m0 + row) * 32 + c4 * 4);
      #pragma unroll
      for (int j = 0; j < 8; ++j) {
        int id = j * 256 + t;
        int vr = id >> 6, vc = id & 63;
        *(float4*)&vs[vr][vc * 4] = *(const float4*)(vT + ((long)b * 4096 + m0 + vr) * 256 + vc * 4);
      }
    }
    __syncthreads();
    #pragma unroll
    for (int j = 0; j < 4; ++j) {
      const float4* kr = (const float4*)&ks[lm + j][0];
      float d = 0.f;
      #pragma unroll
      for (int w = 0; w < 8; ++w) {
        float4 kv = kr[w];
        d += qv[w].x * kv.x + qv[w].y * kv.y + qv[w].z * kv.z + qv[w].w * kv.w;
      }
      ps[ln][lm + j] = expf(d - rm[ln]) * ri[ln];
    }
    __syncthreads();
    #pragma unroll 4
    for (int mm = 0; mm < 32; ++mm) {
      float p0 = ps[ng * 2][mm], p1 = ps[ng * 2 + 1][mm];
      #pragma unroll
      for (int j = 0; j < 4; ++j) {
        float4 v4 = *(const float4*)&vs[mm][cg * 16 + j * 4];
        acc[0][j*4+0] += p0 * v4.x; acc[0][j*4+1] += p0 * v4.y; acc[0][j*4+2] += p0 * v4.z; acc[0][j*4+3] += p0 * v4.w;
        acc[1][j*4+0] += p1 * v4.x; acc[1][j*4+1] += p1 * v4.y; acc[1][j*4+2] += p1 * v4.z; acc[1][j*4+3] += p1 * v4.w;
      }
    }
  }
  #pragma unroll
  for (int i = 0; i < 2; ++i) {
    float* op = pamT + ((long)b * 4096 + n0 + ng * 2 + i) * 256 + cg * 16;
    #pragma unroll
    for (int j = 0; j < 4; ++j)
      *(float4*)(op + j * 4) = make_float4(acc[i][j*4], acc[i][j*4+1], acc[i][j*4+2], acc[i][j*4+3]);
  }
}

// ---------------- CAM ----------------

__global__ __launch_bounds__(256) void fillz(float* __restrict__ p, int n) {
  int i = blockIdx.x * 256 + threadIdx.x;
  if (i < n) p[i] = 0.f;
}

__global__ __launch_bounds__(256) void cam_e(const float* __restrict__ f, float* __restrict__ e) {
  __shared__ __align__(16) float fc[32][68];
  __shared__ __align__(16) float fd[32][68];
  const int c0 = blockIdx.x * 64, d0 = blockIdx.y * 64;
  const int bz = blockIdx.z;
  const int b = bz >> 3, ns = bz & 7;
  const int t = threadIdx.x;
  const int tx = t & 15, ty = t >> 4;
  float acc[4][4] = {};
  const float* fb = f + (long)b * 1048576;
  for (int nc = 0; nc < 16; ++nc) {
    int nb = ns * 512 + nc * 32;
    __syncthreads();
    #pragma unroll
    for (int i = 0; i < 2; ++i) {
      int id = i * 256 + t;
      int row = id >> 3, c4 = id & 7;
      float4 v = *(const float4*)(fb + (long)(c0 + row) * 4096 + nb + c4 * 4);
      fc[c4*4+0][row] = v.x; fc[c4*4+1][row] = v.y; fc[c4*4+2][row] = v.z; fc[c4*4+3][row] = v.w;
      float4 u = *(const float4*)(fb + (long)(d0 + row) * 4096 + nb + c4 * 4);
      fd[c4*4+0][row] = u.x; fd[c4*4+1][row] = u.y; fd[c4*4+2][row] = u.z; fd[c4*4+3][row] = u.w;
    }
    __syncthreads();
    #pragma unroll
    for (int nn = 0; nn < 32; ++nn) {
      float4 a = *(const float4*)&fc[nn][ty * 4];
      float4 bq = *(const float4*)&fd[nn][tx * 4];
      float aa[4] = {a.x, a.y, a.z, a.w};
      float bb[4] = {bq.x, bq.y, bq.z, bq.w};
      #pragma unroll
      for (int i = 0; i < 4; ++i) {
        #pragma unroll
        for (int j = 0; j < 4; ++j) acc[i][j] += aa[i] * bb[j];
      }
    }
  }
  #pragma unroll
  for (int i = 0; i < 4; ++i)
    #pragma unroll
    for (int j = 0; j < 4; ++j)
      atomicAdd(&e[((long)b << 16) + (long)(c0 + ty * 4 + i) * 256 + d0 + tx * 4 + j], acc[i][j]);
}

__global__ __launch_bounds__(256) void cam_softmax(const float* __restrict__ e, float* __restrict__ attn) {
  __shared__ float red[256];
  int c = blockIdx.x, b = blockIdx.y, t = threadIdx.x;
  const float* row = e + ((long)b << 16) + (long)c * 256;
  float v = row[t];
  red[t] = v; __syncthreads();
  for (int s = 128; s > 0; s >>= 1) { if (t < s) red[t] = fminf(red[t], red[t + s]); __syncthreads(); }
  float emin = red[0]; __syncthreads();
  float ex = expf(emin - v);
  red[t] = ex; __syncthreads();
  for (int s = 128; s > 0; s >>= 1) { if (t < s) red[t] += red[t + s]; __syncthreads(); }
  float inv = 1.f / red[0];
  attn[((long)b << 16) + (long)c * 256 + t] = ex * inv;
}

// ---------------- final combine (dtype-aware output) ----------------

__global__ __launch_bounds__(256) void combine(const float* __restrict__ res, const float* __restrict__ pam,
    const float* __restrict__ cam, const float* __restrict__ gp,
    void* __restrict__ outp, const u16* __restrict__ xp) {
  __shared__ int sflag;
  if (threadIdx.x == 0) sflag = detect_fp32(xp);
  __syncthreads();
  int idx = blockIdx.x * 256 + threadIdx.x;
  float g1 = gp[0], g2 = gp[1];   // gamma_pa, gamma_ca (adjacent in staging)
  float v = 3.f * res[idx] + g1 * pam[idx] + g2 * cam[idx];
  if (sflag) ((float*)outp)[idx] = v;
  else       ((u16*)outp)[idx] = f2b(v);
}

// ---------------- launch ----------------

extern "C" void kernel_launch(void* const* d_in, const int* in_sizes, int n_in,
                              void* d_out, int out_size, void* d_ws, size_t ws_size,
                              hipStream_t stream)
{
  (void)out_size; (void)ws_size;
  float* ws = (float*)d_ws;
  const long CN = 256L * 4096;     // 1,048,576 floats: one batch slice of (C,N)

  // Planes (float offsets). Lifetimes verified per-dispatch:
  float* A  = ws;            // [0,2CN)   r -> res
  float* Bp = ws + 2 * CN;   // [2,4CN)   x_f32 -> s1out -> pool tmp -> s5out -> v
  float* Cp = ws + 4 * CN;   // [4,6CN)   CoordAtt smalls -> s3out -> vT
  float* D  = ws + 6 * CN;   // [6,14CN)  cat(8CN) -> {y12 [0,4CN), attn [4CN,6CN), pamT [6CN,8CN)} -> {pam [0,2CN), cam [2CN,4CN)}
  const long WFo = 14 * CN;  // converted weights staging

  // CoordAtt smalls in Cp (dead before s3 writes Cp):
  float* yin = Cp;
  float* ybn = Cp + 65536;
  float* ah  = Cp + 67584;
  float* aw_ = Cp + 100352;

  // Attention smalls in D + 4CN (cat dead by then):
  float* q     = D + 4 * CN;
  float* k     = q + 262144;
  float* qT    = q + 524288;
  float* kT    = q + 786432;
  float* rmx   = q + 1048576;
  float* rsm   = q + 1056768;
  float* e     = q + 1064960;
  float* attnc = q + 1196032;   // ends at 4CN+1,327,104 < 6CN ✓

  float* res  = A;
  float* v    = Bp;
  float* vT   = Cp;
  float* pamT = D + 6 * CN;
  float* pam  = D;            // after y12 dead (post-s7)
  float* cam  = D + 2 * CN;

  // ---- input conversion (detects bf16 vs fp32 on device) ----
  ConvArgs ca;
  long woff[30];
  {
    long cum = 0, w = WFo;
    for (int i = 0; i < 30; ++i) {
      ca.src[i] = d_in[i];
      if (i == 0) { ca.dst[i] = 2 * CN; }           // x -> Bp
      else        { ca.dst[i] = w; w += in_sizes[i]; }
      woff[i] = ca.dst[i];
      cum += in_sizes[i];
      ca.end[i] = (int)cum;
    }
  }
  int total = ca.end[29];
  convert_all<<<dim3((total + 255) / 256), dim3(256), 0, stream>>>(ca, ws, (const u16*)d_in[0], total);

  float* xf    = Bp;
  float* ca_w1 = ws + woff[1];
  float* ca_b1 = ws + woff[2];
  float* ca_bn = ws + woff[3];
  float* ca_wh = ws + woff[4];
  float* ca_bh = ws + woff[5];
  float* ca_ww = ws + woff[6];
  float* ca_bw = ws + woff[7];
  float* s1_w  = ws + woff[8],  *s1_bn = ws + woff[9];
  float* s2_w  = ws + woff[10], *s2_bn = ws + woff[11];
  float* s3_w  = ws + woff[12], *s3_bn = ws + woff[13];
  float* s4_w  = ws + woff[14], *s4_bn = ws + woff[15];
  float* s5_w  = ws + woff[16], *s5_bn = ws + woff[17];
  float* s6_w  = ws + woff[18], *s6_bn = ws + woff[19];
  float* s7_w  = ws + woff[20], *s7_bn = ws + woff[21];
  float* pq_w  = ws + woff[22], *pq_b  = ws + woff[23];
  float* pk_w  = ws + woff[24], *pk_b  = ws + woff[25];
  float* pv_w  = ws + woff[26], *pv_b  = ws + woff[27];
  float* gammas = ws + woff[28];   // [gamma_pa, gamma_ca] adjacent

  // ---- CoordAtt ----
  plane_means<<<dim3(512), dim3(256), 0, stream>>>(xf, yin);
  ca_conv1<<<dim3(2), dim3(128), 0, stream>>>(yin, ca_w1, ca_b1, ca_bn, ybn);
  ca_gate<<<dim3(256, 2), dim3(128), 0, stream>>>(ybn, ca_wh, ca_bh, ca_ww, ca_bw, ah, aw_);
  apply_ca<<<dim3(8192), dim3(256), 0, stream>>>(xf, ah, aw_, A);

  // ---- SPPCSPC ----
  // cat region D: section s, batch b at D + s*CN + b*4CN (8CN total, in-bounds for b=1 ✓)
  gemm_cbs<1><<<dim3(64, 2, 2), dim3(256), 0, stream>>>(s1_w, 0, A, CN, Bp, CN, 256, 256, 4096, s1_bn, nullptr);
  conv3_cbs<<<dim3(128, 2), dim3(256), 0, stream>>>(s3_w, Bp, CN, Cp, CN, 256, 256, s3_bn);
  gemm_cbs<1><<<dim3(64, 2, 2), dim3(256), 0, stream>>>(s4_w, 0, Cp, CN, D, 4 * CN, 256, 256, 4096, s4_bn, nullptr);

  hmax5<<<dim3(4096, 2), dim3(256), 0, stream>>>(D, 4 * CN, Bp, CN);
  vmax5<<<dim3(4096, 2), dim3(256), 0, stream>>>(Bp, CN, D + CN, 4 * CN);
  hmax5<<<dim3(4096, 2), dim3(256), 0, stream>>>(D + CN, 4 * CN, Bp, CN);
  vmax5<<<dim3(4096, 2), dim3(256), 0, stream>>>(Bp, CN, D + 2 * CN, 4 * CN);
  hmax5<<<dim3(4096, 2), dim3(256), 0, stream>>>(D + 2 * CN, 4 * CN, Bp, CN);
  vmax5<<<dim3(4096, 2), dim3(256), 0, stream>>>(Bp, CN, D + 3 * CN, 4 * CN);

  gemm_cbs<1><<<dim3(64, 2, 2), dim3(256), 0, stream>>>(s5_w, 0, D, 4 * CN, Bp, CN, 256, 1024, 4096, s5_bn, nullptr);
  // y12 region at D (cat dead): y1 rows [0,256), y2 rows [256,512), batch-stride 2CN
  conv3_cbs<<<dim3(128, 2), dim3(256), 0, stream>>>(s6_w, Bp, CN, D, 2 * CN, 256, 256, s6_bn);
  gemm_cbs<1><<<dim3(64, 2, 2), dim3(256), 0, stream>>>(s2_w, 0, A, CN, D + CN, 2 * CN, 256, 256, 4096, s2_bn, nullptr);
  gemm_cbs<1><<<dim3(64, 2, 2), dim3(256), 0, stream>>>(s7_w, 0, D, 2 * CN, A, CN, 256, 512, 4096, s7_bn, nullptr);

  // ---- PAM ----
  gemm_cbs<0><<<dim3(64, 1, 2), dim3(256), 0, stream>>>(pq_w, 0, res, CN, q, 131072, 32, 256, 4096, nullptr, pq_b);
  gemm_cbs<0><<<dim3(64, 1, 2), dim3(256), 0, stream>>>(pk_w, 0, res, CN, k, 131072, 32, 256, 4096, nullptr, pk_b);
  gemm_cbs<0><<<dim3(64, 2, 2), dim3(256), 0, stream>>>(pv_w, 0, res, CN, v, CN, 256, 256, 4096, nullptr, pv_b);

  transpose_bk<<<dim3(128, 1, 2), dim3(256), 0, stream>>>(q, qT, 32, 4096);
  transpose_bk<<<dim3(128, 1, 2), dim3(256), 0, stream>>>(k, kT, 32, 4096);
  transpose_bk<<<dim3(128, 8, 2), dim3(256), 0, stream>>>(v, vT, 256, 4096);

  pam_stats<<<dim3(64, 2), dim3(256), 0, stream>>>(qT, kT, rmx, rsm);
  pam_out<<<dim3(128, 2), dim3(256), 0, stream>>>(qT, kT, vT, rmx, rsm, pamT);
  transpose_bk<<<dim3(8, 128, 2), dim3(256), 0, stream>>>(pamT, pam, 4096, 256);

  // ---- CAM ----
  fillz<<<dim3(512), dim3(256), 0, stream>>>(e, 131072);
  cam_e<<<dim3(4, 4, 16), dim3(256), 0, stream>>>(res, e);
  cam_softmax<<<dim3(256, 2), dim3(256), 0, stream>>>(e, attnc);
  gemm_cbs<0><<<dim3(64, 2, 2), dim3(256), 0, stream>>>(attnc, 65536, res, CN, cam, CN, 256, 256, 4096, nullptr, nullptr);

  // ---- combine: 3*res + gpa*PAM + gca*CAM ----
  combine<<<dim3(8192), dim3(256), 0, stream>>>(res, pam, cam, gammas, d_out, (const u16*)d_in[0]);
}

// Round 4
// 1362.094 us; speedup vs baseline: 1.6602x; 1.6602x over previous
//
#include <hip/hip_runtime.h>

typedef unsigned short u16;
typedef __attribute__((ext_vector_type(8))) short bf16x8;
typedef __attribute__((ext_vector_type(4))) float f32x4;
#define EPSV 1e-5f
#define LOG2E 1.4426950408889634f

__device__ __forceinline__ float b2f(u16 u) {
  union { float f; unsigned int i; } v; v.i = ((unsigned int)u) << 16; return v.f;
}
__device__ __forceinline__ u16 f2b(float f) {
  union { float f; unsigned int i; } v; v.f = f;
  unsigned int r = v.i + 0x7FFFu + ((v.i >> 16) & 1u);
  return (u16)(r >> 16);
}
__device__ __forceinline__ float silu_(float z) { return z / (1.f + exp2f(-LOG2E * z)); }

// Detect whether raw inputs are fp32 (1) or bf16 (0) by probing x.
__device__ int detect_fp32(const u16* __restrict__ xp) {
  int wild = 0, zeros = 0;
  for (int i = 0; i < 256; i += 2) {
    u16 u = xp[i];
    int e = (u >> 7) & 0xff;
    if (e != 0 && (e < 90 || e > 160)) wild++;
    if (u == 0) zeros++;
  }
  return (wild > 16 || zeros > 64) ? 1 : 0;
}

// ---------------- input conversion ----------------
// mode 0: -> fp32 at wsF[dst]; mode 1: -> bf16 at wsH[dst]

struct ConvArgs {
  const void* src[30];
  long dst[30];
  int end[30];
  int mode[30];
};

__global__ __launch_bounds__(256) void convert_all(ConvArgs a, float* __restrict__ wsF,
                                                   u16* __restrict__ wsH,
                                                   const u16* __restrict__ xp, int total) {
  __shared__ int sflag;
  if (threadIdx.x == 0) sflag = detect_fp32(xp);
  __syncthreads();
  const int flag = sflag;
  int gid = blockIdx.x * 256 + threadIdx.x;
  if (gid >= total) return;
  #pragma unroll 1
  for (int s = 0; s < 30; ++s) {
    if (gid < a.end[s]) {
      int idx = gid - (s ? a.end[s - 1] : 0);
      if (a.mode[s] == 0) {
        float v = flag ? ((const float*)a.src[s])[idx] : b2f(((const u16*)a.src[s])[idx]);
        wsF[a.dst[s] + idx] = v;
      } else {
        u16 h = flag ? f2b(((const float*)a.src[s])[idx]) : ((const u16*)a.src[s])[idx];
        wsH[a.dst[s] + idx] = h;
      }
      return;
    }
  }
}

// ---------------- CoordAtt ----------------

__global__ __launch_bounds__(256) void plane_means(const float* __restrict__ x, float* __restrict__ yin) {
  __shared__ float pl[4096];
  int bc = blockIdx.x, t = threadIdx.x;
  const float* xp = x + (long)bc * 4096;
  for (int j = 0; j < 16; ++j) { int id = j * 256 + t; pl[id] = xp[id]; }
  __syncthreads();
  if (t < 64) {
    float s = 0.f;
    for (int w = 0; w < 64; ++w) s += pl[t * 64 + w];
    yin[(long)bc * 128 + t] = s * (1.f / 64.f);
  } else if (t < 128) {
    int w = t - 64; float s = 0.f;
    for (int h = 0; h < 64; ++h) s += pl[h * 64 + w];
    yin[(long)bc * 128 + 64 + w] = s * (1.f / 64.f);
  }
}

__global__ __launch_bounds__(128) void ca_conv1(const float* __restrict__ yin, const float* __restrict__ w1,
                                                const float* __restrict__ b1, const float* __restrict__ bnp,
                                                float* __restrict__ ybn) {
  int b = blockIdx.x, p = threadIdx.x;
  float acc[8] = {0.f,0.f,0.f,0.f,0.f,0.f,0.f,0.f};
  for (int c = 0; c < 256; ++c) {
    float yv = yin[((long)b * 256 + c) * 128 + p];
    #pragma unroll
    for (int o = 0; o < 8; ++o) acc[o] += w1[o * 256 + c] * yv;
  }
  #pragma unroll
  for (int o = 0; o < 8; ++o) {
    float z = acc[o] + b1[o];
    float g = bnp[o], bt = bnp[8 + o], mn = bnp[16 + o], vr = bnp[24 + o];
    float s = g * rsqrtf(vr + EPSV);
    z = z * s + (bt - mn * s);
    float hs = fminf(fmaxf(z + 3.f, 0.f), 6.f) * (1.f / 6.f);
    ybn[((long)b * 8 + o) * 128 + p] = z * hs;
  }
}

__global__ __launch_bounds__(128) void ca_gate(const float* __restrict__ ybn,
    const float* __restrict__ wh, const float* __restrict__ bh,
    const float* __restrict__ ww, const float* __restrict__ bw,
    float* __restrict__ ah, float* __restrict__ aw_) {
  int c = blockIdx.x, b = blockIdx.y, t = threadIdx.x;
  if (t < 64) {
    float d = 0.f;
    #pragma unroll
    for (int o = 0; o < 8; ++o) d += wh[c * 8 + o] * ybn[((long)b * 8 + o) * 128 + t];
    d += bh[c];
    ah[((long)b * 256 + c) * 64 + t] = 1.f / (1.f + exp2f(-LOG2E * d));
  } else {
    int w = t - 64;
    float d = 0.f;
    #pragma unroll
    for (int o = 0; o < 8; ++o) d += ww[c * 8 + o] * ybn[((long)b * 8 + o) * 128 + 64 + w];
    d += bw[c];
    aw_[((long)b * 256 + c) * 64 + w] = 1.f / (1.f + exp2f(-LOG2E * d));
  }
}

__global__ __launch_bounds__(256) void apply_ca(const float* __restrict__ x, const float* __restrict__ ah,
                                                const float* __restrict__ aw_, float* __restrict__ r) {
  int idx = blockIdx.x * 256 + threadIdx.x;
  int n = idx & 4095, bc = idx >> 12;
  int h = n >> 6, w = n & 63;
  r[idx] = x[idx] * ah[bc * 64 + h] * aw_[bc * 64 + w];
}

// ---------------- VALU GEMM (kept only for O=32 q/k projections) ----------------

template<int ACT>
__global__ __launch_bounds__(256) void gemm_cbs(
    const float* __restrict__ A, long aBS,
    const float* __restrict__ In, long bBS,
    float* __restrict__ Out, long oBS,
    int O, int K, int N,
    const float* __restrict__ bnp, const float* __restrict__ bias)
{
  __shared__ __align__(16) float As[8][128];
  __shared__ __align__(16) float Bs[8][64];
  const int t = threadIdx.x;
  const int n0 = blockIdx.x * 64;
  const int o0 = blockIdx.y * 128;
  const int b  = blockIdx.z;
  const int tx = t & 15, ty = t >> 4;
  const int ao = t >> 1, ak = (t & 1) * 4;
  const int bk = t >> 5, bn_ = (t & 31) * 2;
  float acc[8][4] = {};
  const float* inb = In + (long)b * bBS + n0;
  const float* Ab = A + (long)b * aBS;
  for (int kc = 0; kc < K; kc += 8) {
    __syncthreads();
    float av[4] = {0.f, 0.f, 0.f, 0.f};
    if (o0 + ao < O) {
      float4 u = *(const float4*)(Ab + (long)(o0 + ao) * K + kc + ak);
      av[0] = u.x; av[1] = u.y; av[2] = u.z; av[3] = u.w;
    }
    #pragma unroll
    for (int j = 0; j < 4; ++j) As[ak + j][ao] = av[j];
    float2 bv = *(const float2*)(inb + (long)(kc + bk) * N + bn_);
    Bs[bk][bn_] = bv.x; Bs[bk][bn_ + 1] = bv.y;
    __syncthreads();
    #pragma unroll
    for (int kk = 0; kk < 8; ++kk) {
      float4 a0 = *(const float4*)&As[kk][ty * 8];
      float4 a1 = *(const float4*)&As[kk][ty * 8 + 4];
      float4 bq = *(const float4*)&Bs[kk][tx * 4];
      float aa[8] = {a0.x, a0.y, a0.z, a0.w, a1.x, a1.y, a1.z, a1.w};
      float bb[4] = {bq.x, bq.y, bq.z, bq.w};
      #pragma unroll
      for (int i = 0; i < 8; ++i)
        #pragma unroll
        for (int j = 0; j < 4; ++j) acc[i][j] += aa[i] * bb[j];
    }
  }
  float* ob = Out + (long)b * oBS + n0 + tx * 4;
  #pragma unroll
  for (int i = 0; i < 8; ++i) {
    int o = o0 + ty * 8 + i;
    if (o < O) {
      float al = 1.f, be = 0.f;
      if (bnp) {
        float g = bnp[o], bt = bnp[O + o], mn = bnp[2 * O + o], vr = bnp[3 * O + o];
        al = g * rsqrtf(vr + EPSV);
        be = bt - mn * al;
      }
      if (bias) be += bias[o];
      float4 rv;
      rv.x = acc[i][0] * al + be;
      rv.y = acc[i][1] * al + be;
      rv.z = acc[i][2] * al + be;
      rv.w = acc[i][3] * al + be;
      if (ACT) { rv.x = silu_(rv.x); rv.y = silu_(rv.y); rv.z = silu_(rv.z); rv.w = silu_(rv.w); }
      *(float4*)(ob + (long)o * N) = rv;
    }
  }
}

// ---------------- MFMA 1x1 conv: Out[b,o,n] = act(alpha_o * sum_k W[o,k]*In[b,k,n] + beta_o) ----------------
// block tile 64o x 128n, BK=32. 4 waves: wave w -> o-sub (w>>1)*32 (2x16), n-sub (w&1)*64 (4x16).
// A/B LDS tiles stored [row][k] bf16, row stride 40 (pad 8) for bank spread.

template<int ACT>
__global__ __launch_bounds__(256) void mfma_cbs(
    const u16* __restrict__ Wbf, long aBS,
    const float* __restrict__ In, long bBS,
    float* __restrict__ Out, long oBS,
    int O, int K, int N,
    const float* __restrict__ bnp, const float* __restrict__ bias)
{
  __shared__ u16 As[64 * 40];
  __shared__ u16 Bs[128 * 40];
  __shared__ float albe[64][2];
  const int t = threadIdx.x;
  const int n0 = blockIdx.x * 128;
  const int o0 = blockIdx.y * 64;
  const int b  = blockIdx.z;
  const int w = t >> 6, l = t & 63, lq = l >> 4, lr = l & 15;
  const int wo = (w >> 1) * 32, wn = (w & 1) * 64;
  if (t < 64) {
    int o = o0 + t;
    float al = 1.f, be = 0.f;
    if (bnp) {
      float g = bnp[o], bt = bnp[O + o], mn = bnp[2 * O + o], vr = bnp[3 * O + o];
      al = g * rsqrtf(vr + EPSV); be = bt - mn * al;
    }
    if (bias) be += bias[o];
    albe[t][0] = al; albe[t][1] = be;
  }
  const u16* Ab = Wbf + (long)b * aBS;
  const float* inb = In + (long)b * bBS + n0;
  const int ao = t >> 2, akq = (t & 3) * 8;   // A staging: 64 rows x 32k
  const int bk = t >> 3, bc8 = t & 7;         // B staging: 32k x 128n
  f32x4 acc[2][4] = {};
  for (int kc = 0; kc < K; kc += 32) {
    __syncthreads();
    *(uint4*)&As[ao * 40 + akq] = *(const uint4*)(Ab + (long)(o0 + ao) * K + kc + akq);
    const float* src = inb + (long)(kc + bk) * N + bc8 * 4;
    u16 tmp[16];
    #pragma unroll
    for (int i = 0; i < 4; ++i) {
      float4 f = *(const float4*)(src + i * 32);
      tmp[i*4+0] = f2b(f.x); tmp[i*4+1] = f2b(f.y); tmp[i*4+2] = f2b(f.z); tmp[i*4+3] = f2b(f.w);
    }
    #pragma unroll
    for (int i = 0; i < 4; ++i) {
      int n = bc8 * 4 + i * 32;
      #pragma unroll
      for (int j = 0; j < 4; ++j) Bs[(n + j) * 40 + bk] = tmp[i * 4 + j];
    }
    __syncthreads();
    bf16x8 af[2], bfv[4];
    #pragma unroll
    for (int i = 0; i < 2; ++i) af[i] = *(const bf16x8*)&As[(wo + i * 16 + lr) * 40 + lq * 8];
    #pragma unroll
    for (int j = 0; j < 4; ++j) bfv[j] = *(const bf16x8*)&Bs[(wn + j * 16 + lr) * 40 + lq * 8];
    #pragma unroll
    for (int i = 0; i < 2; ++i)
      #pragma unroll
      for (int j = 0; j < 4; ++j)
        acc[i][j] = __builtin_amdgcn_mfma_f32_16x16x32_bf16(af[i], bfv[j], acc[i][j], 0, 0, 0);
  }
  float* ob = Out + (long)b * oBS;
  #pragma unroll
  for (int i = 0; i < 2; ++i) {
    #pragma unroll
    for (int r = 0; r < 4; ++r) {
      int ol = wo + i * 16 + lq * 4 + r;
      float al = albe[ol][0], be = albe[ol][1];
      #pragma unroll
      for (int j = 0; j < 4; ++j) {
        float vv = acc[i][j][r] * al + be;
        if (ACT) vv = silu_(vv);
        ob[(long)(o0 + ol) * N + n0 + wn + j * 16 + lr] = vv;
      }
    }
  }
}

// ---------------- 3x3 conv + BN + SiLU (SAME, zero pad) ----------------
__global__ __launch_bounds__(256) void conv3_cbs(
    const float* __restrict__ W, const float* __restrict__ In, long iBS,
    float* __restrict__ Out, long oBS, int O, int I, const float* __restrict__ bnp)
{
  __shared__ float P[66][66];
  const int t = threadIdx.x;
  const int oa = blockIdx.x, obx = blockIdx.x + (O >> 1);
  const int b = blockIdx.y;
  for (int i = t; i < 66 * 66; i += 256) (&P[0][0])[i] = 0.f;
  const int xg = t & 31, yg = t >> 5;
  const int x0 = xg * 2, y0 = yg * 8;
  float accA[8][2] = {}, accB[8][2] = {};
  const float4* inb = (const float4*)(In + (long)b * iBS);
  for (int i = 0; i < I; ++i) {
    __syncthreads();
    #pragma unroll
    for (int j = 0; j < 4; ++j) {
      int id = j * 256 + t;
      float4 v = inb[i * 1024 + id];
      int row = id >> 4, col = (id & 15) * 4;
      P[row + 1][col + 1] = v.x; P[row + 1][col + 2] = v.y;
      P[row + 1][col + 3] = v.z; P[row + 1][col + 4] = v.w;
    }
    __syncthreads();
    float wa[9], wb[9];
    #pragma unroll
    for (int j = 0; j < 9; ++j) {
      wa[j] = W[((long)oa * I + i) * 9 + j];
      wb[j] = W[((long)obx * I + i) * 9 + j];
    }
    float r0[4], r1[4], r2[4];
    #pragma unroll
    for (int d = 0; d < 4; ++d) { r0[d] = P[y0][x0 + d]; r1[d] = P[y0 + 1][x0 + d]; }
    #pragma unroll
    for (int yy = 0; yy < 8; ++yy) {
      #pragma unroll
      for (int d = 0; d < 4; ++d) r2[d] = P[y0 + yy + 2][x0 + d];
      accA[yy][0] += wa[0]*r0[0]+wa[1]*r0[1]+wa[2]*r0[2]+wa[3]*r1[0]+wa[4]*r1[1]+wa[5]*r1[2]+wa[6]*r2[0]+wa[7]*r2[1]+wa[8]*r2[2];
      accA[yy][1] += wa[0]*r0[1]+wa[1]*r0[2]+wa[2]*r0[3]+wa[3]*r1[1]+wa[4]*r1[2]+wa[5]*r1[3]+wa[6]*r2[1]+wa[7]*r2[2]+wa[8]*r2[3];
      accB[yy][0] += wb[0]*r0[0]+wb[1]*r0[1]+wb[2]*r0[2]+wb[3]*r1[0]+wb[4]*r1[1]+wb[5]*r1[2]+wb[6]*r2[0]+wb[7]*r2[1]+wb[8]*r2[2];
      accB[yy][1] += wb[0]*r0[1]+wb[1]*r0[2]+wb[2]*r0[3]+wb[3]*r1[1]+wb[4]*r1[2]+wb[5]*r1[3]+wb[6]*r2[1]+wb[7]*r2[2]+wb[8]*r2[3];
      #pragma unroll
      for (int d = 0; d < 4; ++d) { r0[d] = r1[d]; r1[d] = r2[d]; }
    }
  }
  {
    float g = bnp[oa], bt = bnp[O + oa], mn = bnp[2 * O + oa], vr = bnp[3 * O + oa];
    float al = g * rsqrtf(vr + EPSV), be = bt - mn * al;
    float* ob = Out + (long)b * oBS + (long)oa * 4096;
    #pragma unroll
    for (int yy = 0; yy < 8; ++yy) {
      float2 st = make_float2(silu_(accA[yy][0] * al + be), silu_(accA[yy][1] * al + be));
      *(float2*)(ob + (y0 + yy) * 64 + x0) = st;
    }
  }
  {
    float g = bnp[obx], bt = bnp[O + obx], mn = bnp[2 * O + obx], vr = bnp[3 * O + obx];
    float al = g * rsqrtf(vr + EPSV), be = bt - mn * al;
    float* ob = Out + (long)b * oBS + (long)obx * 4096;
    #pragma unroll
    for (int yy = 0; yy < 8; ++yy) {
      float2 st = make_float2(silu_(accB[yy][0] * al + be), silu_(accB[yy][1] * al + be));
      *(float2*)(ob + (y0 + yy) * 64 + x0) = st;
    }
  }
}

// ---------------- max pools ----------------

__global__ __launch_bounds__(256) void hmax5(const float* __restrict__ src, long sBS,
                                             float* __restrict__ dst, long dBS) {
  int t = blockIdx.x * 256 + threadIdx.x;
  int b = blockIdx.y;
  int n = t & 4095, c = t >> 12;
  int w = n & 63;
  const float* p = src + (long)b * sBS + (long)c * 4096 + (n - w);
  float m = p[w];
  if (w >= 1) m = fmaxf(m, p[w - 1]);
  if (w >= 2) m = fmaxf(m, p[w - 2]);
  if (w <= 62) m = fmaxf(m, p[w + 1]);
  if (w <= 61) m = fmaxf(m, p[w + 2]);
  dst[(long)b * dBS + t] = m;
}

__global__ __launch_bounds__(256) void vmax5(const float* __restrict__ src, long sBS,
                                             float* __restrict__ dst, long dBS) {
  int t = blockIdx.x * 256 + threadIdx.x;
  int b = blockIdx.y;
  int n = t & 4095, c = t >> 12;
  int h = n >> 6, w = n & 63;
  const float* p = src + (long)b * sBS + (long)c * 4096 + w;
  float m = p[h * 64];
  if (h >= 1) m = fmaxf(m, p[(h - 1) * 64]);
  if (h >= 2) m = fmaxf(m, p[(h - 2) * 64]);
  if (h <= 62) m = fmaxf(m, p[(h + 1) * 64]);
  if (h <= 61) m = fmaxf(m, p[(h + 2) * 64]);
  dst[(long)b * dBS + t] = m;
}

// ---------------- transpose (B, R, C) -> (B, C, R) ----------------

__global__ __launch_bounds__(256) void transpose_bk(const float* __restrict__ in, float* __restrict__ out,
                                                    int R, int Cc) {
  __shared__ float tile[32][33];
  int b = blockIdx.z;
  int c0 = blockIdx.x * 32, r0 = blockIdx.y * 32;
  int tx = threadIdx.x & 31, ty = threadIdx.x >> 5;
  const float* ib = in + (long)b * R * Cc;
  float* ob = out + (long)b * R * Cc;
  #pragma unroll
  for (int i = 0; i < 4; ++i) {
    int r = r0 + ty + i * 8;
    tile[ty + i * 8][tx] = ib[(long)r * Cc + c0 + tx];
  }
  __syncthreads();
  #pragma unroll
  for (int i = 0; i < 4; ++i) {
    int c = c0 + ty + i * 8;
    ob[(long)c * R + r0 + tx] = tile[tx][ty + i * 8];
  }
}

// ---------------- PAM stats: row max only, m-split x4 ----------------
__global__ __launch_bounds__(256) void pam_max(const float* __restrict__ qT, const float* __restrict__ kT,
                                               float* __restrict__ pmax) {
  __shared__ __align__(16) float kch[4][64][32];
  __shared__ float cm[4][64];
  const int t = threadIdx.x;
  const int b = blockIdx.z, ms = blockIdx.y, n0 = blockIdx.x * 64;
  const int tn = t & 63, ts = t >> 6;
  float4 qv[8];
  const float4* qrow = (const float4*)(qT + ((long)b * 4096 + n0 + tn) * 32);
  #pragma unroll
  for (int j = 0; j < 8; ++j) qv[j] = qrow[j];
  const float4* k4 = (const float4*)(kT + ((long)b * 4096 + ms * 1024) * 32);
  float mx = -1e30f;
  for (int it = 0; it < 4; ++it) {
    __syncthreads();
    #pragma unroll
    for (int j = 0; j < 8; ++j) {
      int id = j * 256 + t;
      int seg = id >> 9, rem = id & 511;
      int mrow = rem >> 3, c4 = rem & 7;
      *(float4*)&kch[seg][mrow][c4 * 4] = k4[(seg * 256 + it * 64 + mrow) * 8 + c4];
    }
    __syncthreads();
    for (int mm = 0; mm < 64; ++mm) {
      const float4* kr = (const float4*)&kch[ts][mm][0];
      float d = 0.f;
      #pragma unroll
      for (int j = 0; j < 8; ++j) {
        float4 kv = kr[j];
        d += qv[j].x * kv.x + qv[j].y * kv.y + qv[j].z * kv.z + qv[j].w * kv.w;
      }
      mx = fmaxf(mx, d);
    }
  }
  cm[ts][tn] = mx;
  __syncthreads();
  if (t < 64) {
    float M = cm[0][t];
    #pragma unroll
    for (int s = 1; s < 4; ++s) M = fmaxf(M, cm[s][t]);
    pmax[((long)ms * 2 + b) * 4096 + n0 + t] = M;
  }
}

__global__ __launch_bounds__(256) void pam_merge(const float* __restrict__ pmax, float* __restrict__ rmx) {
  int i = blockIdx.x * 256 + threadIdx.x;   // 8192 = B*4096
  int b = i >> 12, n = i & 4095;
  float m = pmax[(long)b * 4096 + n];
  #pragma unroll
  for (int ms = 1; ms < 4; ++ms) m = fmaxf(m, pmax[((long)ms * 2 + b) * 4096 + n]);
  rmx[i] = m;
}

// ---------------- PAM attention (MFMA, self-normalizing): pam[c][n] = sum_m softmax(qk)[n,m] v[c,m] ----------------
// grid (n/32, c/64, B); 4 waves: wn = w&1 (16n), wc = w>>1 (32c).
__global__ __launch_bounds__(256) void pam_attn(const float* __restrict__ qT, const float* __restrict__ kT,
    const float* __restrict__ v, const float* __restrict__ rowmax, float* __restrict__ pam) {
  __shared__ u16 Qs[32 * 40];
  __shared__ u16 Ks[64 * 40];
  __shared__ u16 Vs[64 * 72];
  __shared__ u16 Ps[32 * 72];
  __shared__ float rmL[32];
  __shared__ float srow[32];
  const int t = threadIdx.x;
  const int b = blockIdx.z;
  const int n0 = blockIdx.x * 32;
  const int c0 = blockIdx.y * 64;
  const int w = t >> 6, l = t & 63, lq = l >> 4, lr = l & 15;
  const int wn = w & 1, wc = w >> 1;
  {
    int nn = t >> 3, kq = (t & 7) * 4;
    float4 f = *(const float4*)(qT + ((long)b * 4096 + n0 + nn) * 32 + kq);
    ushort4 u; u.x = f2b(f.x); u.y = f2b(f.y); u.z = f2b(f.z); u.w = f2b(f.w);
    *(ushort4*)&Qs[nn * 40 + kq] = u;
    if (t < 32) { rmL[t] = rowmax[(long)b * 4096 + n0 + t] * LOG2E; srow[t] = 0.f; }
  }
  __syncthreads();
  bf16x8 qf = *(const bf16x8*)&Qs[(wn * 16 + lr) * 40 + lq * 8];
  float rm4[4];
  #pragma unroll
  for (int r = 0; r < 4; ++r) rm4[r] = rmL[wn * 16 + lq * 4 + r];
  float sp[4] = {0.f, 0.f, 0.f, 0.f};
  f32x4 acc[2] = {};
  const int kmm = t >> 2, kkq = (t & 3) * 8;
  const int vcc = t >> 2, vmq = (t & 3) * 16;
  for (int m0 = 0; m0 < 4096; m0 += 64) {
    __syncthreads();
    {
      const float* src = kT + ((long)b * 4096 + m0 + kmm) * 32 + kkq;
      float4 f0 = *(const float4*)src, f1 = *(const float4*)(src + 4);
      ushort4 u0, u1;
      u0.x=f2b(f0.x); u0.y=f2b(f0.y); u0.z=f2b(f0.z); u0.w=f2b(f0.w);
      u1.x=f2b(f1.x); u1.y=f2b(f1.y); u1.z=f2b(f1.z); u1.w=f2b(f1.w);
      *(ushort4*)&Ks[kmm * 40 + kkq] = u0;
      *(ushort4*)&Ks[kmm * 40 + kkq + 4] = u1;
    }
    {
      const float* src = v + ((long)b * 256 + c0 + vcc) * 4096 + m0 + vmq;
      union { u16 h[16]; uint4 q[2]; } tb;
      #pragma unroll
      for (int i = 0; i < 4; ++i) {
        float4 f = *(const float4*)(src + i * 4);
        tb.h[i*4+0]=f2b(f.x); tb.h[i*4+1]=f2b(f.y); tb.h[i*4+2]=f2b(f.z); tb.h[i*4+3]=f2b(f.w);
      }
      *(uint4*)&Vs[vcc * 72 + vmq] = tb.q[0];
      *(uint4*)&Vs[vcc * 72 + vmq + 8] = tb.q[1];
    }
    __syncthreads();
    // QK -> P (wave covers n-sub wn, m-subs wc*2 + {0,1})
    #pragma unroll
    for (int s = 0; s < 2; ++s) {
      int msub = wc * 2 + s;
      bf16x8 kf = *(const bf16x8*)&Ks[(msub * 16 + lr) * 40 + lq * 8];
      f32x4 S = {};
      S = __builtin_amdgcn_mfma_f32_16x16x32_bf16(qf, kf, S, 0, 0, 0);
      #pragma unroll
      for (int r = 0; r < 4; ++r) {
        float p = exp2f(S[r] * LOG2E - rm4[r]);
        u16 pb = f2b(p);
        sp[r] += b2f(pb);
        Ps[(wn * 16 + lq * 4 + r) * 72 + msub * 16 + lr] = pb;
      }
    }
    __syncthreads();
    // PV
    #pragma unroll
    for (int ks = 0; ks < 2; ++ks) {
      bf16x8 pf = *(const bf16x8*)&Ps[(wn * 16 + lr) * 72 + ks * 32 + lq * 8];
      #pragma unroll
      for (int it = 0; it < 2; ++it) {
        bf16x8 vf = *(const bf16x8*)&Vs[(wc * 32 + it * 16 + lr) * 72 + ks * 32 + lq * 8];
        acc[it] = __builtin_amdgcn_mfma_f32_16x16x32_bf16(vf, pf, acc[it], 0, 0, 0);
      }
    }
  }
  #pragma unroll
  for (int r = 0; r < 4; ++r) atomicAdd(&srow[wn * 16 + lq * 4 + r], sp[r]);
  __syncthreads();
  float inv = 1.f / srow[wn * 16 + lr];
  float* ob = pam + (long)b * (256L * 4096) + n0 + wn * 16 + lr;
  #pragma unroll
  for (int it = 0; it < 2; ++it)
    #pragma unroll
    for (int r = 0; r < 4; ++r)
      ob[(long)(c0 + wc * 32 + it * 16 + lq * 4 + r) * 4096] = acc[it][r] * inv;
}

// ---------------- CAM ----------------

__global__ __launch_bounds__(256) void fillz(float* __restrict__ p, int n) {
  int i = blockIdx.x * 256 + threadIdx.x;
  if (i < n) p[i] = 0.f;
}

__global__ __launch_bounds__(256) void cam_e(const float* __restrict__ f, float* __restrict__ e) {
  __shared__ __align__(16) float fc[32][68];
  __shared__ __align__(16) float fd[32][68];
  const int c0 = blockIdx.x * 64, d0 = blockIdx.y * 64;
  const int bz = blockIdx.z;
  const int b = bz >> 3, ns = bz & 7;
  const int t = threadIdx.x;
  const int tx = t & 15, ty = t >> 4;
  float acc[4][4] = {};
  const float* fb = f + (long)b * 1048576;
  for (int nc = 0; nc < 16; ++nc) {
    int nb = ns * 512 + nc * 32;
    __syncthreads();
    #pragma unroll
    for (int i = 0; i < 2; ++i) {
      int id = i * 256 + t;
      int row = id >> 3, c4 = id & 7;
      float4 v = *(const float4*)(fb + (long)(c0 + row) * 4096 + nb + c4 * 4);
      fc[c4*4+0][row] = v.x; fc[c4*4+1][row] = v.y; fc[c4*4+2][row] = v.z; fc[c4*4+3][row] = v.w;
      float4 u = *(const float4*)(fb + (long)(d0 + row) * 4096 + nb + c4 * 4);
      fd[c4*4+0][row] = u.x; fd[c4*4+1][row] = u.y; fd[c4*4+2][row] = u.z; fd[c4*4+3][row] = u.w;
    }
    __syncthreads();
    #pragma unroll
    for (int nn = 0; nn < 32; ++nn) {
      float4 a = *(const float4*)&fc[nn][ty * 4];
      float4 bq = *(const float4*)&fd[nn][tx * 4];
      float aa[4] = {a.x, a.y, a.z, a.w};
      float bb[4] = {bq.x, bq.y, bq.z, bq.w};
      #pragma unroll
      for (int i = 0; i < 4; ++i)
        #pragma unroll
        for (int j = 0; j < 4; ++j) acc[i][j] += aa[i] * bb[j];
    }
  }
  #pragma unroll
  for (int i = 0; i < 4; ++i)
    #pragma unroll
    for (int j = 0; j < 4; ++j)
      atomicAdd(&e[((long)b << 16) + (long)(c0 + ty * 4 + i) * 256 + d0 + tx * 4 + j], acc[i][j]);
}

// softmax(min-shift) over d; outputs bf16 for the MFMA bmm.
__global__ __launch_bounds__(256) void cam_softmax(const float* __restrict__ e, u16* __restrict__ attn) {
  __shared__ float red[256];
  int c = blockIdx.x, b = blockIdx.y, t = threadIdx.x;
  const float* row = e + ((long)b << 16) + (long)c * 256;
  float v = row[t];
  red[t] = v; __syncthreads();
  for (int s = 128; s > 0; s >>= 1) { if (t < s) red[t] = fminf(red[t], red[t + s]); __syncthreads(); }
  float emin = red[0]; __syncthreads();
  float ex = exp2f(LOG2E * (emin - v));
  red[t] = ex; __syncthreads();
  for (int s = 128; s > 0; s >>= 1) { if (t < s) red[t] += red[t + s]; __syncthreads(); }
  float inv = 1.f / red[0];
  attn[((long)b << 16) + (long)c * 256 + t] = f2b(ex * inv);
}

// ---------------- final combine ----------------

__global__ __launch_bounds__(256) void combine(const float* __restrict__ res, const float* __restrict__ pam,
    const float* __restrict__ cam, const float* __restrict__ gp,
    void* __restrict__ outp, const u16* __restrict__ xp) {
  __shared__ int sflag;
  if (threadIdx.x == 0) sflag = detect_fp32(xp);
  __syncthreads();
  int idx = blockIdx.x * 256 + threadIdx.x;
  float g1 = gp[0], g2 = gp[1];
  float v = 3.f * res[idx] + g1 * pam[idx] + g2 * cam[idx];
  if (sflag) ((float*)outp)[idx] = v;
  else       ((u16*)outp)[idx] = f2b(v);
}

// ---------------- launch ----------------

extern "C" void kernel_launch(void* const* d_in, const int* in_sizes, int n_in,
                              void* d_out, int out_size, void* d_ws, size_t ws_size,
                              hipStream_t stream)
{
  (void)out_size; (void)ws_size; (void)n_in;
  float* ws = (float*)d_ws;
  const long CN = 256L * 4096;

  float* A  = ws;            // r -> res
  float* Bp = ws + 2 * CN;   // x_f32 -> s1out -> pool tmp -> s5out -> v
  float* Cp = ws + 4 * CN;   // CoordAtt smalls -> s3out
  float* D  = ws + 6 * CN;   // cat(8CN) -> {y12, attn smalls} -> {pam, cam}
  const long WFo = 14 * CN;

  float* yin = Cp;
  float* ybn = Cp + 65536;
  float* ah  = Cp + 67584;
  float* aw_ = Cp + 100352;

  float* q     = D + 4 * CN;
  float* k     = q + 262144;
  float* qT    = q + 524288;
  float* kT    = q + 786432;
  float* pmax  = q + 1048576;          // 4*2*4096 = 32768
  float* rmx   = q + 1081344;          // 8192
  float* e     = q + 1089536;          // 131072
  u16*   attnc = (u16*)(q + 1220608);  // 65536 u16 (fits in 131072-float slot)

  float* res = A;
  float* v   = Bp;
  float* pam = D;
  float* cam = D + 2 * CN;

  // ---- input conversion ----
  // bf16 staging for MFMA weights: inputs 8(s1_w),10(s2_w),14(s4_w),16(s5_w),20(s7_w),26(pv_w)
  ConvArgs ca;
  long fOff[30], hOff[30];
  int isH[30];
  {
    long cum = 0, fcur = WFo, hcur = 0;
    for (int i = 0; i < 30; ++i) {
      ca.src[i] = d_in[i];
      int h = (i == 8 || i == 10 || i == 14 || i == 16 || i == 20 || i == 26) ? 1 : 0;
      isH[i] = h;
      ca.mode[i] = h;
      if (i == 0) { ca.dst[i] = 2 * CN; fOff[i] = 2 * CN; }
      else if (h) { ca.dst[i] = hcur; hOff[i] = hcur; hcur += in_sizes[i]; }
      else        { ca.dst[i] = fcur; fOff[i] = fcur; fcur += in_sizes[i]; }
      cum += in_sizes[i];
      ca.end[i] = (int)cum;
    }
    (void)isH;
  }
  // u16 staging region starts right after the fp32 weight staging
  long fTotal = WFo;
  for (int i = 1; i < 30; ++i) if (!ca.mode[i]) fTotal = (fOff[i] + in_sizes[i] > fTotal) ? fOff[i] + in_sizes[i] : fTotal;
  u16* wsH = (u16*)(ws + fTotal);
  int total = ca.end[29];
  convert_all<<<dim3((total + 255) / 256), dim3(256), 0, stream>>>(ca, ws, wsH, (const u16*)d_in[0], total);

  float* xf    = Bp;
  float* ca_w1 = ws + fOff[1];
  float* ca_b1 = ws + fOff[2];
  float* ca_bn = ws + fOff[3];
  float* ca_wh = ws + fOff[4];
  float* ca_bh = ws + fOff[5];
  float* ca_ww = ws + fOff[6];
  float* ca_bw = ws + fOff[7];
  u16*   s1_w  = wsH + hOff[8];   float* s1_bn = ws + fOff[9];
  u16*   s2_w  = wsH + hOff[10];  float* s2_bn = ws + fOff[11];
  float* s3_w  = ws + fOff[12];   float* s3_bn = ws + fOff[13];
  u16*   s4_w  = wsH + hOff[14];  float* s4_bn = ws + fOff[15];
  u16*   s5_w  = wsH + hOff[16];  float* s5_bn = ws + fOff[17];
  float* s6_w  = ws + fOff[18];   float* s6_bn = ws + fOff[19];
  u16*   s7_w  = wsH + hOff[20];  float* s7_bn = ws + fOff[21];
  float* pq_w  = ws + fOff[22];   float* pq_b  = ws + fOff[23];
  float* pk_w  = ws + fOff[24];   float* pk_b  = ws + fOff[25];
  u16*   pv_w  = wsH + hOff[26];  float* pv_b  = ws + fOff[27];
  float* gammas = ws + fOff[28];  // [gamma_pa, gamma_ca] adjacent in fp32 staging

  // ---- CoordAtt ----
  plane_means<<<dim3(512), dim3(256), 0, stream>>>(xf, yin);
  ca_conv1<<<dim3(2), dim3(128), 0, stream>>>(yin, ca_w1, ca_b1, ca_bn, ybn);
  ca_gate<<<dim3(256, 2), dim3(128), 0, stream>>>(ybn, ca_wh, ca_bh, ca_ww, ca_bw, ah, aw_);
  apply_ca<<<dim3(8192), dim3(256), 0, stream>>>(xf, ah, aw_, A);

  // ---- SPPCSPC ----
  mfma_cbs<1><<<dim3(32, 4, 2), dim3(256), 0, stream>>>(s1_w, 0, A, CN, Bp, CN, 256, 256, 4096, s1_bn, nullptr);
  conv3_cbs<<<dim3(128, 2), dim3(256), 0, stream>>>(s3_w, Bp, CN, Cp, CN, 256, 256, s3_bn);
  mfma_cbs<1><<<dim3(32, 4, 2), dim3(256), 0, stream>>>(s4_w, 0, Cp, CN, D, 4 * CN, 256, 256, 4096, s4_bn, nullptr);

  hmax5<<<dim3(4096, 2), dim3(256), 0, stream>>>(D, 4 * CN, Bp, CN);
  vmax5<<<dim3(4096, 2), dim3(256), 0, stream>>>(Bp, CN, D + CN, 4 * CN);
  hmax5<<<dim3(4096, 2), dim3(256), 0, stream>>>(D + CN, 4 * CN, Bp, CN);
  vmax5<<<dim3(4096, 2), dim3(256), 0, stream>>>(Bp, CN, D + 2 * CN, 4 * CN);
  hmax5<<<dim3(4096, 2), dim3(256), 0, stream>>>(D + 2 * CN, 4 * CN, Bp, CN);
  vmax5<<<dim3(4096, 2), dim3(256), 0, stream>>>(Bp, CN, D + 3 * CN, 4 * CN);

  mfma_cbs<1><<<dim3(32, 4, 2), dim3(256), 0, stream>>>(s5_w, 0, D, 4 * CN, Bp, CN, 256, 1024, 4096, s5_bn, nullptr);
  conv3_cbs<<<dim3(128, 2), dim3(256), 0, stream>>>(s6_w, Bp, CN, D, 2 * CN, 256, 256, s6_bn);
  mfma_cbs<1><<<dim3(32, 4, 2), dim3(256), 0, stream>>>(s2_w, 0, A, CN, D + CN, 2 * CN, 256, 256, 4096, s2_bn, nullptr);
  mfma_cbs<1><<<dim3(32, 4, 2), dim3(256), 0, stream>>>(s7_w, 0, D, 2 * CN, A, CN, 256, 512, 4096, s7_bn, nullptr);

  // ---- PAM ----
  gemm_cbs<0><<<dim3(64, 1, 2), dim3(256), 0, stream>>>(pq_w, 0, res, CN, q, 131072, 32, 256, 4096, nullptr, pq_b);
  gemm_cbs<0><<<dim3(64, 1, 2), dim3(256), 0, stream>>>(pk_w, 0, res, CN, k, 131072, 32, 256, 4096, nullptr, pk_b);
  mfma_cbs<0><<<dim3(32, 4, 2), dim3(256), 0, stream>>>(pv_w, 0, res, CN, v, CN, 256, 256, 4096, nullptr, pv_b);

  transpose_bk<<<dim3(128, 1, 2), dim3(256), 0, stream>>>(q, qT, 32, 4096);
  transpose_bk<<<dim3(128, 1, 2), dim3(256), 0, stream>>>(k, kT, 32, 4096);

  pam_max<<<dim3(64, 4, 2), dim3(256), 0, stream>>>(qT, kT, pmax);
  pam_merge<<<dim3(32), dim3(256), 0, stream>>>(pmax, rmx);
  pam_attn<<<dim3(128, 4, 2), dim3(256), 0, stream>>>(qT, kT, v, rmx, pam);

  // ---- CAM ----
  fillz<<<dim3(512), dim3(256), 0, stream>>>(e, 131072);
  cam_e<<<dim3(4, 4, 16), dim3(256), 0, stream>>>(res, e);
  cam_softmax<<<dim3(256, 2), dim3(256), 0, stream>>>(e, attnc);
  mfma_cbs<0><<<dim3(32, 4, 2), dim3(256), 0, stream>>>(attnc, 65536, res, CN, cam, CN, 256, 256, 4096, nullptr, nullptr);

  // ---- combine: 3*res + gpa*PAM + gca*CAM ----
  combine<<<dim3(8192), dim3(256), 0, stream>>>(res, pam, cam, gammas, d_out, (const u16*)d_in[0]);
}

// Round 5
// 827.412 us; speedup vs baseline: 2.7330x; 1.6462x over previous
//
#include <hip/hip_runtime.h>

typedef unsigned short u16;
typedef __attribute__((ext_vector_type(8))) short bf16x8;
typedef __attribute__((ext_vector_type(4))) float f32x4;
#define EPSV 1e-5f
#define LOG2E 1.4426950408889634f

__device__ __forceinline__ float b2f(u16 u) {
  union { float f; unsigned int i; } v; v.i = ((unsigned int)u) << 16; return v.f;
}
__device__ __forceinline__ u16 f2b(float f) {
  union { float f; unsigned int i; } v; v.f = f;
  unsigned int r = v.i + 0x7FFFu + ((v.i >> 16) & 1u);
  return (u16)(r >> 16);
}
__device__ __forceinline__ float silu_(float z) { return z / (1.f + exp2f(-LOG2E * z)); }

// Detect whether raw inputs are fp32 (1) or bf16 (0) by probing x.
__device__ int detect_fp32(const u16* __restrict__ xp) {
  int wild = 0, zeros = 0;
  for (int i = 0; i < 256; i += 2) {
    u16 u = xp[i];
    int e = (u >> 7) & 0xff;
    if (e != 0 && (e < 90 || e > 160)) wild++;
    if (u == 0) zeros++;
  }
  return (wild > 16 || zeros > 64) ? 1 : 0;
}

// ---------------- input conversion ----------------
// mode 0: -> fp32 at wsF[dst]; mode 1: -> bf16 at wsH[dst]

struct ConvArgs {
  const void* src[30];
  long dst[30];
  int end[30];
  int mode[30];
};

__global__ __launch_bounds__(256) void convert_all(ConvArgs a, float* __restrict__ wsF,
                                                   u16* __restrict__ wsH,
                                                   const u16* __restrict__ xp, int total) {
  __shared__ int sflag;
  if (threadIdx.x == 0) sflag = detect_fp32(xp);
  __syncthreads();
  const int flag = sflag;
  int gid = blockIdx.x * 256 + threadIdx.x;
  if (gid >= total) return;
  #pragma unroll 1
  for (int s = 0; s < 30; ++s) {
    if (gid < a.end[s]) {
      int idx = gid - (s ? a.end[s - 1] : 0);
      if (a.mode[s] == 0) {
        float v = flag ? ((const float*)a.src[s])[idx] : b2f(((const u16*)a.src[s])[idx]);
        wsF[a.dst[s] + idx] = v;
      } else {
        u16 h = flag ? f2b(((const float*)a.src[s])[idx]) : ((const u16*)a.src[s])[idx];
        wsH[a.dst[s] + idx] = h;
      }
      return;
    }
  }
}

// conv3 weight transform: fp32 W[o][I][3][3] -> bf16 Wt[I/32][tap][256o][32ch]
__global__ __launch_bounds__(256) void w3t(const float* __restrict__ Wsrc, u16* __restrict__ Wdst) {
  int idx = blockIdx.x * 256 + threadIdx.x;   // 589824 total
  int ch = idx & 31;
  int o  = (idx >> 5) & 255;
  int tap = (idx >> 13) % 9;
  int c8 = (idx >> 13) / 9;
  int i = c8 * 32 + ch;
  Wdst[idx] = f2b(Wsrc[((long)o * 256 + i) * 9 + tap]);
}

// ---------------- CoordAtt ----------------

__global__ __launch_bounds__(256) void plane_means(const float* __restrict__ x, float* __restrict__ yin) {
  __shared__ float pl[4096];
  int bc = blockIdx.x, t = threadIdx.x;
  const float* xp = x + (long)bc * 4096;
  for (int j = 0; j < 16; ++j) { int id = j * 256 + t; pl[id] = xp[id]; }
  __syncthreads();
  if (t < 64) {
    float s = 0.f;
    for (int w = 0; w < 64; ++w) s += pl[t * 64 + w];
    yin[(long)bc * 128 + t] = s * (1.f / 64.f);
  } else if (t < 128) {
    int w = t - 64; float s = 0.f;
    for (int h = 0; h < 64; ++h) s += pl[h * 64 + w];
    yin[(long)bc * 128 + 64 + w] = s * (1.f / 64.f);
  }
}

__global__ __launch_bounds__(128) void ca_conv1(const float* __restrict__ yin, const float* __restrict__ w1,
                                                const float* __restrict__ b1, const float* __restrict__ bnp,
                                                float* __restrict__ ybn) {
  int b = blockIdx.x, p = threadIdx.x;
  float acc[8] = {0.f,0.f,0.f,0.f,0.f,0.f,0.f,0.f};
  for (int c = 0; c < 256; ++c) {
    float yv = yin[((long)b * 256 + c) * 128 + p];
    #pragma unroll
    for (int o = 0; o < 8; ++o) acc[o] += w1[o * 256 + c] * yv;
  }
  #pragma unroll
  for (int o = 0; o < 8; ++o) {
    float z = acc[o] + b1[o];
    float g = bnp[o], bt = bnp[8 + o], mn = bnp[16 + o], vr = bnp[24 + o];
    float s = g * rsqrtf(vr + EPSV);
    z = z * s + (bt - mn * s);
    float hs = fminf(fmaxf(z + 3.f, 0.f), 6.f) * (1.f / 6.f);
    ybn[((long)b * 8 + o) * 128 + p] = z * hs;
  }
}

__global__ __launch_bounds__(128) void ca_gate(const float* __restrict__ ybn,
    const float* __restrict__ wh, const float* __restrict__ bh,
    const float* __restrict__ ww, const float* __restrict__ bw,
    float* __restrict__ ah, float* __restrict__ aw_) {
  int c = blockIdx.x, b = blockIdx.y, t = threadIdx.x;
  if (t < 64) {
    float d = 0.f;
    #pragma unroll
    for (int o = 0; o < 8; ++o) d += wh[c * 8 + o] * ybn[((long)b * 8 + o) * 128 + t];
    d += bh[c];
    ah[((long)b * 256 + c) * 64 + t] = 1.f / (1.f + exp2f(-LOG2E * d));
  } else {
    int w = t - 64;
    float d = 0.f;
    #pragma unroll
    for (int o = 0; o < 8; ++o) d += ww[c * 8 + o] * ybn[((long)b * 8 + o) * 128 + 64 + w];
    d += bw[c];
    aw_[((long)b * 256 + c) * 64 + w] = 1.f / (1.f + exp2f(-LOG2E * d));
  }
}

__global__ __launch_bounds__(256) void apply_ca(const float* __restrict__ x, const float* __restrict__ ah,
                                                const float* __restrict__ aw_, float* __restrict__ r) {
  int idx = blockIdx.x * 256 + threadIdx.x;
  int n = idx & 4095, bc = idx >> 12;
  int h = n >> 6, w = n & 63;
  r[idx] = x[idx] * ah[bc * 64 + h] * aw_[bc * 64 + w];
}

// ---------------- VALU GEMM (kept only for O=32 q/k projections) ----------------

template<int ACT>
__global__ __launch_bounds__(256) void gemm_cbs(
    const float* __restrict__ A, long aBS,
    const float* __restrict__ In, long bBS,
    float* __restrict__ Out, long oBS,
    int O, int K, int N,
    const float* __restrict__ bnp, const float* __restrict__ bias)
{
  __shared__ __align__(16) float As[8][128];
  __shared__ __align__(16) float Bs[8][64];
  const int t = threadIdx.x;
  const int n0 = blockIdx.x * 64;
  const int o0 = blockIdx.y * 128;
  const int b  = blockIdx.z;
  const int tx = t & 15, ty = t >> 4;
  const int ao = t >> 1, ak = (t & 1) * 4;
  const int bk = t >> 5, bn_ = (t & 31) * 2;
  float acc[8][4] = {};
  const float* inb = In + (long)b * bBS + n0;
  const float* Ab = A + (long)b * aBS;
  for (int kc = 0; kc < K; kc += 8) {
    __syncthreads();
    float av[4] = {0.f, 0.f, 0.f, 0.f};
    if (o0 + ao < O) {
      float4 u = *(const float4*)(Ab + (long)(o0 + ao) * K + kc + ak);
      av[0] = u.x; av[1] = u.y; av[2] = u.z; av[3] = u.w;
    }
    #pragma unroll
    for (int j = 0; j < 4; ++j) As[ak + j][ao] = av[j];
    float2 bv = *(const float2*)(inb + (long)(kc + bk) * N + bn_);
    Bs[bk][bn_] = bv.x; Bs[bk][bn_ + 1] = bv.y;
    __syncthreads();
    #pragma unroll
    for (int kk = 0; kk < 8; ++kk) {
      float4 a0 = *(const float4*)&As[kk][ty * 8];
      float4 a1 = *(const float4*)&As[kk][ty * 8 + 4];
      float4 bq = *(const float4*)&Bs[kk][tx * 4];
      float aa[8] = {a0.x, a0.y, a0.z, a0.w, a1.x, a1.y, a1.z, a1.w};
      float bb[4] = {bq.x, bq.y, bq.z, bq.w};
      #pragma unroll
      for (int i = 0; i < 8; ++i)
        #pragma unroll
        for (int j = 0; j < 4; ++j) acc[i][j] += aa[i] * bb[j];
    }
  }
  float* ob = Out + (long)b * oBS + n0 + tx * 4;
  #pragma unroll
  for (int i = 0; i < 8; ++i) {
    int o = o0 + ty * 8 + i;
    if (o < O) {
      float al = 1.f, be = 0.f;
      if (bnp) {
        float g = bnp[o], bt = bnp[O + o], mn = bnp[2 * O + o], vr = bnp[3 * O + o];
        al = g * rsqrtf(vr + EPSV);
        be = bt - mn * al;
      }
      if (bias) be += bias[o];
      float4 rv;
      rv.x = acc[i][0] * al + be;
      rv.y = acc[i][1] * al + be;
      rv.z = acc[i][2] * al + be;
      rv.w = acc[i][3] * al + be;
      if (ACT) { rv.x = silu_(rv.x); rv.y = silu_(rv.y); rv.z = silu_(rv.z); rv.w = silu_(rv.w); }
      *(float4*)(ob + (long)o * N) = rv;
    }
  }
}

// ---------------- MFMA 1x1 conv ----------------

template<int ACT>
__global__ __launch_bounds__(256) void mfma_cbs(
    const u16* __restrict__ Wbf, long aBS,
    const float* __restrict__ In, long bBS,
    float* __restrict__ Out, long oBS,
    int O, int K, int N,
    const float* __restrict__ bnp, const float* __restrict__ bias)
{
  __shared__ u16 As[64 * 40];
  __shared__ u16 Bs[128 * 40];
  __shared__ float albe[64][2];
  const int t = threadIdx.x;
  const int n0 = blockIdx.x * 128;
  const int o0 = blockIdx.y * 64;
  const int b  = blockIdx.z;
  const int w = t >> 6, l = t & 63, lq = l >> 4, lr = l & 15;
  const int wo = (w >> 1) * 32, wn = (w & 1) * 64;
  if (t < 64) {
    int o = o0 + t;
    float al = 1.f, be = 0.f;
    if (bnp) {
      float g = bnp[o], bt = bnp[O + o], mn = bnp[2 * O + o], vr = bnp[3 * O + o];
      al = g * rsqrtf(vr + EPSV); be = bt - mn * al;
    }
    if (bias) be += bias[o];
    albe[t][0] = al; albe[t][1] = be;
  }
  const u16* Ab = Wbf + (long)b * aBS;
  const float* inb = In + (long)b * bBS + n0;
  const int ao = t >> 2, akq = (t & 3) * 8;
  const int bk = t >> 3, bc8 = t & 7;
  f32x4 acc[2][4] = {};
  for (int kc = 0; kc < K; kc += 32) {
    __syncthreads();
    *(uint4*)&As[ao * 40 + akq] = *(const uint4*)(Ab + (long)(o0 + ao) * K + kc + akq);
    const float* src = inb + (long)(kc + bk) * N + bc8 * 4;
    u16 tmp[16];
    #pragma unroll
    for (int i = 0; i < 4; ++i) {
      float4 f = *(const float4*)(src + i * 32);
      tmp[i*4+0] = f2b(f.x); tmp[i*4+1] = f2b(f.y); tmp[i*4+2] = f2b(f.z); tmp[i*4+3] = f2b(f.w);
    }
    #pragma unroll
    for (int i = 0; i < 4; ++i) {
      int n = bc8 * 4 + i * 32;
      #pragma unroll
      for (int j = 0; j < 4; ++j) Bs[(n + j) * 40 + bk] = tmp[i * 4 + j];
    }
    __syncthreads();
    bf16x8 af[2], bfv[4];
    #pragma unroll
    for (int i = 0; i < 2; ++i) af[i] = *(const bf16x8*)&As[(wo + i * 16 + lr) * 40 + lq * 8];
    #pragma unroll
    for (int j = 0; j < 4; ++j) bfv[j] = *(const bf16x8*)&Bs[(wn + j * 16 + lr) * 40 + lq * 8];
    #pragma unroll
    for (int i = 0; i < 2; ++i)
      #pragma unroll
      for (int j = 0; j < 4; ++j)
        acc[i][j] = __builtin_amdgcn_mfma_f32_16x16x32_bf16(af[i], bfv[j], acc[i][j], 0, 0, 0);
  }
  float* ob = Out + (long)b * oBS;
  #pragma unroll
  for (int i = 0; i < 2; ++i) {
    #pragma unroll
    for (int r = 0; r < 4; ++r) {
      int ol = wo + i * 16 + lq * 4 + r;
      float al = albe[ol][0], be = albe[ol][1];
      #pragma unroll
      for (int j = 0; j < 4; ++j) {
        float vv = acc[i][j][r] * al + be;
        if (ACT) vv = silu_(vv);
        ob[(long)(o0 + ol) * N + n0 + wn + j * 16 + lr] = vv;
      }
    }
  }
}

// ---------------- MFMA 3x3 conv (implicit GEMM over 9 shifted taps) ----------------
// Wt: [I/32][tap][256o][32ch] bf16. In/Out: (b, C, 64, 64) fp32. Tile 64o x 128n (2 image rows).
__global__ __launch_bounds__(256) void conv3_mfma(
    const u16* __restrict__ Wt,
    const float* __restrict__ In, long iBS,
    float* __restrict__ Out, long oBS, int O, int I,
    const float* __restrict__ bnp)
{
  __shared__ u16 As[9 * 64 * 34];   // [tap][o][ch(pad34)]
  __shared__ u16 Bs[4 * 66 * 34];   // [row][col(halo)][ch(pad34)]
  __shared__ float albe[64][2];
  const int t = threadIdx.x;
  const int h0 = blockIdx.x * 2;
  const int o0 = blockIdx.y * 64;
  const int b  = blockIdx.z;
  const int w = t >> 6, l = t & 63, lq = l >> 4, lr = l & 15;
  const int wo = (w >> 1) * 32, wn = (w & 1) * 64;
  if (t < 64) {
    int o = o0 + t;
    float g = bnp[o], bt = bnp[O + o], mn = bnp[2 * O + o], vr = bnp[3 * O + o];
    float al = g * rsqrtf(vr + EPSV);
    albe[t][0] = al; albe[t][1] = bt - mn * al;
  }
  {
    int r = t >> 6, cs = (t >> 5) & 1, ch = t & 31;
    Bs[(r * 66 + (cs ? 65 : 0)) * 34 + ch] = 0;
  }
  const float* inb = In + (long)b * iBS;
  const int bch = t >> 3, bcg = (t & 7) * 8;
  f32x4 acc[2][4] = {};
  for (int c8 = 0; c8 < (I >> 5); ++c8) {
    __syncthreads();
    {
      const u16* wsrc = Wt + (long)c8 * 9 * 256 * 32;
      #pragma unroll
      for (int j = 0; j < 9; ++j) {
        int e = j * 2048 + t * 8;
        int tap = e >> 11, o = (e >> 5) & 63, ch0 = e & 31;
        uint4 vv = *(const uint4*)(wsrc + ((long)tap * 256 + o0 + o) * 32 + ch0);
        *(uint4*)&As[(tap * 64 + o) * 34 + ch0] = vv;
      }
    }
    {
      const float* cbase = inb + (long)(c8 * 32 + bch) * 4096;
      #pragma unroll
      for (int r = 0; r < 4; ++r) {
        int row = h0 - 1 + r;
        u16 hv[8];
        if (row >= 0 && row < 64) {
          float4 f0 = *(const float4*)(cbase + row * 64 + bcg);
          float4 f1 = *(const float4*)(cbase + row * 64 + bcg + 4);
          hv[0]=f2b(f0.x); hv[1]=f2b(f0.y); hv[2]=f2b(f0.z); hv[3]=f2b(f0.w);
          hv[4]=f2b(f1.x); hv[5]=f2b(f1.y); hv[6]=f2b(f1.z); hv[7]=f2b(f1.w);
        } else {
          #pragma unroll
          for (int j2 = 0; j2 < 8; ++j2) hv[j2] = 0;
        }
        #pragma unroll
        for (int j2 = 0; j2 < 8; ++j2)
          Bs[(r * 66 + bcg + 1 + j2) * 34 + bch] = hv[j2];
      }
    }
    __syncthreads();
    #pragma unroll
    for (int dy = 0; dy < 3; ++dy) {
      #pragma unroll
      for (int dx = 0; dx < 3; ++dx) {
        const int tap = dy * 3 + dx;
        bf16x8 af0 = *(const bf16x8*)&As[(tap * 64 + wo + lr) * 34 + lq * 8];
        bf16x8 af1 = *(const bf16x8*)&As[(tap * 64 + wo + 16 + lr) * 34 + lq * 8];
        #pragma unroll
        for (int j = 0; j < 4; ++j) {
          int nb = wn + j * 16;
          int rowS = (nb >> 6) + dy;
          int colS = (nb & 63) + dx;
          bf16x8 bv = *(const bf16x8*)&Bs[(rowS * 66 + colS + lr) * 34 + lq * 8];
          acc[0][j] = __builtin_amdgcn_mfma_f32_16x16x32_bf16(af0, bv, acc[0][j], 0, 0, 0);
          acc[1][j] = __builtin_amdgcn_mfma_f32_16x16x32_bf16(af1, bv, acc[1][j], 0, 0, 0);
        }
      }
    }
  }
  float* ob = Out + (long)b * oBS;
  const int n0 = h0 * 64;
  #pragma unroll
  for (int i = 0; i < 2; ++i) {
    #pragma unroll
    for (int r = 0; r < 4; ++r) {
      int ol = wo + i * 16 + lq * 4 + r;
      float al = albe[ol][0], be = albe[ol][1];
      #pragma unroll
      for (int j = 0; j < 4; ++j) {
        float vv = silu_(acc[i][j][r] * al + be);
        ob[(long)(o0 + ol) * 4096 + n0 + wn + j * 16 + lr] = vv;
      }
    }
  }
}

// ---------------- max pools ----------------

__global__ __launch_bounds__(256) void hmax5(const float* __restrict__ src, long sBS,
                                             float* __restrict__ dst, long dBS) {
  int t = blockIdx.x * 256 + threadIdx.x;
  int b = blockIdx.y;
  int n = t & 4095, c = t >> 12;
  int w = n & 63;
  const float* p = src + (long)b * sBS + (long)c * 4096 + (n - w);
  float m = p[w];
  if (w >= 1) m = fmaxf(m, p[w - 1]);
  if (w >= 2) m = fmaxf(m, p[w - 2]);
  if (w <= 62) m = fmaxf(m, p[w + 1]);
  if (w <= 61) m = fmaxf(m, p[w + 2]);
  dst[(long)b * dBS + t] = m;
}

__global__ __launch_bounds__(256) void vmax5(const float* __restrict__ src, long sBS,
                                             float* __restrict__ dst, long dBS) {
  int t = blockIdx.x * 256 + threadIdx.x;
  int b = blockIdx.y;
  int n = t & 4095, c = t >> 12;
  int h = n >> 6, w = n & 63;
  const float* p = src + (long)b * sBS + (long)c * 4096 + w;
  float m = p[h * 64];
  if (h >= 1) m = fmaxf(m, p[(h - 1) * 64]);
  if (h >= 2) m = fmaxf(m, p[(h - 2) * 64]);
  if (h <= 62) m = fmaxf(m, p[(h + 1) * 64]);
  if (h <= 61) m = fmaxf(m, p[(h + 2) * 64]);
  dst[(long)b * dBS + t] = m;
}

// ---------------- transpose (B, R, C) -> (B, C, R) ----------------

__global__ __launch_bounds__(256) void transpose_bk(const float* __restrict__ in, float* __restrict__ out,
                                                    int R, int Cc) {
  __shared__ float tile[32][33];
  int b = blockIdx.z;
  int c0 = blockIdx.x * 32, r0 = blockIdx.y * 32;
  int tx = threadIdx.x & 31, ty = threadIdx.x >> 5;
  const float* ib = in + (long)b * R * Cc;
  float* ob = out + (long)b * R * Cc;
  #pragma unroll
  for (int i = 0; i < 4; ++i) {
    int r = r0 + ty + i * 8;
    tile[ty + i * 8][tx] = ib[(long)r * Cc + c0 + tx];
  }
  __syncthreads();
  #pragma unroll
  for (int i = 0; i < 4; ++i) {
    int c = c0 + ty + i * 8;
    ob[(long)c * R + r0 + tx] = tile[tx][ty + i * 8];
  }
}

// ---------------- PAM stats: row max only, m-split x4 ----------------
__global__ __launch_bounds__(256) void pam_max(const float* __restrict__ qT, const float* __restrict__ kT,
                                               float* __restrict__ pmax) {
  __shared__ __align__(16) float kch[4][64][32];
  __shared__ float cm[4][64];
  const int t = threadIdx.x;
  const int b = blockIdx.z, ms = blockIdx.y, n0 = blockIdx.x * 64;
  const int tn = t & 63, ts = t >> 6;
  float4 qv[8];
  const float4* qrow = (const float4*)(qT + ((long)b * 4096 + n0 + tn) * 32);
  #pragma unroll
  for (int j = 0; j < 8; ++j) qv[j] = qrow[j];
  const float4* k4 = (const float4*)(kT + ((long)b * 4096 + ms * 1024) * 32);
  float mx = -1e30f;
  for (int it = 0; it < 4; ++it) {
    __syncthreads();
    #pragma unroll
    for (int j = 0; j < 8; ++j) {
      int id = j * 256 + t;
      int seg = id >> 9, rem = id & 511;
      int mrow = rem >> 3, c4 = rem & 7;
      *(float4*)&kch[seg][mrow][c4 * 4] = k4[(seg * 256 + it * 64 + mrow) * 8 + c4];
    }
    __syncthreads();
    for (int mm = 0; mm < 64; ++mm) {
      const float4* kr = (const float4*)&kch[ts][mm][0];
      float d = 0.f;
      #pragma unroll
      for (int j = 0; j < 8; ++j) {
        float4 kv = kr[j];
        d += qv[j].x * kv.x + qv[j].y * kv.y + qv[j].z * kv.z + qv[j].w * kv.w;
      }
      mx = fmaxf(mx, d);
    }
  }
  cm[ts][tn] = mx;
  __syncthreads();
  if (t < 64) {
    float M = cm[0][t];
    #pragma unroll
    for (int s = 1; s < 4; ++s) M = fmaxf(M, cm[s][t]);
    pmax[((long)ms * 2 + b) * 4096 + n0 + t] = M;
  }
}

__global__ __launch_bounds__(256) void pam_merge(const float* __restrict__ pmax, float* __restrict__ rmx) {
  int i = blockIdx.x * 256 + threadIdx.x;
  int b = i >> 12, n = i & 4095;
  float m = pmax[(long)b * 4096 + n];
  #pragma unroll
  for (int ms = 1; ms < 4; ++ms) m = fmaxf(m, pmax[((long)ms * 2 + b) * 4096 + n]);
  rmx[i] = m;
}

// ---------------- PAM attention (MFMA, self-normalizing) ----------------
__global__ __launch_bounds__(256) void pam_attn(const float* __restrict__ qT, const float* __restrict__ kT,
    const float* __restrict__ v, const float* __restrict__ rowmax, float* __restrict__ pam) {
  __shared__ u16 Qs[32 * 40];
  __shared__ u16 Ks[64 * 40];
  __shared__ u16 Vs[64 * 72];
  __shared__ u16 Ps[32 * 72];
  __shared__ float rmL[32];
  __shared__ float srow[32];
  const int t = threadIdx.x;
  const int b = blockIdx.z;
  const int n0 = blockIdx.x * 32;
  const int c0 = blockIdx.y * 64;
  const int w = t >> 6, l = t & 63, lq = l >> 4, lr = l & 15;
  const int wn = w & 1, wc = w >> 1;
  {
    int nn = t >> 3, kq = (t & 7) * 4;
    float4 f = *(const float4*)(qT + ((long)b * 4096 + n0 + nn) * 32 + kq);
    ushort4 u; u.x = f2b(f.x); u.y = f2b(f.y); u.z = f2b(f.z); u.w = f2b(f.w);
    *(ushort4*)&Qs[nn * 40 + kq] = u;
    if (t < 32) { rmL[t] = rowmax[(long)b * 4096 + n0 + t] * LOG2E; srow[t] = 0.f; }
  }
  __syncthreads();
  bf16x8 qf = *(const bf16x8*)&Qs[(wn * 16 + lr) * 40 + lq * 8];
  float rm4[4];
  #pragma unroll
  for (int r = 0; r < 4; ++r) rm4[r] = rmL[wn * 16 + lq * 4 + r];
  float sp[4] = {0.f, 0.f, 0.f, 0.f};
  f32x4 acc[2] = {};
  const int kmm = t >> 2, kkq = (t & 3) * 8;
  const int vcc = t >> 2, vmq = (t & 3) * 16;
  for (int m0 = 0; m0 < 4096; m0 += 64) {
    __syncthreads();
    {
      const float* src = kT + ((long)b * 4096 + m0 + kmm) * 32 + kkq;
      float4 f0 = *(const float4*)src, f1 = *(const float4*)(src + 4);
      ushort4 u0, u1;
      u0.x=f2b(f0.x); u0.y=f2b(f0.y); u0.z=f2b(f0.z); u0.w=f2b(f0.w);
      u1.x=f2b(f1.x); u1.y=f2b(f1.y); u1.z=f2b(f1.z); u1.w=f2b(f1.w);
      *(ushort4*)&Ks[kmm * 40 + kkq] = u0;
      *(ushort4*)&Ks[kmm * 40 + kkq + 4] = u1;
    }
    {
      const float* src = v + ((long)b * 256 + c0 + vcc) * 4096 + m0 + vmq;
      union { u16 h[16]; uint4 q[2]; } tb;
      #pragma unroll
      for (int i = 0; i < 4; ++i) {
        float4 f = *(const float4*)(src + i * 4);
        tb.h[i*4+0]=f2b(f.x); tb.h[i*4+1]=f2b(f.y); tb.h[i*4+2]=f2b(f.z); tb.h[i*4+3]=f2b(f.w);
      }
      *(uint4*)&Vs[vcc * 72 + vmq] = tb.q[0];
      *(uint4*)&Vs[vcc * 72 + vmq + 8] = tb.q[1];
    }
    __syncthreads();
    #pragma unroll
    for (int s = 0; s < 2; ++s) {
      int msub = wc * 2 + s;
      bf16x8 kf = *(const bf16x8*)&Ks[(msub * 16 + lr) * 40 + lq * 8];
      f32x4 S = {};
      S = __builtin_amdgcn_mfma_f32_16x16x32_bf16(qf, kf, S, 0, 0, 0);
      #pragma unroll
      for (int r = 0; r < 4; ++r) {
        float p = exp2f(S[r] * LOG2E - rm4[r]);
        u16 pb = f2b(p);
        sp[r] += b2f(pb);
        Ps[(wn * 16 + lq * 4 + r) * 72 + msub * 16 + lr] = pb;
      }
    }
    __syncthreads();
    #pragma unroll
    for (int ks = 0; ks < 2; ++ks) {
      bf16x8 pf = *(const bf16x8*)&Ps[(wn * 16 + lr) * 72 + ks * 32 + lq * 8];
      #pragma unroll
      for (int it = 0; it < 2; ++it) {
        bf16x8 vf = *(const bf16x8*)&Vs[(wc * 32 + it * 16 + lr) * 72 + ks * 32 + lq * 8];
        acc[it] = __builtin_amdgcn_mfma_f32_16x16x32_bf16(vf, pf, acc[it], 0, 0, 0);
      }
    }
  }
  #pragma unroll
  for (int r = 0; r < 4; ++r) atomicAdd(&srow[wn * 16 + lq * 4 + r], sp[r]);
  __syncthreads();
  float inv = 1.f / srow[wn * 16 + lr];
  float* ob = pam + (long)b * (256L * 4096) + n0 + wn * 16 + lr;
  #pragma unroll
  for (int it = 0; it < 2; ++it)
    #pragma unroll
    for (int r = 0; r < 4; ++r)
      ob[(long)(c0 + wc * 32 + it * 16 + lq * 4 + r) * 4096] = acc[it][r] * inv;
}

// ---------------- CAM ----------------

__global__ __launch_bounds__(256) void fillz(float* __restrict__ p, int n) {
  int i = blockIdx.x * 256 + threadIdx.x;
  if (i < n) p[i] = 0.f;
}

__global__ __launch_bounds__(256) void cam_e(const float* __restrict__ f, float* __restrict__ e) {
  __shared__ __align__(16) float fc[32][68];
  __shared__ __align__(16) float fd[32][68];
  const int c0 = blockIdx.x * 64, d0 = blockIdx.y * 64;
  const int bz = blockIdx.z;
  const int b = bz >> 3, ns = bz & 7;
  const int t = threadIdx.x;
  const int tx = t & 15, ty = t >> 4;
  float acc[4][4] = {};
  const float* fb = f + (long)b * 1048576;
  for (int nc = 0; nc < 16; ++nc) {
    int nb = ns * 512 + nc * 32;
    __syncthreads();
    #pragma unroll
    for (int i = 0; i < 2; ++i) {
      int id = i * 256 + t;
      int row = id >> 3, c4 = id & 7;
      float4 v = *(const float4*)(fb + (long)(c0 + row) * 4096 + nb + c4 * 4);
      fc[c4*4+0][row] = v.x; fc[c4*4+1][row] = v.y; fc[c4*4+2][row] = v.z; fc[c4*4+3][row] = v.w;
      float4 u = *(const float4*)(fb + (long)(d0 + row) * 4096 + nb + c4 * 4);
      fd[c4*4+0][row] = u.x; fd[c4*4+1][row] = u.y; fd[c4*4+2][row] = u.z; fd[c4*4+3][row] = u.w;
    }
    __syncthreads();
    #pragma unroll
    for (int nn = 0; nn < 32; ++nn) {
      float4 a = *(const float4*)&fc[nn][ty * 4];
      float4 bq = *(const float4*)&fd[nn][tx * 4];
      float aa[4] = {a.x, a.y, a.z, a.w};
      float bb[4] = {bq.x, bq.y, bq.z, bq.w};
      #pragma unroll
      for (int i = 0; i < 4; ++i)
        #pragma unroll
        for (int j = 0; j < 4; ++j) acc[i][j] += aa[i] * bb[j];
    }
  }
  #pragma unroll
  for (int i = 0; i < 4; ++i)
    #pragma unroll
    for (int j = 0; j < 4; ++j)
      atomicAdd(&e[((long)b << 16) + (long)(c0 + ty * 4 + i) * 256 + d0 + tx * 4 + j], acc[i][j]);
}

__global__ __launch_bounds__(256) void cam_softmax(const float* __restrict__ e, u16* __restrict__ attn) {
  __shared__ float red[256];
  int c = blockIdx.x, b = blockIdx.y, t = threadIdx.x;
  const float* row = e + ((long)b << 16) + (long)c * 256;
  float v = row[t];
  red[t] = v; __syncthreads();
  for (int s = 128; s > 0; s >>= 1) { if (t < s) red[t] = fminf(red[t], red[t + s]); __syncthreads(); }
  float emin = red[0]; __syncthreads();
  float ex = exp2f(LOG2E * (emin - v));
  red[t] = ex; __syncthreads();
  for (int s = 128; s > 0; s >>= 1) { if (t < s) red[t] += red[t + s]; __syncthreads(); }
  float inv = 1.f / red[0];
  attn[((long)b << 16) + (long)c * 256 + t] = f2b(ex * inv);
}

// ---------------- final combine ----------------

__global__ __launch_bounds__(256) void combine(const float* __restrict__ res, const float* __restrict__ pam,
    const float* __restrict__ cam, const float* __restrict__ gp,
    void* __restrict__ outp, const u16* __restrict__ xp) {
  __shared__ int sflag;
  if (threadIdx.x == 0) sflag = detect_fp32(xp);
  __syncthreads();
  int idx = blockIdx.x * 256 + threadIdx.x;
  float g1 = gp[0], g2 = gp[1];
  float v = 3.f * res[idx] + g1 * pam[idx] + g2 * cam[idx];
  if (sflag) ((float*)outp)[idx] = v;
  else       ((u16*)outp)[idx] = f2b(v);
}

// ---------------- launch ----------------

extern "C" void kernel_launch(void* const* d_in, const int* in_sizes, int n_in,
                              void* d_out, int out_size, void* d_ws, size_t ws_size,
                              hipStream_t stream)
{
  (void)out_size; (void)ws_size; (void)n_in;
  float* ws = (float*)d_ws;
  const long CN = 256L * 4096;

  float* A  = ws;            // r -> res
  float* Bp = ws + 2 * CN;   // x_f32 -> s1out -> pool tmp -> s5out -> v
  float* Cp = ws + 4 * CN;   // CoordAtt smalls -> s3out
  float* D  = ws + 6 * CN;   // cat(8CN) -> {y12, attn smalls} -> {pam, cam}
  const long WFo = 14 * CN;

  float* yin = Cp;
  float* ybn = Cp + 65536;
  float* ah  = Cp + 67584;
  float* aw_ = Cp + 100352;

  float* q     = D + 4 * CN;
  float* k     = q + 262144;
  float* qT    = q + 524288;
  float* kT    = q + 786432;
  float* pmax  = q + 1048576;
  float* rmx   = q + 1081344;
  float* e     = q + 1089536;
  u16*   attnc = (u16*)(q + 1220608);

  float* res = A;
  float* v   = Bp;
  float* pam = D;
  float* cam = D + 2 * CN;

  // ---- input conversion ----
  ConvArgs ca;
  long fOff[30], hOff[30];
  long hcur = 0;
  {
    long cum = 0, fcur = WFo;
    for (int i = 0; i < 30; ++i) {
      ca.src[i] = d_in[i];
      int h = (i == 8 || i == 10 || i == 14 || i == 16 || i == 20 || i == 26) ? 1 : 0;
      ca.mode[i] = h;
      if (i == 0) { ca.dst[i] = 2 * CN; fOff[i] = 2 * CN; }
      else if (h) { ca.dst[i] = hcur; hOff[i] = hcur; hcur += in_sizes[i]; }
      else        { ca.dst[i] = fcur; fOff[i] = fcur; fcur += in_sizes[i]; }
      cum += in_sizes[i];
      ca.end[i] = (int)cum;
    }
  }
  long fTotal = WFo;
  for (int i = 1; i < 30; ++i) if (!ca.mode[i]) fTotal = (fOff[i] + in_sizes[i] > fTotal) ? fOff[i] + in_sizes[i] : fTotal;
  u16* wsH = (u16*)(ws + fTotal);
  // conv3 transformed weights appended to bf16 staging
  long wt3aOff = hcur;
  long wt3bOff = hcur + 589824;
  u16* wt3a = wsH + wt3aOff;
  u16* wt3b = wsH + wt3bOff;
  int total = ca.end[29];
  convert_all<<<dim3((total + 255) / 256), dim3(256), 0, stream>>>(ca, ws, wsH, (const u16*)d_in[0], total);

  float* xf    = Bp;
  float* ca_w1 = ws + fOff[1];
  float* ca_b1 = ws + fOff[2];
  float* ca_bn = ws + fOff[3];
  float* ca_wh = ws + fOff[4];
  float* ca_bh = ws + fOff[5];
  float* ca_ww = ws + fOff[6];
  float* ca_bw = ws + fOff[7];
  u16*   s1_w  = wsH + hOff[8];   float* s1_bn = ws + fOff[9];
  u16*   s2_w  = wsH + hOff[10];  float* s2_bn = ws + fOff[11];
  float* s3_wf = ws + fOff[12];   float* s3_bn = ws + fOff[13];
  u16*   s4_w  = wsH + hOff[14];  float* s4_bn = ws + fOff[15];
  u16*   s5_w  = wsH + hOff[16];  float* s5_bn = ws + fOff[17];
  float* s6_wf = ws + fOff[18];   float* s6_bn = ws + fOff[19];
  u16*   s7_w  = wsH + hOff[20];  float* s7_bn = ws + fOff[21];
  float* pq_w  = ws + fOff[22];   float* pq_b  = ws + fOff[23];
  float* pk_w  = ws + fOff[24];   float* pk_b  = ws + fOff[25];
  u16*   pv_w  = wsH + hOff[26];  float* pv_b  = ws + fOff[27];
  float* gammas = ws + fOff[28];

  w3t<<<dim3(2304), dim3(256), 0, stream>>>(s3_wf, wt3a);
  w3t<<<dim3(2304), dim3(256), 0, stream>>>(s6_wf, wt3b);

  // ---- CoordAtt ----
  plane_means<<<dim3(512), dim3(256), 0, stream>>>(xf, yin);
  ca_conv1<<<dim3(2), dim3(128), 0, stream>>>(yin, ca_w1, ca_b1, ca_bn, ybn);
  ca_gate<<<dim3(256, 2), dim3(128), 0, stream>>>(ybn, ca_wh, ca_bh, ca_ww, ca_bw, ah, aw_);
  apply_ca<<<dim3(8192), dim3(256), 0, stream>>>(xf, ah, aw_, A);

  // ---- SPPCSPC ----
  mfma_cbs<1><<<dim3(32, 4, 2), dim3(256), 0, stream>>>(s1_w, 0, A, CN, Bp, CN, 256, 256, 4096, s1_bn, nullptr);
  conv3_mfma<<<dim3(32, 4, 2), dim3(256), 0, stream>>>(wt3a, Bp, CN, Cp, CN, 256, 256, s3_bn);
  mfma_cbs<1><<<dim3(32, 4, 2), dim3(256), 0, stream>>>(s4_w, 0, Cp, CN, D, 4 * CN, 256, 256, 4096, s4_bn, nullptr);

  hmax5<<<dim3(4096, 2), dim3(256), 0, stream>>>(D, 4 * CN, Bp, CN);
  vmax5<<<dim3(4096, 2), dim3(256), 0, stream>>>(Bp, CN, D + CN, 4 * CN);
  hmax5<<<dim3(4096, 2), dim3(256), 0, stream>>>(D + CN, 4 * CN, Bp, CN);
  vmax5<<<dim3(4096, 2), dim3(256), 0, stream>>>(Bp, CN, D + 2 * CN, 4 * CN);
  hmax5<<<dim3(4096, 2), dim3(256), 0, stream>>>(D + 2 * CN, 4 * CN, Bp, CN);
  vmax5<<<dim3(4096, 2), dim3(256), 0, stream>>>(Bp, CN, D + 3 * CN, 4 * CN);

  mfma_cbs<1><<<dim3(32, 4, 2), dim3(256), 0, stream>>>(s5_w, 0, D, 4 * CN, Bp, CN, 256, 1024, 4096, s5_bn, nullptr);
  conv3_mfma<<<dim3(32, 4, 2), dim3(256), 0, stream>>>(wt3b, Bp, CN, D, 2 * CN, 256, 256, s6_bn);
  mfma_cbs<1><<<dim3(32, 4, 2), dim3(256), 0, stream>>>(s2_w, 0, A, CN, D + CN, 2 * CN, 256, 256, 4096, s2_bn, nullptr);
  mfma_cbs<1><<<dim3(32, 4, 2), dim3(256), 0, stream>>>(s7_w, 0, D, 2 * CN, A, CN, 256, 512, 4096, s7_bn, nullptr);

  // ---- PAM ----
  gemm_cbs<0><<<dim3(64, 1, 2), dim3(256), 0, stream>>>(pq_w, 0, res, CN, q, 131072, 32, 256, 4096, nullptr, pq_b);
  gemm_cbs<0><<<dim3(64, 1, 2), dim3(256), 0, stream>>>(pk_w, 0, res, CN, k, 131072, 32, 256, 4096, nullptr, pk_b);
  mfma_cbs<0><<<dim3(32, 4, 2), dim3(256), 0, stream>>>(pv_w, 0, res, CN, v, CN, 256, 256, 4096, nullptr, pv_b);

  transpose_bk<<<dim3(128, 1, 2), dim3(256), 0, stream>>>(q, qT, 32, 4096);
  transpose_bk<<<dim3(128, 1, 2), dim3(256), 0, stream>>>(k, kT, 32, 4096);

  pam_max<<<dim3(64, 4, 2), dim3(256), 0, stream>>>(qT, kT, pmax);
  pam_merge<<<dim3(32), dim3(256), 0, stream>>>(pmax, rmx);
  pam_attn<<<dim3(128, 4, 2), dim3(256), 0, stream>>>(qT, kT, v, rmx, pam);

  // ---- CAM ----
  fillz<<<dim3(512), dim3(256), 0, stream>>>(e, 131072);
  cam_e<<<dim3(4, 4, 16), dim3(256), 0, stream>>>(res, e);
  cam_softmax<<<dim3(256, 2), dim3(256), 0, stream>>>(e, attnc);
  mfma_cbs<0><<<dim3(32, 4, 2), dim3(256), 0, stream>>>(attnc, 65536, res, CN, cam, CN, 256, 256, 4096, nullptr, nullptr);

  // ---- combine ----
  combine<<<dim3(8192), dim3(256), 0, stream>>>(res, pam, cam, gammas, d_out, (const u16*)d_in[0]);
}

// Round 6
// 726.339 us; speedup vs baseline: 3.1133x; 1.1392x over previous
//
#include <hip/hip_runtime.h>

typedef unsigned short u16;
typedef __attribute__((ext_vector_type(8))) short bf16x8;
typedef __attribute__((ext_vector_type(4))) float f32x4;
#define EPSV 1e-5f
#define LOG2E 1.4426950408889634f

__device__ __forceinline__ float b2f(u16 u) {
  union { float f; unsigned int i; } v; v.i = ((unsigned int)u) << 16; return v.f;
}
__device__ __forceinline__ u16 f2b(float f) {
  union { float f; unsigned int i; } v; v.f = f;
  unsigned int r = v.i + 0x7FFFu + ((v.i >> 16) & 1u);
  return (u16)(r >> 16);
}
__device__ __forceinline__ float silu_(float z) { return z / (1.f + exp2f(-LOG2E * z)); }

// Detect whether raw inputs are fp32 (1) or bf16 (0) by probing x.
__device__ int detect_fp32(const u16* __restrict__ xp) {
  int wild = 0, zeros = 0;
  for (int i = 0; i < 256; i += 2) {
    u16 u = xp[i];
    int e = (u >> 7) & 0xff;
    if (e != 0 && (e < 90 || e > 160)) wild++;
    if (u == 0) zeros++;
  }
  return (wild > 16 || zeros > 64) ? 1 : 0;
}

// ---------------- input conversion ----------------

struct ConvArgs {
  const void* src[30];
  long dst[30];
  int end[30];
  int mode[30];
};

__global__ __launch_bounds__(256) void convert_all(ConvArgs a, float* __restrict__ wsF,
                                                   u16* __restrict__ wsH,
                                                   const u16* __restrict__ xp, int total) {
  __shared__ int sflag;
  if (threadIdx.x == 0) sflag = detect_fp32(xp);
  __syncthreads();
  const int flag = sflag;
  int gid = blockIdx.x * 256 + threadIdx.x;
  if (gid >= total) return;
  #pragma unroll 1
  for (int s = 0; s < 30; ++s) {
    if (gid < a.end[s]) {
      int idx = gid - (s ? a.end[s - 1] : 0);
      if (a.mode[s] == 0) {
        float v = flag ? ((const float*)a.src[s])[idx] : b2f(((const u16*)a.src[s])[idx]);
        wsF[a.dst[s] + idx] = v;
      } else {
        u16 h = flag ? f2b(((const float*)a.src[s])[idx]) : ((const u16*)a.src[s])[idx];
        wsH[a.dst[s] + idx] = h;
      }
      return;
    }
  }
}

// conv3 weight transform: fp32 W[o][I][3][3] -> bf16 Wt[I/32][tap][256o][32ch]
__global__ __launch_bounds__(256) void w3t(const float* __restrict__ Wsrc, u16* __restrict__ Wdst) {
  int idx = blockIdx.x * 256 + threadIdx.x;
  int ch = idx & 31;
  int o  = (idx >> 5) & 255;
  int tap = (idx >> 13) % 9;
  int c8 = (idx >> 13) / 9;
  int i = c8 * 32 + ch;
  Wdst[idx] = f2b(Wsrc[((long)o * 256 + i) * 9 + tap]);
}

// ---------------- CoordAtt ----------------

__global__ __launch_bounds__(256) void plane_means(const float* __restrict__ x, float* __restrict__ yin) {
  __shared__ float pl[4096];
  int bc = blockIdx.x, t = threadIdx.x;
  const float* xp = x + (long)bc * 4096;
  for (int j = 0; j < 16; ++j) { int id = j * 256 + t; pl[id] = xp[id]; }
  __syncthreads();
  if (t < 64) {
    float s = 0.f;
    for (int w = 0; w < 64; ++w) s += pl[t * 64 + w];
    yin[(long)bc * 128 + t] = s * (1.f / 64.f);
  } else if (t < 128) {
    int w = t - 64; float s = 0.f;
    for (int h = 0; h < 64; ++h) s += pl[h * 64 + w];
    yin[(long)bc * 128 + 64 + w] = s * (1.f / 64.f);
  }
}

__global__ __launch_bounds__(128) void ca_conv1(const float* __restrict__ yin, const float* __restrict__ w1,
                                                const float* __restrict__ b1, const float* __restrict__ bnp,
                                                float* __restrict__ ybn) {
  int b = blockIdx.x, p = threadIdx.x;
  float acc[8] = {0.f,0.f,0.f,0.f,0.f,0.f,0.f,0.f};
  for (int c = 0; c < 256; ++c) {
    float yv = yin[((long)b * 256 + c) * 128 + p];
    #pragma unroll
    for (int o = 0; o < 8; ++o) acc[o] += w1[o * 256 + c] * yv;
  }
  #pragma unroll
  for (int o = 0; o < 8; ++o) {
    float z = acc[o] + b1[o];
    float g = bnp[o], bt = bnp[8 + o], mn = bnp[16 + o], vr = bnp[24 + o];
    float s = g * rsqrtf(vr + EPSV);
    z = z * s + (bt - mn * s);
    float hs = fminf(fmaxf(z + 3.f, 0.f), 6.f) * (1.f / 6.f);
    ybn[((long)b * 8 + o) * 128 + p] = z * hs;
  }
}

__global__ __launch_bounds__(128) void ca_gate(const float* __restrict__ ybn,
    const float* __restrict__ wh, const float* __restrict__ bh,
    const float* __restrict__ ww, const float* __restrict__ bw,
    float* __restrict__ ah, float* __restrict__ aw_) {
  int c = blockIdx.x, b = blockIdx.y, t = threadIdx.x;
  if (t < 64) {
    float d = 0.f;
    #pragma unroll
    for (int o = 0; o < 8; ++o) d += wh[c * 8 + o] * ybn[((long)b * 8 + o) * 128 + t];
    d += bh[c];
    ah[((long)b * 256 + c) * 64 + t] = 1.f / (1.f + exp2f(-LOG2E * d));
  } else {
    int w = t - 64;
    float d = 0.f;
    #pragma unroll
    for (int o = 0; o < 8; ++o) d += ww[c * 8 + o] * ybn[((long)b * 8 + o) * 128 + 64 + w];
    d += bw[c];
    aw_[((long)b * 256 + c) * 64 + w] = 1.f / (1.f + exp2f(-LOG2E * d));
  }
}

__global__ __launch_bounds__(256) void apply_ca(const float* __restrict__ x, const float* __restrict__ ah,
                                                const float* __restrict__ aw_, float* __restrict__ r) {
  int idx = blockIdx.x * 256 + threadIdx.x;
  int n = idx & 4095, bc = idx >> 12;
  int h = n >> 6, w = n & 63;
  r[idx] = x[idx] * ah[bc * 64 + h] * aw_[bc * 64 + w];
}

// ---------------- VALU GEMM (O=32 q/k projections) ----------------

template<int ACT>
__global__ __launch_bounds__(256) void gemm_cbs(
    const float* __restrict__ A, long aBS,
    const float* __restrict__ In, long bBS,
    float* __restrict__ Out, long oBS,
    int O, int K, int N,
    const float* __restrict__ bnp, const float* __restrict__ bias)
{
  __shared__ __align__(16) float As[8][128];
  __shared__ __align__(16) float Bs[8][64];
  const int t = threadIdx.x;
  const int n0 = blockIdx.x * 64;
  const int o0 = blockIdx.y * 128;
  const int b  = blockIdx.z;
  const int tx = t & 15, ty = t >> 4;
  const int ao = t >> 1, ak = (t & 1) * 4;
  const int bk = t >> 5, bn_ = (t & 31) * 2;
  float acc[8][4] = {};
  const float* inb = In + (long)b * bBS + n0;
  const float* Ab = A + (long)b * aBS;
  for (int kc = 0; kc < K; kc += 8) {
    __syncthreads();
    float av[4] = {0.f, 0.f, 0.f, 0.f};
    if (o0 + ao < O) {
      float4 u = *(const float4*)(Ab + (long)(o0 + ao) * K + kc + ak);
      av[0] = u.x; av[1] = u.y; av[2] = u.z; av[3] = u.w;
    }
    #pragma unroll
    for (int j = 0; j < 4; ++j) As[ak + j][ao] = av[j];
    float2 bv = *(const float2*)(inb + (long)(kc + bk) * N + bn_);
    Bs[bk][bn_] = bv.x; Bs[bk][bn_ + 1] = bv.y;
    __syncthreads();
    #pragma unroll
    for (int kk = 0; kk < 8; ++kk) {
      float4 a0 = *(const float4*)&As[kk][ty * 8];
      float4 a1 = *(const float4*)&As[kk][ty * 8 + 4];
      float4 bq = *(const float4*)&Bs[kk][tx * 4];
      float aa[8] = {a0.x, a0.y, a0.z, a0.w, a1.x, a1.y, a1.z, a1.w};
      float bb[4] = {bq.x, bq.y, bq.z, bq.w};
      #pragma unroll
      for (int i = 0; i < 8; ++i)
        #pragma unroll
        for (int j = 0; j < 4; ++j) acc[i][j] += aa[i] * bb[j];
    }
  }
  float* ob = Out + (long)b * oBS + n0 + tx * 4;
  #pragma unroll
  for (int i = 0; i < 8; ++i) {
    int o = o0 + ty * 8 + i;
    if (o < O) {
      float al = 1.f, be = 0.f;
      if (bnp) {
        float g = bnp[o], bt = bnp[O + o], mn = bnp[2 * O + o], vr = bnp[3 * O + o];
        al = g * rsqrtf(vr + EPSV);
        be = bt - mn * al;
      }
      if (bias) be += bias[o];
      float4 rv;
      rv.x = acc[i][0] * al + be;
      rv.y = acc[i][1] * al + be;
      rv.z = acc[i][2] * al + be;
      rv.w = acc[i][3] * al + be;
      if (ACT) { rv.x = silu_(rv.x); rv.y = silu_(rv.y); rv.z = silu_(rv.z); rv.w = silu_(rv.w); }
      *(float4*)(ob + (long)o * N) = rv;
    }
  }
}

// ---------------- MFMA 1x1 conv; OUTH=1 -> bf16 output ----------------

template<int ACT, int OUTH>
__global__ __launch_bounds__(256) void mfma_cbs(
    const u16* __restrict__ Wbf, long aBS,
    const float* __restrict__ In, long bBS,
    float* __restrict__ Out, long oBS,
    int O, int K, int N,
    const float* __restrict__ bnp, const float* __restrict__ bias)
{
  __shared__ u16 As[64 * 40];
  __shared__ u16 Bs[128 * 40];
  __shared__ float albe[64][2];
  const int t = threadIdx.x;
  const int n0 = blockIdx.x * 128;
  const int o0 = blockIdx.y * 64;
  const int b  = blockIdx.z;
  const int w = t >> 6, l = t & 63, lq = l >> 4, lr = l & 15;
  const int wo = (w >> 1) * 32, wn = (w & 1) * 64;
  if (t < 64) {
    int o = o0 + t;
    float al = 1.f, be = 0.f;
    if (bnp) {
      float g = bnp[o], bt = bnp[O + o], mn = bnp[2 * O + o], vr = bnp[3 * O + o];
      al = g * rsqrtf(vr + EPSV); be = bt - mn * al;
    }
    if (bias) be += bias[o];
    albe[t][0] = al; albe[t][1] = be;
  }
  const u16* Ab = Wbf + (long)b * aBS;
  const float* inb = In + (long)b * bBS + n0;
  const int ao = t >> 2, akq = (t & 3) * 8;
  const int bk = t >> 3, bc8 = t & 7;
  f32x4 acc[2][4] = {};
  for (int kc = 0; kc < K; kc += 32) {
    __syncthreads();
    *(uint4*)&As[ao * 40 + akq] = *(const uint4*)(Ab + (long)(o0 + ao) * K + kc + akq);
    const float* src = inb + (long)(kc + bk) * N + bc8 * 4;
    u16 tmp[16];
    #pragma unroll
    for (int i = 0; i < 4; ++i) {
      float4 f = *(const float4*)(src + i * 32);
      tmp[i*4+0] = f2b(f.x); tmp[i*4+1] = f2b(f.y); tmp[i*4+2] = f2b(f.z); tmp[i*4+3] = f2b(f.w);
    }
    #pragma unroll
    for (int i = 0; i < 4; ++i) {
      int n = bc8 * 4 + i * 32;
      #pragma unroll
      for (int j = 0; j < 4; ++j) Bs[(n + j) * 40 + bk] = tmp[i * 4 + j];
    }
    __syncthreads();
    bf16x8 af[2], bfv[4];
    #pragma unroll
    for (int i = 0; i < 2; ++i) af[i] = *(const bf16x8*)&As[(wo + i * 16 + lr) * 40 + lq * 8];
    #pragma unroll
    for (int j = 0; j < 4; ++j) bfv[j] = *(const bf16x8*)&Bs[(wn + j * 16 + lr) * 40 + lq * 8];
    #pragma unroll
    for (int i = 0; i < 2; ++i)
      #pragma unroll
      for (int j = 0; j < 4; ++j)
        acc[i][j] = __builtin_amdgcn_mfma_f32_16x16x32_bf16(af[i], bfv[j], acc[i][j], 0, 0, 0);
  }
  float* ob = Out + (long)b * oBS;
  u16* obh = (u16*)Out + (long)b * oBS;
  #pragma unroll
  for (int i = 0; i < 2; ++i) {
    #pragma unroll
    for (int r = 0; r < 4; ++r) {
      int ol = wo + i * 16 + lq * 4 + r;
      float al = albe[ol][0], be = albe[ol][1];
      #pragma unroll
      for (int j = 0; j < 4; ++j) {
        float vv = acc[i][j][r] * al + be;
        if (ACT) vv = silu_(vv);
        if (OUTH) obh[(long)(o0 + ol) * N + n0 + wn + j * 16 + lr] = f2b(vv);
        else      ob[(long)(o0 + ol) * N + n0 + wn + j * 16 + lr] = vv;
      }
    }
  }
}

// ---------------- MFMA 3x3 conv (implicit GEMM over 9 shifted taps) ----------------
__global__ __launch_bounds__(256) void conv3_mfma(
    const u16* __restrict__ Wt,
    const float* __restrict__ In, long iBS,
    float* __restrict__ Out, long oBS, int O, int I,
    const float* __restrict__ bnp)
{
  __shared__ u16 As[9 * 64 * 34];
  __shared__ u16 Bs[4 * 66 * 34];
  __shared__ float albe[64][2];
  const int t = threadIdx.x;
  const int h0 = blockIdx.x * 2;
  const int o0 = blockIdx.y * 64;
  const int b  = blockIdx.z;
  const int w = t >> 6, l = t & 63, lq = l >> 4, lr = l & 15;
  const int wo = (w >> 1) * 32, wn = (w & 1) * 64;
  if (t < 64) {
    int o = o0 + t;
    float g = bnp[o], bt = bnp[O + o], mn = bnp[2 * O + o], vr = bnp[3 * O + o];
    float al = g * rsqrtf(vr + EPSV);
    albe[t][0] = al; albe[t][1] = bt - mn * al;
  }
  {
    int r = t >> 6, cs = (t >> 5) & 1, ch = t & 31;
    Bs[(r * 66 + (cs ? 65 : 0)) * 34 + ch] = 0;
  }
  const float* inb = In + (long)b * iBS;
  const int bch = t >> 3, bcg = (t & 7) * 8;
  f32x4 acc[2][4] = {};
  for (int c8 = 0; c8 < (I >> 5); ++c8) {
    __syncthreads();
    {
      const u16* wsrc = Wt + (long)c8 * 9 * 256 * 32;
      #pragma unroll
      for (int j = 0; j < 9; ++j) {
        int e = j * 2048 + t * 8;
        int tap = e >> 11, o = (e >> 5) & 63, ch0 = e & 31;
        uint4 vv = *(const uint4*)(wsrc + ((long)tap * 256 + o0 + o) * 32 + ch0);
        *(uint4*)&As[(tap * 64 + o) * 34 + ch0] = vv;
      }
    }
    {
      const float* cbase = inb + (long)(c8 * 32 + bch) * 4096;
      #pragma unroll
      for (int r = 0; r < 4; ++r) {
        int row = h0 - 1 + r;
        u16 hv[8];
        if (row >= 0 && row < 64) {
          float4 f0 = *(const float4*)(cbase + row * 64 + bcg);
          float4 f1 = *(const float4*)(cbase + row * 64 + bcg + 4);
          hv[0]=f2b(f0.x); hv[1]=f2b(f0.y); hv[2]=f2b(f0.z); hv[3]=f2b(f0.w);
          hv[4]=f2b(f1.x); hv[5]=f2b(f1.y); hv[6]=f2b(f1.z); hv[7]=f2b(f1.w);
        } else {
          #pragma unroll
          for (int j2 = 0; j2 < 8; ++j2) hv[j2] = 0;
        }
        #pragma unroll
        for (int j2 = 0; j2 < 8; ++j2)
          Bs[(r * 66 + bcg + 1 + j2) * 34 + bch] = hv[j2];
      }
    }
    __syncthreads();
    #pragma unroll
    for (int dy = 0; dy < 3; ++dy) {
      #pragma unroll
      for (int dx = 0; dx < 3; ++dx) {
        const int tap = dy * 3 + dx;
        bf16x8 af0 = *(const bf16x8*)&As[(tap * 64 + wo + lr) * 34 + lq * 8];
        bf16x8 af1 = *(const bf16x8*)&As[(tap * 64 + wo + 16 + lr) * 34 + lq * 8];
        #pragma unroll
        for (int j = 0; j < 4; ++j) {
          int nb = wn + j * 16;
          int rowS = (nb >> 6) + dy;
          int colS = (nb & 63) + dx;
          bf16x8 bv = *(const bf16x8*)&Bs[(rowS * 66 + colS + lr) * 34 + lq * 8];
          acc[0][j] = __builtin_amdgcn_mfma_f32_16x16x32_bf16(af0, bv, acc[0][j], 0, 0, 0);
          acc[1][j] = __builtin_amdgcn_mfma_f32_16x16x32_bf16(af1, bv, acc[1][j], 0, 0, 0);
        }
      }
    }
  }
  float* ob = Out + (long)b * oBS;
  const int n0 = h0 * 64;
  #pragma unroll
  for (int i = 0; i < 2; ++i) {
    #pragma unroll
    for (int r = 0; r < 4; ++r) {
      int ol = wo + i * 16 + lq * 4 + r;
      float al = albe[ol][0], be = albe[ol][1];
      #pragma unroll
      for (int j = 0; j < 4; ++j) {
        float vv = silu_(acc[i][j][r] * al + be);
        ob[(long)(o0 + ol) * 4096 + n0 + wn + j * 16 + lr] = vv;
      }
    }
  }
}

// ---------------- max pools ----------------

__global__ __launch_bounds__(256) void hmax5(const float* __restrict__ src, long sBS,
                                             float* __restrict__ dst, long dBS) {
  int t = blockIdx.x * 256 + threadIdx.x;
  int b = blockIdx.y;
  int n = t & 4095, c = t >> 12;
  int w = n & 63;
  const float* p = src + (long)b * sBS + (long)c * 4096 + (n - w);
  float m = p[w];
  if (w >= 1) m = fmaxf(m, p[w - 1]);
  if (w >= 2) m = fmaxf(m, p[w - 2]);
  if (w <= 62) m = fmaxf(m, p[w + 1]);
  if (w <= 61) m = fmaxf(m, p[w + 2]);
  dst[(long)b * dBS + t] = m;
}

__global__ __launch_bounds__(256) void vmax5(const float* __restrict__ src, long sBS,
                                             float* __restrict__ dst, long dBS) {
  int t = blockIdx.x * 256 + threadIdx.x;
  int b = blockIdx.y;
  int n = t & 4095, c = t >> 12;
  int h = n >> 6, w = n & 63;
  const float* p = src + (long)b * sBS + (long)c * 4096 + w;
  float m = p[h * 64];
  if (h >= 1) m = fmaxf(m, p[(h - 1) * 64]);
  if (h >= 2) m = fmaxf(m, p[(h - 2) * 64]);
  if (h <= 62) m = fmaxf(m, p[(h + 1) * 64]);
  if (h <= 61) m = fmaxf(m, p[(h + 2) * 64]);
  dst[(long)b * dBS + t] = m;
}

// ---------------- transpose (B, R, 4096) fp32 -> (B, 4096, R) bf16 ----------------

__global__ __launch_bounds__(256) void transpose_h(const float* __restrict__ in, u16* __restrict__ out,
                                                   int R, int Cc) {
  __shared__ float tile[32][33];
  int b = blockIdx.z;
  int c0 = blockIdx.x * 32, r0 = blockIdx.y * 32;
  int tx = threadIdx.x & 31, ty = threadIdx.x >> 5;
  const float* ib = in + (long)b * R * Cc;
  u16* ob = out + (long)b * R * Cc;
  #pragma unroll
  for (int i = 0; i < 4; ++i) {
    int r = r0 + ty + i * 8;
    tile[ty + i * 8][tx] = ib[(long)r * Cc + c0 + tx];
  }
  __syncthreads();
  #pragma unroll
  for (int i = 0; i < 4; ++i) {
    int c = c0 + ty + i * 8;
    ob[(long)c * R + r0 + tx] = f2b(tile[tx][ty + i * 8]);
  }
}

// ---------------- PAM row-max via MFMA on bf16 (exact max of the logits pass-2 uses) ----------------
// grid (n/32, 4 m-split, B). qTb/kTb: bf16 [b][4096][32].
__global__ __launch_bounds__(256) void pam_qk_max(const u16* __restrict__ qTb, const u16* __restrict__ kTb,
                                                  float* __restrict__ pmax) {
  __shared__ u16 Qs[32 * 40];
  __shared__ u16 Ks[64 * 40];
  __shared__ float red[4][32][17];
  const int t = threadIdx.x;
  const int b = blockIdx.z, ms = blockIdx.y, n0 = blockIdx.x * 32;
  const int w = t >> 6, l = t & 63, lq = l >> 4, lr = l & 15;
  const int wn = w & 1, wc = w >> 1;
  if (t < 128) {
    int row = t >> 2, cq = (t & 3) * 8;
    *(uint4*)&Qs[row * 40 + cq] = *(const uint4*)(qTb + ((long)b * 4096 + n0 + row) * 32 + cq);
  }
  __syncthreads();
  bf16x8 qf = *(const bf16x8*)&Qs[(wn * 16 + lr) * 40 + lq * 8];
  float mx4[4] = {-1e30f, -1e30f, -1e30f, -1e30f};
  const int krow = t >> 2, kcq = (t & 3) * 8;
  for (int it = 0; it < 16; ++it) {
    int m0 = ms * 1024 + it * 64;
    __syncthreads();
    *(uint4*)&Ks[krow * 40 + kcq] = *(const uint4*)(kTb + ((long)b * 4096 + m0 + krow) * 32 + kcq);
    __syncthreads();
    #pragma unroll
    for (int s = 0; s < 2; ++s) {
      int msub = wc * 2 + s;
      bf16x8 kf = *(const bf16x8*)&Ks[(msub * 16 + lr) * 40 + lq * 8];
      f32x4 S = {};
      S = __builtin_amdgcn_mfma_f32_16x16x32_bf16(qf, kf, S, 0, 0, 0);
      #pragma unroll
      for (int r = 0; r < 4; ++r) mx4[r] = fmaxf(mx4[r], S[r]);
    }
  }
  #pragma unroll
  for (int r = 0; r < 4; ++r) red[w][wn * 16 + lq * 4 + r][lr] = mx4[r];
  __syncthreads();
  if (t < 32) {
    int wbase = t >> 4;
    float M = -1e30f;
    #pragma unroll
    for (int j = 0; j < 2; ++j)
      #pragma unroll
      for (int l2 = 0; l2 < 16; ++l2)
        M = fmaxf(M, red[wbase + 2 * j][t][l2]);
    pmax[((long)ms * 2 + b) * 4096 + n0 + t] = M;
  }
}

__global__ __launch_bounds__(256) void pam_merge(const float* __restrict__ pmax, float* __restrict__ rmx) {
  int i = blockIdx.x * 256 + threadIdx.x;
  int b = i >> 12, n = i & 4095;
  float m = pmax[(long)b * 4096 + n];
  #pragma unroll
  for (int ms = 1; ms < 4; ++ms) m = fmaxf(m, pmax[((long)ms * 2 + b) * 4096 + n]);
  rmx[i] = m;
}

// ---------------- PAM attention (MFMA, self-normalizing, bf16 inputs) ----------------
__global__ __launch_bounds__(256) void pam_attn(const u16* __restrict__ qTb, const u16* __restrict__ kTb,
    const u16* __restrict__ vb, const float* __restrict__ rowmax, float* __restrict__ pam) {
  __shared__ u16 Qs[32 * 40];
  __shared__ u16 Ks[64 * 40];
  __shared__ u16 Vs[64 * 72];
  __shared__ u16 Ps[32 * 72];
  __shared__ float rmL[32];
  __shared__ float srow[32];
  const int t = threadIdx.x;
  const int b = blockIdx.z;
  const int n0 = blockIdx.x * 32;
  const int c0 = blockIdx.y * 64;
  const int w = t >> 6, l = t & 63, lq = l >> 4, lr = l & 15;
  const int wn = w & 1, wc = w >> 1;
  if (t < 128) {
    int row = t >> 2, cq = (t & 3) * 8;
    *(uint4*)&Qs[row * 40 + cq] = *(const uint4*)(qTb + ((long)b * 4096 + n0 + row) * 32 + cq);
  }
  if (t < 32) { rmL[t] = rowmax[(long)b * 4096 + n0 + t] * LOG2E; srow[t] = 0.f; }
  __syncthreads();
  bf16x8 qf = *(const bf16x8*)&Qs[(wn * 16 + lr) * 40 + lq * 8];
  float rm4[4];
  #pragma unroll
  for (int r = 0; r < 4; ++r) rm4[r] = rmL[wn * 16 + lq * 4 + r];
  float sp[4] = {0.f, 0.f, 0.f, 0.f};
  f32x4 acc[2] = {};
  const int krow = t >> 2, kcq = (t & 3) * 8;
  const int vcc = t >> 2, vmq = (t & 3) * 16;
  for (int m0 = 0; m0 < 4096; m0 += 64) {
    __syncthreads();
    *(uint4*)&Ks[krow * 40 + kcq] = *(const uint4*)(kTb + ((long)b * 4096 + m0 + krow) * 32 + kcq);
    {
      const u16* src = vb + ((long)(b * 256 + c0 + vcc)) * 4096 + m0 + vmq;
      *(uint4*)&Vs[vcc * 72 + vmq] = *(const uint4*)src;
      *(uint4*)&Vs[vcc * 72 + vmq + 8] = *(const uint4*)(src + 8);
    }
    __syncthreads();
    #pragma unroll
    for (int s = 0; s < 2; ++s) {
      int msub = wc * 2 + s;
      bf16x8 kf = *(const bf16x8*)&Ks[(msub * 16 + lr) * 40 + lq * 8];
      f32x4 S = {};
      S = __builtin_amdgcn_mfma_f32_16x16x32_bf16(qf, kf, S, 0, 0, 0);
      #pragma unroll
      for (int r = 0; r < 4; ++r) {
        float p = exp2f(S[r] * LOG2E - rm4[r]);
        u16 pb = f2b(p);
        sp[r] += b2f(pb);
        Ps[(wn * 16 + lq * 4 + r) * 72 + msub * 16 + lr] = pb;
      }
    }
    __syncthreads();
    #pragma unroll
    for (int ks = 0; ks < 2; ++ks) {
      bf16x8 pf = *(const bf16x8*)&Ps[(wn * 16 + lr) * 72 + ks * 32 + lq * 8];
      #pragma unroll
      for (int it = 0; it < 2; ++it) {
        bf16x8 vf = *(const bf16x8*)&Vs[(wc * 32 + it * 16 + lr) * 72 + ks * 32 + lq * 8];
        acc[it] = __builtin_amdgcn_mfma_f32_16x16x32_bf16(vf, pf, acc[it], 0, 0, 0);
      }
    }
  }
  #pragma unroll
  for (int r = 0; r < 4; ++r) atomicAdd(&srow[wn * 16 + lq * 4 + r], sp[r]);
  __syncthreads();
  float inv = 1.f / srow[wn * 16 + lr];
  float* ob = pam + (long)b * (256L * 4096) + n0 + wn * 16 + lr;
  #pragma unroll
  for (int it = 0; it < 2; ++it)
    #pragma unroll
    for (int r = 0; r < 4; ++r)
      ob[(long)(c0 + wc * 32 + it * 16 + lq * 4 + r) * 4096] = acc[it][r] * inv;
}

// ---------------- CAM ----------------

__global__ __launch_bounds__(256) void fillz(float* __restrict__ p, int n) {
  int i = blockIdx.x * 256 + threadIdx.x;
  if (i < n) p[i] = 0.f;
}

__global__ __launch_bounds__(256) void cam_e(const float* __restrict__ f, float* __restrict__ e) {
  __shared__ __align__(16) float fc[32][68];
  __shared__ __align__(16) float fd[32][68];
  const int c0 = blockIdx.x * 64, d0 = blockIdx.y * 64;
  const int bz = blockIdx.z;
  const int b = bz >> 3, ns = bz & 7;
  const int t = threadIdx.x;
  const int tx = t & 15, ty = t >> 4;
  float acc[4][4] = {};
  const float* fb = f + (long)b * 1048576;
  for (int nc = 0; nc < 16; ++nc) {
    int nb = ns * 512 + nc * 32;
    __syncthreads();
    #pragma unroll
    for (int i = 0; i < 2; ++i) {
      int id = i * 256 + t;
      int row = id >> 3, c4 = id & 7;
      float4 v = *(const float4*)(fb + (long)(c0 + row) * 4096 + nb + c4 * 4);
      fc[c4*4+0][row] = v.x; fc[c4*4+1][row] = v.y; fc[c4*4+2][row] = v.z; fc[c4*4+3][row] = v.w;
      float4 u = *(const float4*)(fb + (long)(d0 + row) * 4096 + nb + c4 * 4);
      fd[c4*4+0][row] = u.x; fd[c4*4+1][row] = u.y; fd[c4*4+2][row] = u.z; fd[c4*4+3][row] = u.w;
    }
    __syncthreads();
    #pragma unroll
    for (int nn = 0; nn < 32; ++nn) {
      float4 a = *(const float4*)&fc[nn][ty * 4];
      float4 bq = *(const float4*)&fd[nn][tx * 4];
      float aa[4] = {a.x, a.y, a.z, a.w};
      float bb[4] = {bq.x, bq.y, bq.z, bq.w};
      #pragma unroll
      for (int i = 0; i < 4; ++i)
        #pragma unroll
        for (int j = 0; j < 4; ++j) acc[i][j] += aa[i] * bb[j];
    }
  }
  #pragma unroll
  for (int i = 0; i < 4; ++i)
    #pragma unroll
    for (int j = 0; j < 4; ++j)
      atomicAdd(&e[((long)b << 16) + (long)(c0 + ty * 4 + i) * 256 + d0 + tx * 4 + j], acc[i][j]);
}

__global__ __launch_bounds__(256) void cam_softmax(const float* __restrict__ e, u16* __restrict__ attn) {
  __shared__ float red[256];
  int c = blockIdx.x, b = blockIdx.y, t = threadIdx.x;
  const float* row = e + ((long)b << 16) + (long)c * 256;
  float v = row[t];
  red[t] = v; __syncthreads();
  for (int s = 128; s > 0; s >>= 1) { if (t < s) red[t] = fminf(red[t], red[t + s]); __syncthreads(); }
  float emin = red[0]; __syncthreads();
  float ex = exp2f(LOG2E * (emin - v));
  red[t] = ex; __syncthreads();
  for (int s = 128; s > 0; s >>= 1) { if (t < s) red[t] += red[t + s]; __syncthreads(); }
  float inv = 1.f / red[0];
  attn[((long)b << 16) + (long)c * 256 + t] = f2b(ex * inv);
}

// ---------------- final combine ----------------

__global__ __launch_bounds__(256) void combine(const float* __restrict__ res, const float* __restrict__ pam,
    const float* __restrict__ cam, const float* __restrict__ gp,
    void* __restrict__ outp, const u16* __restrict__ xp) {
  __shared__ int sflag;
  if (threadIdx.x == 0) sflag = detect_fp32(xp);
  __syncthreads();
  int idx = blockIdx.x * 256 + threadIdx.x;
  float g1 = gp[0], g2 = gp[1];
  float v = 3.f * res[idx] + g1 * pam[idx] + g2 * cam[idx];
  if (sflag) ((float*)outp)[idx] = v;
  else       ((u16*)outp)[idx] = f2b(v);
}

// ---------------- launch ----------------

extern "C" void kernel_launch(void* const* d_in, const int* in_sizes, int n_in,
                              void* d_out, int out_size, void* d_ws, size_t ws_size,
                              hipStream_t stream)
{
  (void)out_size; (void)ws_size; (void)n_in;
  float* ws = (float*)d_ws;
  const long CN = 256L * 4096;

  float* A  = ws;            // r -> res
  float* Bp = ws + 2 * CN;   // x_f32 -> s1out -> pool tmp -> s5out
  float* Cp = ws + 4 * CN;   // CoordAtt smalls -> s3out -> {vb, qTb, kTb (bf16)}
  float* D  = ws + 6 * CN;   // cat(8CN) -> {y12, attn smalls} -> {pam, cam}
  const long WFo = 14 * CN;

  float* yin = Cp;
  float* ybn = Cp + 65536;
  float* ah  = Cp + 67584;
  float* aw_ = Cp + 100352;

  // bf16 attention operands packed into Cp (dead after s4):
  u16* vb  = (u16*)Cp;                 // [B][256][4096] bf16 = 2CN u16 = CN floats
  u16* qTb = (u16*)(Cp + CN);          // [B][4096][32] bf16 = 262144 u16
  u16* kTb = (u16*)(Cp + CN + 131072); // 262144 u16 (ends CN+262144 floats < 2CN)

  float* q     = D + 4 * CN;
  float* k     = q + 262144;
  float* pmax  = q + 1048576;
  float* rmx   = q + 1081344;
  float* e     = q + 1089536;
  u16*   attnc = (u16*)(q + 1220608);

  float* res = A;
  float* pam = D;
  float* cam = D + 2 * CN;

  // ---- input conversion ----
  ConvArgs ca;
  long fOff[30], hOff[30];
  long hcur = 0;
  {
    long cum = 0, fcur = WFo;
    for (int i = 0; i < 30; ++i) {
      ca.src[i] = d_in[i];
      int h = (i == 8 || i == 10 || i == 14 || i == 16 || i == 20 || i == 26) ? 1 : 0;
      ca.mode[i] = h;
      if (i == 0) { ca.dst[i] = 2 * CN; fOff[i] = 2 * CN; }
      else if (h) { ca.dst[i] = hcur; hOff[i] = hcur; hcur += in_sizes[i]; }
      else        { ca.dst[i] = fcur; fOff[i] = fcur; fcur += in_sizes[i]; }
      cum += in_sizes[i];
      ca.end[i] = (int)cum;
    }
  }
  long fTotal = WFo;
  for (int i = 1; i < 30; ++i) if (!ca.mode[i]) fTotal = (fOff[i] + in_sizes[i] > fTotal) ? fOff[i] + in_sizes[i] : fTotal;
  u16* wsH = (u16*)(ws + fTotal);
  long wt3aOff = hcur;
  long wt3bOff = hcur + 589824;
  u16* wt3a = wsH + wt3aOff;
  u16* wt3b = wsH + wt3bOff;
  int total = ca.end[29];
  convert_all<<<dim3((total + 255) / 256), dim3(256), 0, stream>>>(ca, ws, wsH, (const u16*)d_in[0], total);

  float* xf    = Bp;
  float* ca_w1 = ws + fOff[1];
  float* ca_b1 = ws + fOff[2];
  float* ca_bn = ws + fOff[3];
  float* ca_wh = ws + fOff[4];
  float* ca_bh = ws + fOff[5];
  float* ca_ww = ws + fOff[6];
  float* ca_bw = ws + fOff[7];
  u16*   s1_w  = wsH + hOff[8];   float* s1_bn = ws + fOff[9];
  u16*   s2_w  = wsH + hOff[10];  float* s2_bn = ws + fOff[11];
  float* s3_wf = ws + fOff[12];   float* s3_bn = ws + fOff[13];
  u16*   s4_w  = wsH + hOff[14];  float* s4_bn = ws + fOff[15];
  u16*   s5_w  = wsH + hOff[16];  float* s5_bn = ws + fOff[17];
  float* s6_wf = ws + fOff[18];   float* s6_bn = ws + fOff[19];
  u16*   s7_w  = wsH + hOff[20];  float* s7_bn = ws + fOff[21];
  float* pq_w  = ws + fOff[22];   float* pq_b  = ws + fOff[23];
  float* pk_w  = ws + fOff[24];   float* pk_b  = ws + fOff[25];
  u16*   pv_w  = wsH + hOff[26];  float* pv_b  = ws + fOff[27];
  float* gammas = ws + fOff[28];

  w3t<<<dim3(2304), dim3(256), 0, stream>>>(s3_wf, wt3a);
  w3t<<<dim3(2304), dim3(256), 0, stream>>>(s6_wf, wt3b);

  // ---- CoordAtt ----
  plane_means<<<dim3(512), dim3(256), 0, stream>>>(xf, yin);
  ca_conv1<<<dim3(2), dim3(128), 0, stream>>>(yin, ca_w1, ca_b1, ca_bn, ybn);
  ca_gate<<<dim3(256, 2), dim3(128), 0, stream>>>(ybn, ca_wh, ca_bh, ca_ww, ca_bw, ah, aw_);
  apply_ca<<<dim3(8192), dim3(256), 0, stream>>>(xf, ah, aw_, A);

  // ---- SPPCSPC ----
  mfma_cbs<1,0><<<dim3(32, 4, 2), dim3(256), 0, stream>>>(s1_w, 0, A, CN, Bp, CN, 256, 256, 4096, s1_bn, nullptr);
  conv3_mfma<<<dim3(32, 4, 2), dim3(256), 0, stream>>>(wt3a, Bp, CN, Cp, CN, 256, 256, s3_bn);
  mfma_cbs<1,0><<<dim3(32, 4, 2), dim3(256), 0, stream>>>(s4_w, 0, Cp, CN, D, 4 * CN, 256, 256, 4096, s4_bn, nullptr);

  hmax5<<<dim3(4096, 2), dim3(256), 0, stream>>>(D, 4 * CN, Bp, CN);
  vmax5<<<dim3(4096, 2), dim3(256), 0, stream>>>(Bp, CN, D + CN, 4 * CN);
  hmax5<<<dim3(4096, 2), dim3(256), 0, stream>>>(D + CN, 4 * CN, Bp, CN);
  vmax5<<<dim3(4096, 2), dim3(256), 0, stream>>>(Bp, CN, D + 2 * CN, 4 * CN);
  hmax5<<<dim3(4096, 2), dim3(256), 0, stream>>>(D + 2 * CN, 4 * CN, Bp, CN);
  vmax5<<<dim3(4096, 2), dim3(256), 0, stream>>>(Bp, CN, D + 3 * CN, 4 * CN);

  mfma_cbs<1,0><<<dim3(32, 4, 2), dim3(256), 0, stream>>>(s5_w, 0, D, 4 * CN, Bp, CN, 256, 1024, 4096, s5_bn, nullptr);
  conv3_mfma<<<dim3(32, 4, 2), dim3(256), 0, stream>>>(wt3b, Bp, CN, D, 2 * CN, 256, 256, s6_bn);
  mfma_cbs<1,0><<<dim3(32, 4, 2), dim3(256), 0, stream>>>(s2_w, 0, A, CN, D + CN, 2 * CN, 256, 256, 4096, s2_bn, nullptr);
  mfma_cbs<1,0><<<dim3(32, 4, 2), dim3(256), 0, stream>>>(s7_w, 0, D, 2 * CN, A, CN, 256, 512, 4096, s7_bn, nullptr);

  // ---- PAM ----
  gemm_cbs<0><<<dim3(64, 1, 2), dim3(256), 0, stream>>>(pq_w, 0, res, CN, q, 131072, 32, 256, 4096, nullptr, pq_b);
  gemm_cbs<0><<<dim3(64, 1, 2), dim3(256), 0, stream>>>(pk_w, 0, res, CN, k, 131072, 32, 256, 4096, nullptr, pk_b);
  mfma_cbs<0,1><<<dim3(32, 4, 2), dim3(256), 0, stream>>>(pv_w, 0, res, CN, (float*)vb, CN, 256, 256, 4096, nullptr, pv_b);

  transpose_h<<<dim3(128, 1, 2), dim3(256), 0, stream>>>(q, qTb, 32, 4096);
  transpose_h<<<dim3(128, 1, 2), dim3(256), 0, stream>>>(k, kTb, 32, 4096);

  pam_qk_max<<<dim3(128, 4, 2), dim3(256), 0, stream>>>(qTb, kTb, pmax);
  pam_merge<<<dim3(32), dim3(256), 0, stream>>>(pmax, rmx);
  pam_attn<<<dim3(128, 4, 2), dim3(256), 0, stream>>>(qTb, kTb, vb, rmx, pam);

  // ---- CAM ----
  fillz<<<dim3(512), dim3(256), 0, stream>>>(e, 131072);
  cam_e<<<dim3(4, 4, 16), dim3(256), 0, stream>>>(res, e);
  cam_softmax<<<dim3(256, 2), dim3(256), 0, stream>>>(e, attnc);
  mfma_cbs<0,0><<<dim3(32, 4, 2), dim3(256), 0, stream>>>(attnc, 65536, res, CN, cam, CN, 256, 256, 4096, nullptr, nullptr);

  // ---- combine ----
  combine<<<dim3(8192), dim3(256), 0, stream>>>(res, pam, cam, gammas, d_out, (const u16*)d_in[0]);
}

// Round 7
// 721.923 us; speedup vs baseline: 3.1324x; 1.0061x over previous
//
#include <hip/hip_runtime.h>

typedef unsigned short u16;
typedef __attribute__((ext_vector_type(8))) short bf16x8;
typedef __attribute__((ext_vector_type(4))) float f32x4;
#define EPSV 1e-5f
#define LOG2E 1.4426950408889634f

__device__ __forceinline__ float b2f(u16 u) {
  union { float f; unsigned int i; } v; v.i = ((unsigned int)u) << 16; return v.f;
}
__device__ __forceinline__ u16 f2b(float f) {
  union { float f; unsigned int i; } v; v.f = f;
  unsigned int r = v.i + 0x7FFFu + ((v.i >> 16) & 1u);
  return (u16)(r >> 16);
}
__device__ __forceinline__ u16 f2b_trunc(float f) {
  union { float f; unsigned int i; } v; v.f = f;
  return (u16)(v.i >> 16);
}
__device__ __forceinline__ float silu_(float z) { return z / (1.f + exp2f(-LOG2E * z)); }

// Detect whether raw inputs are fp32 (1) or bf16 (0) by probing x.
__device__ int detect_fp32(const u16* __restrict__ xp) {
  int wild = 0, zeros = 0;
  for (int i = 0; i < 256; i += 2) {
    u16 u = xp[i];
    int e = (u >> 7) & 0xff;
    if (e != 0 && (e < 90 || e > 160)) wild++;
    if (u == 0) zeros++;
  }
  return (wild > 16 || zeros > 64) ? 1 : 0;
}

// ---------------- input conversion ----------------

struct ConvArgs {
  const void* src[30];
  long dst[30];
  int end[30];
  int mode[30];
};

__global__ __launch_bounds__(256) void convert_all(ConvArgs a, float* __restrict__ wsF,
                                                   u16* __restrict__ wsH,
                                                   const u16* __restrict__ xp, int total) {
  __shared__ int sflag;
  if (threadIdx.x == 0) sflag = detect_fp32(xp);
  __syncthreads();
  const int flag = sflag;
  int gid = blockIdx.x * 256 + threadIdx.x;
  if (gid >= total) return;
  #pragma unroll 1
  for (int s = 0; s < 30; ++s) {
    if (gid < a.end[s]) {
      int idx = gid - (s ? a.end[s - 1] : 0);
      if (a.mode[s] == 0) {
        float v = flag ? ((const float*)a.src[s])[idx] : b2f(((const u16*)a.src[s])[idx]);
        wsF[a.dst[s] + idx] = v;
      } else {
        u16 h = flag ? f2b(((const float*)a.src[s])[idx]) : ((const u16*)a.src[s])[idx];
        wsH[a.dst[s] + idx] = h;
      }
      return;
    }
  }
}

// conv3 weight transform: fp32 W[o][I][3][3] -> bf16 Wt[I/32][tap][256o][32ch]
__global__ __launch_bounds__(256) void w3t(const float* __restrict__ Wsrc, u16* __restrict__ Wdst) {
  int idx = blockIdx.x * 256 + threadIdx.x;
  int ch = idx & 31;
  int o  = (idx >> 5) & 255;
  int tap = (idx >> 13) % 9;
  int c8 = (idx >> 13) / 9;
  int i = c8 * 32 + ch;
  Wdst[idx] = f2b(Wsrc[((long)o * 256 + i) * 9 + tap]);
}

// ---------------- CoordAtt ----------------

__global__ __launch_bounds__(256) void plane_means(const float* __restrict__ x, float* __restrict__ yin) {
  __shared__ float pl[4096];
  int bc = blockIdx.x, t = threadIdx.x;
  const float* xp = x + (long)bc * 4096;
  for (int j = 0; j < 16; ++j) { int id = j * 256 + t; pl[id] = xp[id]; }
  __syncthreads();
  if (t < 64) {
    float s = 0.f;
    for (int w = 0; w < 64; ++w) s += pl[t * 64 + w];
    yin[(long)bc * 128 + t] = s * (1.f / 64.f);
  } else if (t < 128) {
    int w = t - 64; float s = 0.f;
    for (int h = 0; h < 64; ++h) s += pl[h * 64 + w];
    yin[(long)bc * 128 + 64 + w] = s * (1.f / 64.f);
  }
}

__global__ __launch_bounds__(128) void ca_conv1(const float* __restrict__ yin, const float* __restrict__ w1,
                                                const float* __restrict__ b1, const float* __restrict__ bnp,
                                                float* __restrict__ ybn) {
  int b = blockIdx.x, p = threadIdx.x;
  float acc[8] = {0.f,0.f,0.f,0.f,0.f,0.f,0.f,0.f};
  for (int c = 0; c < 256; ++c) {
    float yv = yin[((long)b * 256 + c) * 128 + p];
    #pragma unroll
    for (int o = 0; o < 8; ++o) acc[o] += w1[o * 256 + c] * yv;
  }
  #pragma unroll
  for (int o = 0; o < 8; ++o) {
    float z = acc[o] + b1[o];
    float g = bnp[o], bt = bnp[8 + o], mn = bnp[16 + o], vr = bnp[24 + o];
    float s = g * rsqrtf(vr + EPSV);
    z = z * s + (bt - mn * s);
    float hs = fminf(fmaxf(z + 3.f, 0.f), 6.f) * (1.f / 6.f);
    ybn[((long)b * 8 + o) * 128 + p] = z * hs;
  }
}

__global__ __launch_bounds__(128) void ca_gate(const float* __restrict__ ybn,
    const float* __restrict__ wh, const float* __restrict__ bh,
    const float* __restrict__ ww, const float* __restrict__ bw,
    float* __restrict__ ah, float* __restrict__ aw_) {
  int c = blockIdx.x, b = blockIdx.y, t = threadIdx.x;
  if (t < 64) {
    float d = 0.f;
    #pragma unroll
    for (int o = 0; o < 8; ++o) d += wh[c * 8 + o] * ybn[((long)b * 8 + o) * 128 + t];
    d += bh[c];
    ah[((long)b * 256 + c) * 64 + t] = 1.f / (1.f + exp2f(-LOG2E * d));
  } else {
    int w = t - 64;
    float d = 0.f;
    #pragma unroll
    for (int o = 0; o < 8; ++o) d += ww[c * 8 + o] * ybn[((long)b * 8 + o) * 128 + 64 + w];
    d += bw[c];
    aw_[((long)b * 256 + c) * 64 + w] = 1.f / (1.f + exp2f(-LOG2E * d));
  }
}

__global__ __launch_bounds__(256) void apply_ca(const float* __restrict__ x, const float* __restrict__ ah,
                                                const float* __restrict__ aw_, float* __restrict__ r) {
  int idx = blockIdx.x * 256 + threadIdx.x;
  int n = idx & 4095, bc = idx >> 12;
  int h = n >> 6, w = n & 63;
  r[idx] = x[idx] * ah[bc * 64 + h] * aw_[bc * 64 + w];
}

// ---------------- VALU GEMM (O=32 q/k projections) ----------------

template<int ACT>
__global__ __launch_bounds__(256) void gemm_cbs(
    const float* __restrict__ A, long aBS,
    const float* __restrict__ In, long bBS,
    float* __restrict__ Out, long oBS,
    int O, int K, int N,
    const float* __restrict__ bnp, const float* __restrict__ bias)
{
  __shared__ __align__(16) float As[8][128];
  __shared__ __align__(16) float Bs[8][64];
  const int t = threadIdx.x;
  const int n0 = blockIdx.x * 64;
  const int o0 = blockIdx.y * 128;
  const int b  = blockIdx.z;
  const int tx = t & 15, ty = t >> 4;
  const int ao = t >> 1, ak = (t & 1) * 4;
  const int bk = t >> 5, bn_ = (t & 31) * 2;
  float acc[8][4] = {};
  const float* inb = In + (long)b * bBS + n0;
  const float* Ab = A + (long)b * aBS;
  for (int kc = 0; kc < K; kc += 8) {
    __syncthreads();
    float av[4] = {0.f, 0.f, 0.f, 0.f};
    if (o0 + ao < O) {
      float4 u = *(const float4*)(Ab + (long)(o0 + ao) * K + kc + ak);
      av[0] = u.x; av[1] = u.y; av[2] = u.z; av[3] = u.w;
    }
    #pragma unroll
    for (int j = 0; j < 4; ++j) As[ak + j][ao] = av[j];
    float2 bv = *(const float2*)(inb + (long)(kc + bk) * N + bn_);
    Bs[bk][bn_] = bv.x; Bs[bk][bn_ + 1] = bv.y;
    __syncthreads();
    #pragma unroll
    for (int kk = 0; kk < 8; ++kk) {
      float4 a0 = *(const float4*)&As[kk][ty * 8];
      float4 a1 = *(const float4*)&As[kk][ty * 8 + 4];
      float4 bq = *(const float4*)&Bs[kk][tx * 4];
      float aa[8] = {a0.x, a0.y, a0.z, a0.w, a1.x, a1.y, a1.z, a1.w};
      float bb[4] = {bq.x, bq.y, bq.z, bq.w};
      #pragma unroll
      for (int i = 0; i < 8; ++i)
        #pragma unroll
        for (int j = 0; j < 4; ++j) acc[i][j] += aa[i] * bb[j];
    }
  }
  float* ob = Out + (long)b * oBS + n0 + tx * 4;
  #pragma unroll
  for (int i = 0; i < 8; ++i) {
    int o = o0 + ty * 8 + i;
    if (o < O) {
      float al = 1.f, be = 0.f;
      if (bnp) {
        float g = bnp[o], bt = bnp[O + o], mn = bnp[2 * O + o], vr = bnp[3 * O + o];
        al = g * rsqrtf(vr + EPSV);
        be = bt - mn * al;
      }
      if (bias) be += bias[o];
      float4 rv;
      rv.x = acc[i][0] * al + be;
      rv.y = acc[i][1] * al + be;
      rv.z = acc[i][2] * al + be;
      rv.w = acc[i][3] * al + be;
      if (ACT) { rv.x = silu_(rv.x); rv.y = silu_(rv.y); rv.z = silu_(rv.z); rv.w = silu_(rv.w); }
      *(float4*)(ob + (long)o * N) = rv;
    }
  }
}

// ---------------- MFMA 1x1 conv; OUTH=1 -> bf16 output ----------------

template<int ACT, int OUTH>
__global__ __launch_bounds__(256) void mfma_cbs(
    const u16* __restrict__ Wbf, long aBS,
    const float* __restrict__ In, long bBS,
    float* __restrict__ Out, long oBS,
    int O, int K, int N,
    const float* __restrict__ bnp, const float* __restrict__ bias)
{
  __shared__ u16 As[64 * 40];
  __shared__ u16 Bs[128 * 40];
  __shared__ float albe[64][2];
  const int t = threadIdx.x;
  const int n0 = blockIdx.x * 128;
  const int o0 = blockIdx.y * 64;
  const int b  = blockIdx.z;
  const int w = t >> 6, l = t & 63, lq = l >> 4, lr = l & 15;
  const int wo = (w >> 1) * 32, wn = (w & 1) * 64;
  if (t < 64) {
    int o = o0 + t;
    float al = 1.f, be = 0.f;
    if (bnp) {
      float g = bnp[o], bt = bnp[O + o], mn = bnp[2 * O + o], vr = bnp[3 * O + o];
      al = g * rsqrtf(vr + EPSV); be = bt - mn * al;
    }
    if (bias) be += bias[o];
    albe[t][0] = al; albe[t][1] = be;
  }
  const u16* Ab = Wbf + (long)b * aBS;
  const float* inb = In + (long)b * bBS + n0;
  const int ao = t >> 2, akq = (t & 3) * 8;
  const int bk = t >> 3, bc8 = t & 7;
  f32x4 acc[2][4] = {};
  for (int kc = 0; kc < K; kc += 32) {
    __syncthreads();
    *(uint4*)&As[ao * 40 + akq] = *(const uint4*)(Ab + (long)(o0 + ao) * K + kc + akq);
    const float* src = inb + (long)(kc + bk) * N + bc8 * 4;
    u16 tmp[16];
    #pragma unroll
    for (int i = 0; i < 4; ++i) {
      float4 f = *(const float4*)(src + i * 32);
      tmp[i*4+0] = f2b(f.x); tmp[i*4+1] = f2b(f.y); tmp[i*4+2] = f2b(f.z); tmp[i*4+3] = f2b(f.w);
    }
    #pragma unroll
    for (int i = 0; i < 4; ++i) {
      int n = bc8 * 4 + i * 32;
      #pragma unroll
      for (int j = 0; j < 4; ++j) Bs[(n + j) * 40 + bk] = tmp[i * 4 + j];
    }
    __syncthreads();
    bf16x8 af[2], bfv[4];
    #pragma unroll
    for (int i = 0; i < 2; ++i) af[i] = *(const bf16x8*)&As[(wo + i * 16 + lr) * 40 + lq * 8];
    #pragma unroll
    for (int j = 0; j < 4; ++j) bfv[j] = *(const bf16x8*)&Bs[(wn + j * 16 + lr) * 40 + lq * 8];
    #pragma unroll
    for (int i = 0; i < 2; ++i)
      #pragma unroll
      for (int j = 0; j < 4; ++j)
        acc[i][j] = __builtin_amdgcn_mfma_f32_16x16x32_bf16(af[i], bfv[j], acc[i][j], 0, 0, 0);
  }
  float* ob = Out + (long)b * oBS;
  u16* obh = (u16*)Out + (long)b * oBS;
  #pragma unroll
  for (int i = 0; i < 2; ++i) {
    #pragma unroll
    for (int r = 0; r < 4; ++r) {
      int ol = wo + i * 16 + lq * 4 + r;
      float al = albe[ol][0], be = albe[ol][1];
      #pragma unroll
      for (int j = 0; j < 4; ++j) {
        float vv = acc[i][j][r] * al + be;
        if (ACT) vv = silu_(vv);
        if (OUTH) obh[(long)(o0 + ol) * N + n0 + wn + j * 16 + lr] = f2b(vv);
        else      ob[(long)(o0 + ol) * N + n0 + wn + j * 16 + lr] = vv;
      }
    }
  }
}

// ---------------- MFMA 3x3 conv (implicit GEMM over 9 shifted taps) ----------------
__global__ __launch_bounds__(256) void conv3_mfma(
    const u16* __restrict__ Wt,
    const float* __restrict__ In, long iBS,
    float* __restrict__ Out, long oBS, int O, int I,
    const float* __restrict__ bnp)
{
  __shared__ u16 As[9 * 64 * 34];
  __shared__ u16 Bs[4 * 66 * 34];
  __shared__ float albe[64][2];
  const int t = threadIdx.x;
  const int h0 = blockIdx.x * 2;
  const int o0 = blockIdx.y * 64;
  const int b  = blockIdx.z;
  const int w = t >> 6, l = t & 63, lq = l >> 4, lr = l & 15;
  const int wo = (w >> 1) * 32, wn = (w & 1) * 64;
  if (t < 64) {
    int o = o0 + t;
    float g = bnp[o], bt = bnp[O + o], mn = bnp[2 * O + o], vr = bnp[3 * O + o];
    float al = g * rsqrtf(vr + EPSV);
    albe[t][0] = al; albe[t][1] = bt - mn * al;
  }
  {
    int r = t >> 6, cs = (t >> 5) & 1, ch = t & 31;
    Bs[(r * 66 + (cs ? 65 : 0)) * 34 + ch] = 0;
  }
  const float* inb = In + (long)b * iBS;
  const int bch = t >> 3, bcg = (t & 7) * 8;
  f32x4 acc[2][4] = {};
  for (int c8 = 0; c8 < (I >> 5); ++c8) {
    __syncthreads();
    {
      const u16* wsrc = Wt + (long)c8 * 9 * 256 * 32;
      #pragma unroll
      for (int j = 0; j < 9; ++j) {
        int e = j * 2048 + t * 8;
        int tap = e >> 11, o = (e >> 5) & 63, ch0 = e & 31;
        uint4 vv = *(const uint4*)(wsrc + ((long)tap * 256 + o0 + o) * 32 + ch0);
        *(uint4*)&As[(tap * 64 + o) * 34 + ch0] = vv;
      }
    }
    {
      const float* cbase = inb + (long)(c8 * 32 + bch) * 4096;
      #pragma unroll
      for (int r = 0; r < 4; ++r) {
        int row = h0 - 1 + r;
        u16 hv[8];
        if (row >= 0 && row < 64) {
          float4 f0 = *(const float4*)(cbase + row * 64 + bcg);
          float4 f1 = *(const float4*)(cbase + row * 64 + bcg + 4);
          hv[0]=f2b(f0.x); hv[1]=f2b(f0.y); hv[2]=f2b(f0.z); hv[3]=f2b(f0.w);
          hv[4]=f2b(f1.x); hv[5]=f2b(f1.y); hv[6]=f2b(f1.z); hv[7]=f2b(f1.w);
        } else {
          #pragma unroll
          for (int j2 = 0; j2 < 8; ++j2) hv[j2] = 0;
        }
        #pragma unroll
        for (int j2 = 0; j2 < 8; ++j2)
          Bs[(r * 66 + bcg + 1 + j2) * 34 + bch] = hv[j2];
      }
    }
    __syncthreads();
    #pragma unroll
    for (int dy = 0; dy < 3; ++dy) {
      #pragma unroll
      for (int dx = 0; dx < 3; ++dx) {
        const int tap = dy * 3 + dx;
        bf16x8 af0 = *(const bf16x8*)&As[(tap * 64 + wo + lr) * 34 + lq * 8];
        bf16x8 af1 = *(const bf16x8*)&As[(tap * 64 + wo + 16 + lr) * 34 + lq * 8];
        #pragma unroll
        for (int j = 0; j < 4; ++j) {
          int nb = wn + j * 16;
          int rowS = (nb >> 6) + dy;
          int colS = (nb & 63) + dx;
          bf16x8 bv = *(const bf16x8*)&Bs[(rowS * 66 + colS + lr) * 34 + lq * 8];
          acc[0][j] = __builtin_amdgcn_mfma_f32_16x16x32_bf16(af0, bv, acc[0][j], 0, 0, 0);
          acc[1][j] = __builtin_amdgcn_mfma_f32_16x16x32_bf16(af1, bv, acc[1][j], 0, 0, 0);
        }
      }
    }
  }
  float* ob = Out + (long)b * oBS;
  const int n0 = h0 * 64;
  #pragma unroll
  for (int i = 0; i < 2; ++i) {
    #pragma unroll
    for (int r = 0; r < 4; ++r) {
      int ol = wo + i * 16 + lq * 4 + r;
      float al = albe[ol][0], be = albe[ol][1];
      #pragma unroll
      for (int j = 0; j < 4; ++j) {
        float vv = silu_(acc[i][j][r] * al + be);
        ob[(long)(o0 + ol) * 4096 + n0 + wn + j * 16 + lr] = vv;
      }
    }
  }
}

// ---------------- max pools ----------------

__global__ __launch_bounds__(256) void hmax5(const float* __restrict__ src, long sBS,
                                             float* __restrict__ dst, long dBS) {
  int t = blockIdx.x * 256 + threadIdx.x;
  int b = blockIdx.y;
  int n = t & 4095, c = t >> 12;
  int w = n & 63;
  const float* p = src + (long)b * sBS + (long)c * 4096 + (n - w);
  float m = p[w];
  if (w >= 1) m = fmaxf(m, p[w - 1]);
  if (w >= 2) m = fmaxf(m, p[w - 2]);
  if (w <= 62) m = fmaxf(m, p[w + 1]);
  if (w <= 61) m = fmaxf(m, p[w + 2]);
  dst[(long)b * dBS + t] = m;
}

__global__ __launch_bounds__(256) void vmax5(const float* __restrict__ src, long sBS,
                                             float* __restrict__ dst, long dBS) {
  int t = blockIdx.x * 256 + threadIdx.x;
  int b = blockIdx.y;
  int n = t & 4095, c = t >> 12;
  int h = n >> 6, w = n & 63;
  const float* p = src + (long)b * sBS + (long)c * 4096 + w;
  float m = p[h * 64];
  if (h >= 1) m = fmaxf(m, p[(h - 1) * 64]);
  if (h >= 2) m = fmaxf(m, p[(h - 2) * 64]);
  if (h <= 62) m = fmaxf(m, p[(h + 1) * 64]);
  if (h <= 61) m = fmaxf(m, p[(h + 2) * 64]);
  dst[(long)b * dBS + t] = m;
}

// ---------------- transpose (B, R, 4096) fp32 -> (B, 4096, R) bf16 ----------------

__global__ __launch_bounds__(256) void transpose_h(const float* __restrict__ in, u16* __restrict__ out,
                                                   int R, int Cc) {
  __shared__ float tile[32][33];
  int b = blockIdx.z;
  int c0 = blockIdx.x * 32, r0 = blockIdx.y * 32;
  int tx = threadIdx.x & 31, ty = threadIdx.x >> 5;
  const float* ib = in + (long)b * R * Cc;
  u16* ob = out + (long)b * R * Cc;
  #pragma unroll
  for (int i = 0; i < 4; ++i) {
    int r = r0 + ty + i * 8;
    tile[ty + i * 8][tx] = ib[(long)r * Cc + c0 + tx];
  }
  __syncthreads();
  #pragma unroll
  for (int i = 0; i < 4; ++i) {
    int c = c0 + ty + i * 8;
    ob[(long)c * R + r0 + tx] = f2b(tile[tx][ty + i * 8]);
  }
}

// ---------------- PAM row-max via MFMA on bf16 ----------------
__global__ __launch_bounds__(256) void pam_qk_max(const u16* __restrict__ qTb, const u16* __restrict__ kTb,
                                                  float* __restrict__ pmax) {
  __shared__ u16 Qs[32 * 40];
  __shared__ u16 Ks[64 * 40];
  __shared__ float red[4][32][17];
  const int t = threadIdx.x;
  const int b = blockIdx.z, ms = blockIdx.y, n0 = blockIdx.x * 32;
  const int w = t >> 6, l = t & 63, lq = l >> 4, lr = l & 15;
  const int wn = w & 1, wc = w >> 1;
  if (t < 128) {
    int row = t >> 2, cq = (t & 3) * 8;
    *(uint4*)&Qs[row * 40 + cq] = *(const uint4*)(qTb + ((long)b * 4096 + n0 + row) * 32 + cq);
  }
  __syncthreads();
  bf16x8 qf = *(const bf16x8*)&Qs[(wn * 16 + lr) * 40 + lq * 8];
  float mx4[4] = {-1e30f, -1e30f, -1e30f, -1e30f};
  const int krow = t >> 2, kcq = (t & 3) * 8;
  for (int it = 0; it < 16; ++it) {
    int m0 = ms * 1024 + it * 64;
    __syncthreads();
    *(uint4*)&Ks[krow * 40 + kcq] = *(const uint4*)(kTb + ((long)b * 4096 + m0 + krow) * 32 + kcq);
    __syncthreads();
    #pragma unroll
    for (int s = 0; s < 2; ++s) {
      int msub = wc * 2 + s;
      bf16x8 kf = *(const bf16x8*)&Ks[(msub * 16 + lr) * 40 + lq * 8];
      f32x4 S = {};
      S = __builtin_amdgcn_mfma_f32_16x16x32_bf16(qf, kf, S, 0, 0, 0);
      #pragma unroll
      for (int r = 0; r < 4; ++r) mx4[r] = fmaxf(mx4[r], S[r]);
    }
  }
  #pragma unroll
  for (int r = 0; r < 4; ++r) red[w][wn * 16 + lq * 4 + r][lr] = mx4[r];
  __syncthreads();
  if (t < 32) {
    int wbase = t >> 4;
    float M = -1e30f;
    #pragma unroll
    for (int j = 0; j < 2; ++j)
      #pragma unroll
      for (int l2 = 0; l2 < 16; ++l2)
        M = fmaxf(M, red[wbase + 2 * j][t][l2]);
    pmax[((long)ms * 2 + b) * 4096 + n0 + t] = M;
  }
}

__global__ __launch_bounds__(256) void pam_merge(const float* __restrict__ pmax, float* __restrict__ rmx) {
  int i = blockIdx.x * 256 + threadIdx.x;
  int b = i >> 12, n = i & 4095;
  float m = pmax[(long)b * 4096 + n];
  #pragma unroll
  for (int ms = 1; ms < 4; ++ms) m = fmaxf(m, pmax[((long)ms * 2 + b) * 4096 + n]);
  rmx[i] = m;
}

// ---------------- PAM attention v2: one block covers all 256 c (no redundant QK/exp) ----------------
// 512 threads / 8 waves. Wave w: QK tile (n-frag w&1, m-frag w>>1); PV c-slice w*32.
__global__ __launch_bounds__(512) void pam_attn(const u16* __restrict__ qTb, const u16* __restrict__ kTb,
    const u16* __restrict__ vb, const float* __restrict__ rowmax, float* __restrict__ pam) {
  __shared__ u16 Qs[32 * 40];
  __shared__ u16 Ks[64 * 40];
  __shared__ u16 Vs[256 * 72];
  __shared__ u16 Ps[32 * 72];
  __shared__ float rmL[32];
  __shared__ float srow[32];
  const int t = threadIdx.x;
  const int b = blockIdx.z;
  const int n0 = blockIdx.x * 32;
  const int w = t >> 6, l = t & 63, lq = l >> 4, lr = l & 15;
  const int nf = w & 1;       // QK n-frag
  const int mf = w >> 1;      // QK m-frag 0..3
  const int cw = w * 32;      // PV c-base
  if (t < 128) {
    int row = t >> 2, cq = (t & 3) * 8;
    *(uint4*)&Qs[row * 40 + cq] = *(const uint4*)(qTb + ((long)b * 4096 + n0 + row) * 32 + cq);
  }
  if (t < 32) { rmL[t] = rowmax[(long)b * 4096 + n0 + t] * LOG2E; srow[t] = 0.f; }
  __syncthreads();
  bf16x8 qf = *(const bf16x8*)&Qs[(nf * 16 + lr) * 40 + lq * 8];
  float rm4[4];
  #pragma unroll
  for (int r = 0; r < 4; ++r) rm4[r] = rmL[nf * 16 + lq * 4 + r];
  float sp[4] = {0.f, 0.f, 0.f, 0.f};
  f32x4 acc[2][2] = {};   // [cfrag][nfrag]
  const int krow = t >> 3, kc4 = (t & 7) * 4;      // K: 64 rows x 32, uint2/lane
  const int vcc = t >> 1, vm = (t & 1) * 32;       // V: 256 rows x 64, 4x uint4/lane
  const u16* kbase = kTb + ((long)b * 4096 + krow) * 32 + kc4;
  const u16* vbase = vb + ((long)b * 256 + vcc) * 4096 + vm;
  for (int m0 = 0; m0 < 4096; m0 += 64) {
    __syncthreads();
    *(uint2*)&Ks[krow * 40 + kc4] = *(const uint2*)(kbase + (long)m0 * 32);
    {
      const u16* src = vbase + m0;
      u16* dst = &Vs[vcc * 72 + vm];
      #pragma unroll
      for (int i = 0; i < 4; ++i) *(uint4*)(dst + i * 8) = *(const uint4*)(src + i * 8);
    }
    __syncthreads();
    // QK: one 16x16 tile per wave
    {
      bf16x8 kf = *(const bf16x8*)&Ks[(mf * 16 + lr) * 40 + lq * 8];
      f32x4 S = {};
      S = __builtin_amdgcn_mfma_f32_16x16x32_bf16(qf, kf, S, 0, 0, 0);
      #pragma unroll
      for (int r = 0; r < 4; ++r) {
        float p = exp2f(S[r] * LOG2E - rm4[r]);
        sp[r] += p;
        Ps[(nf * 16 + lq * 4 + r) * 72 + mf * 16 + lr] = f2b_trunc(p);
      }
    }
    __syncthreads();
    // PV: wave's 32-c slice over all 32 n, k=64
    #pragma unroll
    for (int ks = 0; ks < 2; ++ks) {
      bf16x8 pf0 = *(const bf16x8*)&Ps[lr * 72 + ks * 32 + lq * 8];
      bf16x8 pf1 = *(const bf16x8*)&Ps[(16 + lr) * 72 + ks * 32 + lq * 8];
      #pragma unroll
      for (int cf = 0; cf < 2; ++cf) {
        bf16x8 vf = *(const bf16x8*)&Vs[(cw + cf * 16 + lr) * 72 + ks * 32 + lq * 8];
        acc[cf][0] = __builtin_amdgcn_mfma_f32_16x16x32_bf16(vf, pf0, acc[cf][0], 0, 0, 0);
        acc[cf][1] = __builtin_amdgcn_mfma_f32_16x16x32_bf16(vf, pf1, acc[cf][1], 0, 0, 0);
      }
    }
  }
  // reduce sp over lr within each quad-row, then one atomic per group
  #pragma unroll
  for (int r = 0; r < 4; ++r) {
    float s = sp[r];
    s += __shfl_xor(s, 1); s += __shfl_xor(s, 2);
    s += __shfl_xor(s, 4); s += __shfl_xor(s, 8);
    if (lr == 0) atomicAdd(&srow[nf * 16 + lq * 4 + r], s);
  }
  __syncthreads();
  float inv0 = 1.f / srow[lr];
  float inv1 = 1.f / srow[16 + lr];
  float* ob = pam + (long)b * (256L * 4096) + n0;
  #pragma unroll
  for (int cf = 0; cf < 2; ++cf) {
    #pragma unroll
    for (int r = 0; r < 4; ++r) {
      int c = cw + cf * 16 + lq * 4 + r;
      ob[(long)c * 4096 + lr]      = acc[cf][0][r] * inv0;
      ob[(long)c * 4096 + 16 + lr] = acc[cf][1][r] * inv1;
    }
  }
}

// ---------------- CAM ----------------

__global__ __launch_bounds__(256) void fillz(float* __restrict__ p, int n) {
  int i = blockIdx.x * 256 + threadIdx.x;
  if (i < n) p[i] = 0.f;
}

__global__ __launch_bounds__(256) void cam_e(const float* __restrict__ f, float* __restrict__ e) {
  __shared__ __align__(16) float fc[32][68];
  __shared__ __align__(16) float fd[32][68];
  const int c0 = blockIdx.x * 64, d0 = blockIdx.y * 64;
  const int bz = blockIdx.z;
  const int b = bz >> 3, ns = bz & 7;
  const int t = threadIdx.x;
  const int tx = t & 15, ty = t >> 4;
  float acc[4][4] = {};
  const float* fb = f + (long)b * 1048576;
  for (int nc = 0; nc < 16; ++nc) {
    int nb = ns * 512 + nc * 32;
    __syncthreads();
    #pragma unroll
    for (int i = 0; i < 2; ++i) {
      int id = i * 256 + t;
      int row = id >> 3, c4 = id & 7;
      float4 v = *(const float4*)(fb + (long)(c0 + row) * 4096 + nb + c4 * 4);
      fc[c4*4+0][row] = v.x; fc[c4*4+1][row] = v.y; fc[c4*4+2][row] = v.z; fc[c4*4+3][row] = v.w;
      float4 u = *(const float4*)(fb + (long)(d0 + row) * 4096 + nb + c4 * 4);
      fd[c4*4+0][row] = u.x; fd[c4*4+1][row] = u.y; fd[c4*4+2][row] = u.z; fd[c4*4+3][row] = u.w;
    }
    __syncthreads();
    #pragma unroll
    for (int nn = 0; nn < 32; ++nn) {
      float4 a = *(const float4*)&fc[nn][ty * 4];
      float4 bq = *(const float4*)&fd[nn][tx * 4];
      float aa[4] = {a.x, a.y, a.z, a.w};
      float bb[4] = {bq.x, bq.y, bq.z, bq.w};
      #pragma unroll
      for (int i = 0; i < 4; ++i)
        #pragma unroll
        for (int j = 0; j < 4; ++j) acc[i][j] += aa[i] * bb[j];
    }
  }
  #pragma unroll
  for (int i = 0; i < 4; ++i)
    #pragma unroll
    for (int j = 0; j < 4; ++j)
      atomicAdd(&e[((long)b << 16) + (long)(c0 + ty * 4 + i) * 256 + d0 + tx * 4 + j], acc[i][j]);
}

__global__ __launch_bounds__(256) void cam_softmax(const float* __restrict__ e, u16* __restrict__ attn) {
  __shared__ float red[256];
  int c = blockIdx.x, b = blockIdx.y, t = threadIdx.x;
  const float* row = e + ((long)b << 16) + (long)c * 256;
  float v = row[t];
  red[t] = v; __syncthreads();
  for (int s = 128; s > 0; s >>= 1) { if (t < s) red[t] = fminf(red[t], red[t + s]); __syncthreads(); }
  float emin = red[0]; __syncthreads();
  float ex = exp2f(LOG2E * (emin - v));
  red[t] = ex; __syncthreads();
  for (int s = 128; s > 0; s >>= 1) { if (t < s) red[t] += red[t + s]; __syncthreads(); }
  float inv = 1.f / red[0];
  attn[((long)b << 16) + (long)c * 256 + t] = f2b(ex * inv);
}

// ---------------- final combine ----------------

__global__ __launch_bounds__(256) void combine(const float* __restrict__ res, const float* __restrict__ pam,
    const float* __restrict__ cam, const float* __restrict__ gp,
    void* __restrict__ outp, const u16* __restrict__ xp) {
  __shared__ int sflag;
  if (threadIdx.x == 0) sflag = detect_fp32(xp);
  __syncthreads();
  int idx = blockIdx.x * 256 + threadIdx.x;
  float g1 = gp[0], g2 = gp[1];
  float v = 3.f * res[idx] + g1 * pam[idx] + g2 * cam[idx];
  if (sflag) ((float*)outp)[idx] = v;
  else       ((u16*)outp)[idx] = f2b(v);
}

// ---------------- launch ----------------

extern "C" void kernel_launch(void* const* d_in, const int* in_sizes, int n_in,
                              void* d_out, int out_size, void* d_ws, size_t ws_size,
                              hipStream_t stream)
{
  (void)out_size; (void)ws_size; (void)n_in;
  float* ws = (float*)d_ws;
  const long CN = 256L * 4096;

  float* A  = ws;            // r -> res
  float* Bp = ws + 2 * CN;   // x_f32 -> s1out -> pool tmp -> s5out
  float* Cp = ws + 4 * CN;   // CoordAtt smalls -> s3out -> {vb, qTb, kTb (bf16)}
  float* D  = ws + 6 * CN;   // cat(8CN) -> {y12, attn smalls} -> {pam, cam}
  const long WFo = 14 * CN;

  float* yin = Cp;
  float* ybn = Cp + 65536;
  float* ah  = Cp + 67584;
  float* aw_ = Cp + 100352;

  u16* vb  = (u16*)Cp;
  u16* qTb = (u16*)(Cp + CN);
  u16* kTb = (u16*)(Cp + CN + 131072);

  float* q     = D + 4 * CN;
  float* k     = q + 262144;
  float* pmax  = q + 1048576;
  float* rmx   = q + 1081344;
  float* e     = q + 1089536;
  u16*   attnc = (u16*)(q + 1220608);

  float* res = A;
  float* pam = D;
  float* cam = D + 2 * CN;

  ConvArgs ca;
  long fOff[30], hOff[30];
  long hcur = 0;
  {
    long cum = 0, fcur = WFo;
    for (int i = 0; i < 30; ++i) {
      ca.src[i] = d_in[i];
      int h = (i == 8 || i == 10 || i == 14 || i == 16 || i == 20 || i == 26) ? 1 : 0;
      ca.mode[i] = h;
      if (i == 0) { ca.dst[i] = 2 * CN; fOff[i] = 2 * CN; }
      else if (h) { ca.dst[i] = hcur; hOff[i] = hcur; hcur += in_sizes[i]; }
      else        { ca.dst[i] = fcur; fOff[i] = fcur; fcur += in_sizes[i]; }
      cum += in_sizes[i];
      ca.end[i] = (int)cum;
    }
  }
  long fTotal = WFo;
  for (int i = 1; i < 30; ++i) if (!ca.mode[i]) fTotal = (fOff[i] + in_sizes[i] > fTotal) ? fOff[i] + in_sizes[i] : fTotal;
  u16* wsH = (u16*)(ws + fTotal);
  long wt3aOff = hcur;
  long wt3bOff = hcur + 589824;
  u16* wt3a = wsH + wt3aOff;
  u16* wt3b = wsH + wt3bOff;
  int total = ca.end[29];
  convert_all<<<dim3((total + 255) / 256), dim3(256), 0, stream>>>(ca, ws, wsH, (const u16*)d_in[0], total);

  float* xf    = Bp;
  float* ca_w1 = ws + fOff[1];
  float* ca_b1 = ws + fOff[2];
  float* ca_bn = ws + fOff[3];
  float* ca_wh = ws + fOff[4];
  float* ca_bh = ws + fOff[5];
  float* ca_ww = ws + fOff[6];
  float* ca_bw = ws + fOff[7];
  u16*   s1_w  = wsH + hOff[8];   float* s1_bn = ws + fOff[9];
  u16*   s2_w  = wsH + hOff[10];  float* s2_bn = ws + fOff[11];
  float* s3_wf = ws + fOff[12];   float* s3_bn = ws + fOff[13];
  u16*   s4_w  = wsH + hOff[14];  float* s4_bn = ws + fOff[15];
  u16*   s5_w  = wsH + hOff[16];  float* s5_bn = ws + fOff[17];
  float* s6_wf = ws + fOff[18];   float* s6_bn = ws + fOff[19];
  u16*   s7_w  = wsH + hOff[20];  float* s7_bn = ws + fOff[21];
  float* pq_w  = ws + fOff[22];   float* pq_b  = ws + fOff[23];
  float* pk_w  = ws + fOff[24];   float* pk_b  = ws + fOff[25];
  u16*   pv_w  = wsH + hOff[26];  float* pv_b  = ws + fOff[27];
  float* gammas = ws + fOff[28];

  w3t<<<dim3(2304), dim3(256), 0, stream>>>(s3_wf, wt3a);
  w3t<<<dim3(2304), dim3(256), 0, stream>>>(s6_wf, wt3b);

  // ---- CoordAtt ----
  plane_means<<<dim3(512), dim3(256), 0, stream>>>(xf, yin);
  ca_conv1<<<dim3(2), dim3(128), 0, stream>>>(yin, ca_w1, ca_b1, ca_bn, ybn);
  ca_gate<<<dim3(256, 2), dim3(128), 0, stream>>>(ybn, ca_wh, ca_bh, ca_ww, ca_bw, ah, aw_);
  apply_ca<<<dim3(8192), dim3(256), 0, stream>>>(xf, ah, aw_, A);

  // ---- SPPCSPC ----
  mfma_cbs<1,0><<<dim3(32, 4, 2), dim3(256), 0, stream>>>(s1_w, 0, A, CN, Bp, CN, 256, 256, 4096, s1_bn, nullptr);
  conv3_mfma<<<dim3(32, 4, 2), dim3(256), 0, stream>>>(wt3a, Bp, CN, Cp, CN, 256, 256, s3_bn);
  mfma_cbs<1,0><<<dim3(32, 4, 2), dim3(256), 0, stream>>>(s4_w, 0, Cp, CN, D, 4 * CN, 256, 256, 4096, s4_bn, nullptr);

  hmax5<<<dim3(4096, 2), dim3(256), 0, stream>>>(D, 4 * CN, Bp, CN);
  vmax5<<<dim3(4096, 2), dim3(256), 0, stream>>>(Bp, CN, D + CN, 4 * CN);
  hmax5<<<dim3(4096, 2), dim3(256), 0, stream>>>(D + CN, 4 * CN, Bp, CN);
  vmax5<<<dim3(4096, 2), dim3(256), 0, stream>>>(Bp, CN, D + 2 * CN, 4 * CN);
  hmax5<<<dim3(4096, 2), dim3(256), 0, stream>>>(D + 2 * CN, 4 * CN, Bp, CN);
  vmax5<<<dim3(4096, 2), dim3(256), 0, stream>>>(Bp, CN, D + 3 * CN, 4 * CN);

  mfma_cbs<1,0><<<dim3(32, 4, 2), dim3(256), 0, stream>>>(s5_w, 0, D, 4 * CN, Bp, CN, 256, 1024, 4096, s5_bn, nullptr);
  conv3_mfma<<<dim3(32, 4, 2), dim3(256), 0, stream>>>(wt3b, Bp, CN, D, 2 * CN, 256, 256, s6_bn);
  mfma_cbs<1,0><<<dim3(32, 4, 2), dim3(256), 0, stream>>>(s2_w, 0, A, CN, D + CN, 2 * CN, 256, 256, 4096, s2_bn, nullptr);
  mfma_cbs<1,0><<<dim3(32, 4, 2), dim3(256), 0, stream>>>(s7_w, 0, D, 2 * CN, A, CN, 256, 512, 4096, s7_bn, nullptr);

  // ---- PAM ----
  gemm_cbs<0><<<dim3(64, 1, 2), dim3(256), 0, stream>>>(pq_w, 0, res, CN, q, 131072, 32, 256, 4096, nullptr, pq_b);
  gemm_cbs<0><<<dim3(64, 1, 2), dim3(256), 0, stream>>>(pk_w, 0, res, CN, k, 131072, 32, 256, 4096, nullptr, pk_b);
  mfma_cbs<0,1><<<dim3(32, 4, 2), dim3(256), 0, stream>>>(pv_w, 0, res, CN, (float*)vb, CN, 256, 256, 4096, nullptr, pv_b);

  transpose_h<<<dim3(128, 1, 2), dim3(256), 0, stream>>>(q, qTb, 32, 4096);
  transpose_h<<<dim3(128, 1, 2), dim3(256), 0, stream>>>(k, kTb, 32, 4096);

  pam_qk_max<<<dim3(128, 4, 2), dim3(256), 0, stream>>>(qTb, kTb, pmax);
  pam_merge<<<dim3(32), dim3(256), 0, stream>>>(pmax, rmx);
  pam_attn<<<dim3(128, 1, 2), dim3(512), 0, stream>>>(qTb, kTb, vb, rmx, pam);

  // ---- CAM ----
  fillz<<<dim3(512), dim3(256), 0, stream>>>(e, 131072);
  cam_e<<<dim3(4, 4, 16), dim3(256), 0, stream>>>(res, e);
  cam_softmax<<<dim3(256, 2), dim3(256), 0, stream>>>(e, attnc);
  mfma_cbs<0,0><<<dim3(32, 4, 2), dim3(256), 0, stream>>>(attnc, 65536, res, CN, cam, CN, 256, 256, 4096, nullptr, nullptr);

  // ---- combine ----
  combine<<<dim3(8192), dim3(256), 0, stream>>>(res, pam, cam, gammas, d_out, (const u16*)d_in[0]);
}

// Round 8
// 537.874 us; speedup vs baseline: 4.2042x; 1.3422x over previous
//
#include <hip/hip_runtime.h>

typedef unsigned short u16;
typedef __attribute__((ext_vector_type(8))) short bf16x8;
typedef __attribute__((ext_vector_type(4))) float f32x4;
#define EPSV 1e-5f
#define LOG2E 1.4426950408889634f

__device__ __forceinline__ float b2f(u16 u) {
  union { float f; unsigned int i; } v; v.i = ((unsigned int)u) << 16; return v.f;
}
__device__ __forceinline__ u16 f2b(float f) {
  union { float f; unsigned int i; } v; v.f = f;
  unsigned int r = v.i + 0x7FFFu + ((v.i >> 16) & 1u);
  return (u16)(r >> 16);
}
__device__ __forceinline__ u16 f2b_trunc(float f) {
  union { float f; unsigned int i; } v; v.f = f;
  return (u16)(v.i >> 16);
}
__device__ __forceinline__ float silu_(float z) { return z / (1.f + exp2f(-LOG2E * z)); }

// ---------------- dtype detect (ONCE, parallel) ----------------
__global__ __launch_bounds__(128) void detect_k(const u16* __restrict__ xp, float* __restrict__ flag) {
  __shared__ int cnt[2];
  int t = threadIdx.x;
  if (t < 2) cnt[t] = 0;
  __syncthreads();
  u16 u = xp[t * 2];
  int e = (u >> 7) & 0xff;
  if (e != 0 && (e < 90 || e > 160)) atomicAdd(&cnt[0], 1);
  if (u == 0) atomicAdd(&cnt[1], 1);
  __syncthreads();
  if (t == 0) *flag = (cnt[0] > 16 || cnt[1] > 64) ? 1.f : 0.f;
}

// ---------------- input conversion ----------------

struct ConvArgs {
  const void* src[30];
  long dst[30];
  int end[30];
  int mode[30];
};

__global__ __launch_bounds__(256) void convert_all(ConvArgs a, float* __restrict__ wsF,
                                                   u16* __restrict__ wsH,
                                                   const float* __restrict__ flagp, int total) {
  const int flag = (*flagp > 0.5f);
  int gid = blockIdx.x * 256 + threadIdx.x;
  if (gid >= total) return;
  #pragma unroll 1
  for (int s = 0; s < 30; ++s) {
    if (gid < a.end[s]) {
      int idx = gid - (s ? a.end[s - 1] : 0);
      if (a.mode[s] == 0) {
        float v = flag ? ((const float*)a.src[s])[idx] : b2f(((const u16*)a.src[s])[idx]);
        wsF[a.dst[s] + idx] = v;
      } else {
        u16 h = flag ? f2b(((const float*)a.src[s])[idx]) : ((const u16*)a.src[s])[idx];
        wsH[a.dst[s] + idx] = h;
      }
      return;
    }
  }
}

// conv3 weight transform: fp32 W[o][I][3][3] -> bf16 Wt[I/32][tap][256o][32ch]
__global__ __launch_bounds__(256) void w3t(const float* __restrict__ Wsrc, u16* __restrict__ Wdst) {
  int idx = blockIdx.x * 256 + threadIdx.x;
  int ch = idx & 31;
  int o  = (idx >> 5) & 255;
  int tap = (idx >> 13) % 9;
  int c8 = (idx >> 13) / 9;
  int i = c8 * 32 + ch;
  Wdst[idx] = f2b(Wsrc[((long)o * 256 + i) * 9 + tap]);
}

// fp32 -> bf16 bulk convert (8 elems/thread)
__global__ __launch_bounds__(256) void cvtb(const float* __restrict__ src, u16* __restrict__ dst, int n8) {
  int i = blockIdx.x * 256 + threadIdx.x;
  if (i >= n8) return;
  float4 f0 = *(const float4*)(src + (long)i * 8);
  float4 f1 = *(const float4*)(src + (long)i * 8 + 4);
  union { u16 h[8]; uint4 q; } u;
  u.h[0]=f2b(f0.x); u.h[1]=f2b(f0.y); u.h[2]=f2b(f0.z); u.h[3]=f2b(f0.w);
  u.h[4]=f2b(f1.x); u.h[5]=f2b(f1.y); u.h[6]=f2b(f1.z); u.h[7]=f2b(f1.w);
  *(uint4*)(dst + (long)i * 8) = u.q;
}

// ---------------- CoordAtt ----------------

__global__ __launch_bounds__(256) void plane_means(const float* __restrict__ x, float* __restrict__ yin) {
  __shared__ float pl[4096];
  int bc = blockIdx.x, t = threadIdx.x;
  const float* xp = x + (long)bc * 4096;
  for (int j = 0; j < 16; ++j) { int id = j * 256 + t; pl[id] = xp[id]; }
  __syncthreads();
  if (t < 64) {
    float s = 0.f;
    for (int w = 0; w < 64; ++w) s += pl[t * 64 + w];
    yin[(long)bc * 128 + t] = s * (1.f / 64.f);
  } else if (t < 128) {
    int w = t - 64; float s = 0.f;
    for (int h = 0; h < 64; ++h) s += pl[h * 64 + w];
    yin[(long)bc * 128 + 64 + w] = s * (1.f / 64.f);
  }
}

__global__ __launch_bounds__(128) void ca_conv1(const float* __restrict__ yin, const float* __restrict__ w1,
                                                const float* __restrict__ b1, const float* __restrict__ bnp,
                                                float* __restrict__ ybn) {
  int b = blockIdx.x, p = threadIdx.x;
  float acc[8] = {0.f,0.f,0.f,0.f,0.f,0.f,0.f,0.f};
  for (int c = 0; c < 256; ++c) {
    float yv = yin[((long)b * 256 + c) * 128 + p];
    #pragma unroll
    for (int o = 0; o < 8; ++o) acc[o] += w1[o * 256 + c] * yv;
  }
  #pragma unroll
  for (int o = 0; o < 8; ++o) {
    float z = acc[o] + b1[o];
    float g = bnp[o], bt = bnp[8 + o], mn = bnp[16 + o], vr = bnp[24 + o];
    float s = g * rsqrtf(vr + EPSV);
    z = z * s + (bt - mn * s);
    float hs = fminf(fmaxf(z + 3.f, 0.f), 6.f) * (1.f / 6.f);
    ybn[((long)b * 8 + o) * 128 + p] = z * hs;
  }
}

__global__ __launch_bounds__(128) void ca_gate(const float* __restrict__ ybn,
    const float* __restrict__ wh, const float* __restrict__ bh,
    const float* __restrict__ ww, const float* __restrict__ bw,
    float* __restrict__ ah, float* __restrict__ aw_) {
  int c = blockIdx.x, b = blockIdx.y, t = threadIdx.x;
  if (t < 64) {
    float d = 0.f;
    #pragma unroll
    for (int o = 0; o < 8; ++o) d += wh[c * 8 + o] * ybn[((long)b * 8 + o) * 128 + t];
    d += bh[c];
    ah[((long)b * 256 + c) * 64 + t] = 1.f / (1.f + exp2f(-LOG2E * d));
  } else {
    int w = t - 64;
    float d = 0.f;
    #pragma unroll
    for (int o = 0; o < 8; ++o) d += ww[c * 8 + o] * ybn[((long)b * 8 + o) * 128 + 64 + w];
    d += bw[c];
    aw_[((long)b * 256 + c) * 64 + w] = 1.f / (1.f + exp2f(-LOG2E * d));
  }
}

__global__ __launch_bounds__(256) void apply_ca(const float* __restrict__ x, const float* __restrict__ ah,
                                                const float* __restrict__ aw_, float* __restrict__ r) {
  int idx = blockIdx.x * 256 + threadIdx.x;
  int n = idx & 4095, bc = idx >> 12;
  int h = n >> 6, w = n & 63;
  r[idx] = x[idx] * ah[bc * 64 + h] * aw_[bc * 64 + w];
}

// ---------------- MFMA 1x1 conv; OUTH=1 -> bf16 output ----------------

template<int ACT, int OUTH>
__global__ __launch_bounds__(256) void mfma_cbs(
    const u16* __restrict__ Wbf, long aBS,
    const float* __restrict__ In, long bBS,
    float* __restrict__ Out, long oBS,
    int O, int K, int N,
    const float* __restrict__ bnp, const float* __restrict__ bias)
{
  __shared__ u16 As[64 * 40];
  __shared__ u16 Bs[128 * 40];
  __shared__ float albe[64][2];
  const int t = threadIdx.x;
  const int n0 = blockIdx.x * 128;
  const int o0 = blockIdx.y * 64;
  const int b  = blockIdx.z;
  const int w = t >> 6, l = t & 63, lq = l >> 4, lr = l & 15;
  const int wo = (w >> 1) * 32, wn = (w & 1) * 64;
  if (t < 64) {
    int o = o0 + t;
    float al = 1.f, be = 0.f;
    if (bnp) {
      float g = bnp[o], bt = bnp[O + o], mn = bnp[2 * O + o], vr = bnp[3 * O + o];
      al = g * rsqrtf(vr + EPSV); be = bt - mn * al;
    }
    if (bias) be += bias[o];
    albe[t][0] = al; albe[t][1] = be;
  }
  const u16* Ab = Wbf + (long)b * aBS;
  const float* inb = In + (long)b * bBS + n0;
  const int ao = t >> 2, akq = (t & 3) * 8;
  const int bk = t >> 3, bc8 = t & 7;
  f32x4 acc[2][4] = {};
  for (int kc = 0; kc < K; kc += 32) {
    __syncthreads();
    *(uint4*)&As[ao * 40 + akq] = *(const uint4*)(Ab + (long)(o0 + ao) * K + kc + akq);
    const float* src = inb + (long)(kc + bk) * N + bc8 * 4;
    u16 tmp[16];
    #pragma unroll
    for (int i = 0; i < 4; ++i) {
      float4 f = *(const float4*)(src + i * 32);
      tmp[i*4+0] = f2b(f.x); tmp[i*4+1] = f2b(f.y); tmp[i*4+2] = f2b(f.z); tmp[i*4+3] = f2b(f.w);
    }
    #pragma unroll
    for (int i = 0; i < 4; ++i) {
      int n = bc8 * 4 + i * 32;
      #pragma unroll
      for (int j = 0; j < 4; ++j) Bs[(n + j) * 40 + bk] = tmp[i * 4 + j];
    }
    __syncthreads();
    bf16x8 af[2], bfv[4];
    #pragma unroll
    for (int i = 0; i < 2; ++i) af[i] = *(const bf16x8*)&As[(wo + i * 16 + lr) * 40 + lq * 8];
    #pragma unroll
    for (int j = 0; j < 4; ++j) bfv[j] = *(const bf16x8*)&Bs[(wn + j * 16 + lr) * 40 + lq * 8];
    #pragma unroll
    for (int i = 0; i < 2; ++i)
      #pragma unroll
      for (int j = 0; j < 4; ++j)
        acc[i][j] = __builtin_amdgcn_mfma_f32_16x16x32_bf16(af[i], bfv[j], acc[i][j], 0, 0, 0);
  }
  float* ob = Out + (long)b * oBS;
  u16* obh = (u16*)Out + (long)b * oBS;
  #pragma unroll
  for (int i = 0; i < 2; ++i) {
    #pragma unroll
    for (int r = 0; r < 4; ++r) {
      int ol = wo + i * 16 + lq * 4 + r;
      float al = albe[ol][0], be = albe[ol][1];
      #pragma unroll
      for (int j = 0; j < 4; ++j) {
        float vv = acc[i][j][r] * al + be;
        if (ACT) vv = silu_(vv);
        if (OUTH) obh[(long)(o0 + ol) * N + n0 + wn + j * 16 + lr] = f2b(vv);
        else      ob[(long)(o0 + ol) * N + n0 + wn + j * 16 + lr] = vv;
      }
    }
  }
}

// ---------------- MFMA 3x3 conv (implicit GEMM over 9 shifted taps) ----------------
__global__ __launch_bounds__(256) void conv3_mfma(
    const u16* __restrict__ Wt,
    const float* __restrict__ In, long iBS,
    float* __restrict__ Out, long oBS, int O, int I,
    const float* __restrict__ bnp)
{
  __shared__ u16 As[9 * 64 * 34];
  __shared__ u16 Bs[4 * 66 * 34];
  __shared__ float albe[64][2];
  const int t = threadIdx.x;
  const int h0 = blockIdx.x * 2;
  const int o0 = blockIdx.y * 64;
  const int b  = blockIdx.z;
  const int w = t >> 6, l = t & 63, lq = l >> 4, lr = l & 15;
  const int wo = (w >> 1) * 32, wn = (w & 1) * 64;
  if (t < 64) {
    int o = o0 + t;
    float g = bnp[o], bt = bnp[O + o], mn = bnp[2 * O + o], vr = bnp[3 * O + o];
    float al = g * rsqrtf(vr + EPSV);
    albe[t][0] = al; albe[t][1] = bt - mn * al;
  }
  {
    int r = t >> 6, cs = (t >> 5) & 1, ch = t & 31;
    Bs[(r * 66 + (cs ? 65 : 0)) * 34 + ch] = 0;
  }
  const float* inb = In + (long)b * iBS;
  const int bch = t >> 3, bcg = (t & 7) * 8;
  f32x4 acc[2][4] = {};
  for (int c8 = 0; c8 < (I >> 5); ++c8) {
    __syncthreads();
    {
      const u16* wsrc = Wt + (long)c8 * 9 * 256 * 32;
      #pragma unroll
      for (int j = 0; j < 9; ++j) {
        int e = j * 2048 + t * 8;
        int tap = e >> 11, o = (e >> 5) & 63, ch0 = e & 31;
        uint4 vv = *(const uint4*)(wsrc + ((long)tap * 256 + o0 + o) * 32 + ch0);
        *(uint4*)&As[(tap * 64 + o) * 34 + ch0] = vv;
      }
    }
    {
      const float* cbase = inb + (long)(c8 * 32 + bch) * 4096;
      #pragma unroll
      for (int r = 0; r < 4; ++r) {
        int row = h0 - 1 + r;
        u16 hv[8];
        if (row >= 0 && row < 64) {
          float4 f0 = *(const float4*)(cbase + row * 64 + bcg);
          float4 f1 = *(const float4*)(cbase + row * 64 + bcg + 4);
          hv[0]=f2b(f0.x); hv[1]=f2b(f0.y); hv[2]=f2b(f0.z); hv[3]=f2b(f0.w);
          hv[4]=f2b(f1.x); hv[5]=f2b(f1.y); hv[6]=f2b(f1.z); hv[7]=f2b(f1.w);
        } else {
          #pragma unroll
          for (int j2 = 0; j2 < 8; ++j2) hv[j2] = 0;
        }
        #pragma unroll
        for (int j2 = 0; j2 < 8; ++j2)
          Bs[(r * 66 + bcg + 1 + j2) * 34 + bch] = hv[j2];
      }
    }
    __syncthreads();
    #pragma unroll
    for (int dy = 0; dy < 3; ++dy) {
      #pragma unroll
      for (int dx = 0; dx < 3; ++dx) {
        const int tap = dy * 3 + dx;
        bf16x8 af0 = *(const bf16x8*)&As[(tap * 64 + wo + lr) * 34 + lq * 8];
        bf16x8 af1 = *(const bf16x8*)&As[(tap * 64 + wo + 16 + lr) * 34 + lq * 8];
        #pragma unroll
        for (int j = 0; j < 4; ++j) {
          int nb = wn + j * 16;
          int rowS = (nb >> 6) + dy;
          int colS = (nb & 63) + dx;
          bf16x8 bv = *(const bf16x8*)&Bs[(rowS * 66 + colS + lr) * 34 + lq * 8];
          acc[0][j] = __builtin_amdgcn_mfma_f32_16x16x32_bf16(af0, bv, acc[0][j], 0, 0, 0);
          acc[1][j] = __builtin_amdgcn_mfma_f32_16x16x32_bf16(af1, bv, acc[1][j], 0, 0, 0);
        }
      }
    }
  }
  float* ob = Out + (long)b * oBS;
  const int n0 = h0 * 64;
  #pragma unroll
  for (int i = 0; i < 2; ++i) {
    #pragma unroll
    for (int r = 0; r < 4; ++r) {
      int ol = wo + i * 16 + lq * 4 + r;
      float al = albe[ol][0], be = albe[ol][1];
      #pragma unroll
      for (int j = 0; j < 4; ++j) {
        float vv = silu_(acc[i][j][r] * al + be);
        ob[(long)(o0 + ol) * 4096 + n0 + wn + j * 16 + lr] = vv;
      }
    }
  }
}

// ---------------- max pools ----------------

__global__ __launch_bounds__(256) void hmax5(const float* __restrict__ src, long sBS,
                                             float* __restrict__ dst, long dBS) {
  int t = blockIdx.x * 256 + threadIdx.x;
  int b = blockIdx.y;
  int n = t & 4095, c = t >> 12;
  int w = n & 63;
  const float* p = src + (long)b * sBS + (long)c * 4096 + (n - w);
  float m = p[w];
  if (w >= 1) m = fmaxf(m, p[w - 1]);
  if (w >= 2) m = fmaxf(m, p[w - 2]);
  if (w <= 62) m = fmaxf(m, p[w + 1]);
  if (w <= 61) m = fmaxf(m, p[w + 2]);
  dst[(long)b * dBS + t] = m;
}

__global__ __launch_bounds__(256) void vmax5(const float* __restrict__ src, long sBS,
                                             float* __restrict__ dst, long dBS) {
  int t = blockIdx.x * 256 + threadIdx.x;
  int b = blockIdx.y;
  int n = t & 4095, c = t >> 12;
  int h = n >> 6, w = n & 63;
  const float* p = src + (long)b * sBS + (long)c * 4096 + w;
  float m = p[h * 64];
  if (h >= 1) m = fmaxf(m, p[(h - 1) * 64]);
  if (h >= 2) m = fmaxf(m, p[(h - 2) * 64]);
  if (h <= 62) m = fmaxf(m, p[(h + 1) * 64]);
  if (h <= 61) m = fmaxf(m, p[(h + 2) * 64]);
  dst[(long)b * dBS + t] = m;
}

// ---------------- bf16 transpose: (B,64,4096) -> (B,4096,64) ----------------
__global__ __launch_bounds__(256) void transpose_hh(const u16* __restrict__ in, u16* __restrict__ out) {
  __shared__ u16 tile[32][34];
  int b = blockIdx.z;
  int c0 = blockIdx.x * 32, r0 = blockIdx.y * 32;
  int tx = threadIdx.x & 31, ty = threadIdx.x >> 5;
  const u16* ib = in + (long)b * 262144;
  u16* ob = out + (long)b * 262144;
  #pragma unroll
  for (int i = 0; i < 4; ++i) {
    int r = r0 + ty + i * 8;
    tile[ty + i * 8][tx] = ib[(long)r * 4096 + c0 + tx];
  }
  __syncthreads();
  #pragma unroll
  for (int i = 0; i < 4; ++i) {
    int c = c0 + ty + i * 8;
    ob[(long)c * 64 + r0 + tx] = tile[tx][ty + i * 8];
  }
}

// ---------------- PAM row-max via MFMA (qkT: [b][4096][64], q cols 0-31, k cols 32-63) ----------------
__global__ __launch_bounds__(256) void pam_qk_max(const u16* __restrict__ qkT, float* __restrict__ pmax) {
  __shared__ u16 Qs[32 * 40];
  __shared__ u16 Ks[64 * 40];
  __shared__ float red[4][32][17];
  const int t = threadIdx.x;
  const int b = blockIdx.z, ms = blockIdx.y, n0 = blockIdx.x * 32;
  const int w = t >> 6, l = t & 63, lq = l >> 4, lr = l & 15;
  const int wn = w & 1, wc = w >> 1;
  if (t < 128) {
    int row = t >> 2, cq = (t & 3) * 8;
    *(uint4*)&Qs[row * 40 + cq] = *(const uint4*)(qkT + ((long)b * 4096 + n0 + row) * 64 + cq);
  }
  __syncthreads();
  bf16x8 qf = *(const bf16x8*)&Qs[(wn * 16 + lr) * 40 + lq * 8];
  float mx4[4] = {-1e30f, -1e30f, -1e30f, -1e30f};
  const int krow = t >> 2, kcq = (t & 3) * 8;
  for (int it = 0; it < 16; ++it) {
    int m0 = ms * 1024 + it * 64;
    __syncthreads();
    *(uint4*)&Ks[krow * 40 + kcq] = *(const uint4*)(qkT + ((long)b * 4096 + m0 + krow) * 64 + 32 + kcq);
    __syncthreads();
    #pragma unroll
    for (int s = 0; s < 2; ++s) {
      int msub = wc * 2 + s;
      bf16x8 kf = *(const bf16x8*)&Ks[(msub * 16 + lr) * 40 + lq * 8];
      f32x4 S = {};
      S = __builtin_amdgcn_mfma_f32_16x16x32_bf16(qf, kf, S, 0, 0, 0);
      #pragma unroll
      for (int r = 0; r < 4; ++r) mx4[r] = fmaxf(mx4[r], S[r]);
    }
  }
  #pragma unroll
  for (int r = 0; r < 4; ++r) red[w][wn * 16 + lq * 4 + r][lr] = mx4[r];
  __syncthreads();
  if (t < 32) {
    int wbase = t >> 4;
    float M = -1e30f;
    #pragma unroll
    for (int j = 0; j < 2; ++j)
      #pragma unroll
      for (int l2 = 0; l2 < 16; ++l2)
        M = fmaxf(M, red[wbase + 2 * j][t][l2]);
    pmax[((long)ms * 2 + b) * 4096 + n0 + t] = M;
  }
}

__global__ __launch_bounds__(256) void pam_merge(const float* __restrict__ pmax, float* __restrict__ rmx) {
  int i = blockIdx.x * 256 + threadIdx.x;
  int b = i >> 12, n = i & 4095;
  float m = pmax[(long)b * 4096 + n];
  #pragma unroll
  for (int ms = 1; ms < 4; ++ms) m = fmaxf(m, pmax[((long)ms * 2 + b) * 4096 + n]);
  rmx[i] = m;
}

// ---------------- PAM attention: one block covers all 256 c ----------------
__global__ __launch_bounds__(512) void pam_attn(const u16* __restrict__ qkT,
    const u16* __restrict__ vb, const float* __restrict__ rowmax, float* __restrict__ pam) {
  __shared__ u16 Qs[32 * 40];
  __shared__ u16 Ks[64 * 40];
  __shared__ u16 Vs[256 * 72];
  __shared__ u16 Ps[32 * 72];
  __shared__ float rmL[32];
  __shared__ float srow[32];
  const int t = threadIdx.x;
  const int b = blockIdx.z;
  const int n0 = blockIdx.x * 32;
  const int w = t >> 6, l = t & 63, lq = l >> 4, lr = l & 15;
  const int nf = w & 1;
  const int mf = w >> 1;
  const int cw = w * 32;
  if (t < 128) {
    int row = t >> 2, cq = (t & 3) * 8;
    *(uint4*)&Qs[row * 40 + cq] = *(const uint4*)(qkT + ((long)b * 4096 + n0 + row) * 64 + cq);
  }
  if (t < 32) { rmL[t] = rowmax[(long)b * 4096 + n0 + t] * LOG2E; srow[t] = 0.f; }
  __syncthreads();
  bf16x8 qf = *(const bf16x8*)&Qs[(nf * 16 + lr) * 40 + lq * 8];
  float rm4[4];
  #pragma unroll
  for (int r = 0; r < 4; ++r) rm4[r] = rmL[nf * 16 + lq * 4 + r];
  float sp[4] = {0.f, 0.f, 0.f, 0.f};
  f32x4 acc[2][2] = {};
  const int krow = t >> 3, kc4 = (t & 7) * 4;
  const int vcc = t >> 1, vm = (t & 1) * 32;
  const u16* kbase = qkT + ((long)b * 4096 + krow) * 64 + 32 + kc4;
  const u16* vbase = vb + ((long)b * 256 + vcc) * 4096 + vm;
  for (int m0 = 0; m0 < 4096; m0 += 64) {
    __syncthreads();
    *(uint2*)&Ks[krow * 40 + kc4] = *(const uint2*)(kbase + (long)m0 * 64);
    {
      const u16* src = vbase + m0;
      u16* dst = &Vs[vcc * 72 + vm];
      #pragma unroll
      for (int i = 0; i < 4; ++i) *(uint4*)(dst + i * 8) = *(const uint4*)(src + i * 8);
    }
    __syncthreads();
    {
      bf16x8 kf = *(const bf16x8*)&Ks[(mf * 16 + lr) * 40 + lq * 8];
      f32x4 S = {};
      S = __builtin_amdgcn_mfma_f32_16x16x32_bf16(qf, kf, S, 0, 0, 0);
      #pragma unroll
      for (int r = 0; r < 4; ++r) {
        float p = exp2f(S[r] * LOG2E - rm4[r]);
        sp[r] += p;
        Ps[(nf * 16 + lq * 4 + r) * 72 + mf * 16 + lr] = f2b_trunc(p);
      }
    }
    __syncthreads();
    #pragma unroll
    for (int ks = 0; ks < 2; ++ks) {
      bf16x8 pf0 = *(const bf16x8*)&Ps[lr * 72 + ks * 32 + lq * 8];
      bf16x8 pf1 = *(const bf16x8*)&Ps[(16 + lr) * 72 + ks * 32 + lq * 8];
      #pragma unroll
      for (int cf = 0; cf < 2; ++cf) {
        bf16x8 vf = *(const bf16x8*)&Vs[(cw + cf * 16 + lr) * 72 + ks * 32 + lq * 8];
        acc[cf][0] = __builtin_amdgcn_mfma_f32_16x16x32_bf16(vf, pf0, acc[cf][0], 0, 0, 0);
        acc[cf][1] = __builtin_amdgcn_mfma_f32_16x16x32_bf16(vf, pf1, acc[cf][1], 0, 0, 0);
      }
    }
  }
  #pragma unroll
  for (int r = 0; r < 4; ++r) {
    float s = sp[r];
    s += __shfl_xor(s, 1); s += __shfl_xor(s, 2);
    s += __shfl_xor(s, 4); s += __shfl_xor(s, 8);
    if (lr == 0) atomicAdd(&srow[nf * 16 + lq * 4 + r], s);
  }
  __syncthreads();
  float inv0 = 1.f / srow[lr];
  float inv1 = 1.f / srow[16 + lr];
  float* ob = pam + (long)b * (256L * 4096) + n0;
  #pragma unroll
  for (int cf = 0; cf < 2; ++cf) {
    #pragma unroll
    for (int r = 0; r < 4; ++r) {
      int c = cw + cf * 16 + lq * 4 + r;
      ob[(long)c * 4096 + lr]      = acc[cf][0][r] * inv0;
      ob[(long)c * 4096 + 16 + lr] = acc[cf][1][r] * inv1;
    }
  }
}

// ---------------- CAM ----------------

__global__ __launch_bounds__(256) void fillz(float* __restrict__ p, int n) {
  int i = blockIdx.x * 256 + threadIdx.x;
  if (i < n) p[i] = 0.f;
}

// e[b,c,d] += sum_k resb[c,k]*resb[d,k] over this block's K slice (MFMA, split-K x8)
__global__ __launch_bounds__(256) void cam_e_mfma(const u16* __restrict__ resb, float* __restrict__ e) {
  __shared__ u16 As[64 * 40];
  __shared__ u16 Bs[128 * 40];
  const int t = threadIdx.x;
  const int d0 = blockIdx.x * 128;
  const int c0 = blockIdx.y * 64;
  const int bz = blockIdx.z;
  const int b = bz >> 3, ks = bz & 7;
  const int w = t >> 6, l = t & 63, lq = l >> 4, lr = l & 15;
  const int wo = (w >> 1) * 32, wn = (w & 1) * 64;
  const u16* fb = resb + (long)b * 1048576;
  const int ao = t >> 2, akq = (t & 3) * 8;
  const int bo = t >> 1, bkq = (t & 1) * 16;
  f32x4 acc[2][4] = {};
  for (int kc = ks * 512; kc < ks * 512 + 512; kc += 32) {
    __syncthreads();
    *(uint4*)&As[ao * 40 + akq] = *(const uint4*)(fb + (long)(c0 + ao) * 4096 + kc + akq);
    #pragma unroll
    for (int i = 0; i < 2; ++i)
      *(uint4*)&Bs[bo * 40 + bkq + i * 8] = *(const uint4*)(fb + (long)(d0 + bo) * 4096 + kc + bkq + i * 8);
    __syncthreads();
    bf16x8 af[2], bfv[4];
    #pragma unroll
    for (int i = 0; i < 2; ++i) af[i] = *(const bf16x8*)&As[(wo + i * 16 + lr) * 40 + lq * 8];
    #pragma unroll
    for (int j = 0; j < 4; ++j) bfv[j] = *(const bf16x8*)&Bs[(wn + j * 16 + lr) * 40 + lq * 8];
    #pragma unroll
    for (int i = 0; i < 2; ++i)
      #pragma unroll
      for (int j = 0; j < 4; ++j)
        acc[i][j] = __builtin_amdgcn_mfma_f32_16x16x32_bf16(af[i], bfv[j], acc[i][j], 0, 0, 0);
  }
  #pragma unroll
  for (int i = 0; i < 2; ++i)
    #pragma unroll
    for (int r = 0; r < 4; ++r) {
      int ol = wo + i * 16 + lq * 4 + r;
      #pragma unroll
      for (int j = 0; j < 4; ++j)
        atomicAdd(&e[((long)b << 16) + (long)(c0 + ol) * 256 + d0 + wn + j * 16 + lr], acc[i][j][r]);
    }
}

__global__ __launch_bounds__(256) void cam_softmax(const float* __restrict__ e, u16* __restrict__ attn) {
  __shared__ float red[256];
  int c = blockIdx.x, b = blockIdx.y, t = threadIdx.x;
  const float* row = e + ((long)b << 16) + (long)c * 256;
  float v = row[t];
  red[t] = v; __syncthreads();
  for (int s = 128; s > 0; s >>= 1) { if (t < s) red[t] = fminf(red[t], red[t + s]); __syncthreads(); }
  float emin = red[0]; __syncthreads();
  float ex = exp2f(LOG2E * (emin - v));
  red[t] = ex; __syncthreads();
  for (int s = 128; s > 0; s >>= 1) { if (t < s) red[t] += red[t + s]; __syncthreads(); }
  float inv = 1.f / red[0];
  attn[((long)b << 16) + (long)c * 256 + t] = f2b(ex * inv);
}

// ---------------- final combine ----------------

__global__ __launch_bounds__(256) void combine(const float* __restrict__ res, const float* __restrict__ pam,
    const float* __restrict__ cam, const float* __restrict__ gp,
    void* __restrict__ outp, const float* __restrict__ flagp) {
  int idx = blockIdx.x * 256 + threadIdx.x;
  float g1 = gp[0], g2 = gp[1];
  float v = 3.f * res[idx] + g1 * pam[idx] + g2 * cam[idx];
  if (*flagp > 0.5f) ((float*)outp)[idx] = v;
  else               ((u16*)outp)[idx] = f2b(v);
}

// ---------------- launch ----------------

extern "C" void kernel_launch(void* const* d_in, const int* in_sizes, int n_in,
                              void* d_out, int out_size, void* d_ws, size_t ws_size,
                              hipStream_t stream)
{
  (void)out_size; (void)ws_size; (void)n_in;
  float* ws = (float*)d_ws;
  const long CN = 256L * 4096;

  float* A  = ws;            // r -> res
  float* Bp = ws + 2 * CN;   // x_f32 -> s1out -> pool tmp -> s5out
  float* Cp = ws + 4 * CN;   // CoordAtt smalls -> s3out -> {vb (bf16)}
  float* D  = ws + 6 * CN;   // cat(8CN) -> {y12, attn smalls, resb} -> {pam, cam}
  const long WFo = 14 * CN;

  float* yin = Cp;
  float* ybn = Cp + 65536;
  float* ah  = Cp + 67584;
  float* aw_ = Cp + 100352;

  u16* vb  = (u16*)Cp;                      // [B][256][4096] bf16

  u16*   qkb  = (u16*)(D + 4 * CN);         // [B][64][4096] bf16
  u16*   qkT  = (u16*)(D + 4 * CN + 131072);// [B][4096][64] bf16 (262144 u16/b)
  float* pmax = D + 4 * CN + 1048576;
  float* rmx  = D + 4 * CN + 1081344;
  float* e    = D + 4 * CN + 1089536;
  u16*   attnc= (u16*)(D + 4 * CN + 1220608);
  u16*   resb = (u16*)(D + 6 * CN);         // [B][256][4096] bf16

  float* res = A;
  float* pam = D;
  float* cam = D + 2 * CN;

  ConvArgs ca;
  long fOff[30], hOff[30];
  long hcur = 0;
  float* flagp = ws + WFo;     // dtype flag slot
  {
    long cum = 0, fcur = WFo + 4;
    for (int i = 0; i < 30; ++i) {
      ca.src[i] = d_in[i];
      int h = (i == 8 || i == 10 || i == 14 || i == 16 || i == 20 ||
               i == 22 || i == 24 || i == 26) ? 1 : 0;
      ca.mode[i] = h;
      if (i == 0) { ca.dst[i] = 2 * CN; fOff[i] = 2 * CN; }
      else if (h) { ca.dst[i] = hcur; hOff[i] = hcur; hcur += in_sizes[i]; }
      else        { ca.dst[i] = fcur; fOff[i] = fcur; fcur += in_sizes[i]; }
      cum += in_sizes[i];
      ca.end[i] = (int)cum;
    }
  }
  long fTotal = WFo + 4;
  for (int i = 1; i < 30; ++i) if (!ca.mode[i]) fTotal = (fOff[i] + in_sizes[i] > fTotal) ? fOff[i] + in_sizes[i] : fTotal;
  u16* wsH = (u16*)(ws + fTotal);
  long wt3aOff = hcur;
  long wt3bOff = hcur + 589824;
  u16* wt3a = wsH + wt3aOff;
  u16* wt3b = wsH + wt3bOff;
  int total = ca.end[29];

  detect_k<<<dim3(1), dim3(128), 0, stream>>>((const u16*)d_in[0], flagp);
  convert_all<<<dim3((total + 255) / 256), dim3(256), 0, stream>>>(ca, ws, wsH, flagp, total);

  float* xf    = Bp;
  float* ca_w1 = ws + fOff[1];
  float* ca_b1 = ws + fOff[2];
  float* ca_bn = ws + fOff[3];
  float* ca_wh = ws + fOff[4];
  float* ca_bh = ws + fOff[5];
  float* ca_ww = ws + fOff[6];
  float* ca_bw = ws + fOff[7];
  u16*   s1_w  = wsH + hOff[8];   float* s1_bn = ws + fOff[9];
  u16*   s2_w  = wsH + hOff[10];  float* s2_bn = ws + fOff[11];
  float* s3_wf = ws + fOff[12];   float* s3_bn = ws + fOff[13];
  u16*   s4_w  = wsH + hOff[14];  float* s4_bn = ws + fOff[15];
  u16*   s5_w  = wsH + hOff[16];  float* s5_bn = ws + fOff[17];
  float* s6_wf = ws + fOff[18];   float* s6_bn = ws + fOff[19];
  u16*   s7_w  = wsH + hOff[20];  float* s7_bn = ws + fOff[21];
  u16*   qk_w  = wsH + hOff[22];  // pq_w(32x256) + pk_w(32x256) contiguous -> [64][256]
  float* qk_b  = ws + fOff[23];   // pq_b(32) + pk_b(32) contiguous -> [64]
  u16*   pv_w  = wsH + hOff[26];  float* pv_b  = ws + fOff[27];
  float* gammas = ws + fOff[28];

  w3t<<<dim3(2304), dim3(256), 0, stream>>>(s3_wf, wt3a);
  w3t<<<dim3(2304), dim3(256), 0, stream>>>(s6_wf, wt3b);

  // ---- CoordAtt ----
  plane_means<<<dim3(512), dim3(256), 0, stream>>>(xf, yin);
  ca_conv1<<<dim3(2), dim3(128), 0, stream>>>(yin, ca_w1, ca_b1, ca_bn, ybn);
  ca_gate<<<dim3(256, 2), dim3(128), 0, stream>>>(ybn, ca_wh, ca_bh, ca_ww, ca_bw, ah, aw_);
  apply_ca<<<dim3(8192), dim3(256), 0, stream>>>(xf, ah, aw_, A);

  // ---- SPPCSPC ----
  mfma_cbs<1,0><<<dim3(32, 4, 2), dim3(256), 0, stream>>>(s1_w, 0, A, CN, Bp, CN, 256, 256, 4096, s1_bn, nullptr);
  conv3_mfma<<<dim3(32, 4, 2), dim3(256), 0, stream>>>(wt3a, Bp, CN, Cp, CN, 256, 256, s3_bn);
  mfma_cbs<1,0><<<dim3(32, 4, 2), dim3(256), 0, stream>>>(s4_w, 0, Cp, CN, D, 4 * CN, 256, 256, 4096, s4_bn, nullptr);

  hmax5<<<dim3(4096, 2), dim3(256), 0, stream>>>(D, 4 * CN, Bp, CN);
  vmax5<<<dim3(4096, 2), dim3(256), 0, stream>>>(Bp, CN, D + CN, 4 * CN);
  hmax5<<<dim3(4096, 2), dim3(256), 0, stream>>>(D + CN, 4 * CN, Bp, CN);
  vmax5<<<dim3(4096, 2), dim3(256), 0, stream>>>(Bp, CN, D + 2 * CN, 4 * CN);
  hmax5<<<dim3(4096, 2), dim3(256), 0, stream>>>(D + 2 * CN, 4 * CN, Bp, CN);
  vmax5<<<dim3(4096, 2), dim3(256), 0, stream>>>(Bp, CN, D + 3 * CN, 4 * CN);

  mfma_cbs<1,0><<<dim3(32, 4, 2), dim3(256), 0, stream>>>(s5_w, 0, D, 4 * CN, Bp, CN, 256, 1024, 4096, s5_bn, nullptr);
  conv3_mfma<<<dim3(32, 4, 2), dim3(256), 0, stream>>>(wt3b, Bp, CN, D, 2 * CN, 256, 256, s6_bn);
  mfma_cbs<1,0><<<dim3(32, 4, 2), dim3(256), 0, stream>>>(s2_w, 0, A, CN, D + CN, 2 * CN, 256, 256, 4096, s2_bn, nullptr);
  mfma_cbs<1,0><<<dim3(32, 4, 2), dim3(256), 0, stream>>>(s7_w, 0, D, 2 * CN, A, CN, 256, 512, 4096, s7_bn, nullptr);

  // ---- PAM ----
  mfma_cbs<0,1><<<dim3(32, 1, 2), dim3(256), 0, stream>>>(qk_w, 0, res, CN, (float*)qkb, 262144, 64, 256, 4096, nullptr, qk_b);
  mfma_cbs<0,1><<<dim3(32, 4, 2), dim3(256), 0, stream>>>(pv_w, 0, res, CN, (float*)vb, CN, 256, 256, 4096, nullptr, pv_b);
  transpose_hh<<<dim3(128, 2, 2), dim3(256), 0, stream>>>(qkb, qkT);

  pam_qk_max<<<dim3(128, 4, 2), dim3(256), 0, stream>>>(qkT, pmax);
  pam_merge<<<dim3(32), dim3(256), 0, stream>>>(pmax, rmx);
  pam_attn<<<dim3(128, 1, 2), dim3(512), 0, stream>>>(qkT, vb, rmx, pam);

  // ---- CAM ----
  cvtb<<<dim3(1024), dim3(256), 0, stream>>>(res, resb, 262144);
  fillz<<<dim3(512), dim3(256), 0, stream>>>(e, 131072);
  cam_e_mfma<<<dim3(2, 4, 16), dim3(256), 0, stream>>>(resb, e);
  cam_softmax<<<dim3(256, 2), dim3(256), 0, stream>>>(e, attnc);
  mfma_cbs<0,0><<<dim3(32, 4, 2), dim3(256), 0, stream>>>(attnc, 65536, res, CN, cam, CN, 256, 256, 4096, nullptr, nullptr);

  // ---- combine ----
  combine<<<dim3(8192), dim3(256), 0, stream>>>(res, pam, cam, gammas, d_out, flagp);
}

// Round 10
// 518.418 us; speedup vs baseline: 4.3620x; 1.0375x over previous
//
#include <hip/hip_runtime.h>

typedef unsigned short u16;
typedef __attribute__((ext_vector_type(8))) short bf16x8;
typedef __attribute__((ext_vector_type(4))) float f32x4;
#define EPSV 1e-5f
#define LOG2E 1.4426950408889634f

__device__ __forceinline__ float b2f(u16 u) {
  union { float f; unsigned int i; } v; v.i = ((unsigned int)u) << 16; return v.f;
}
__device__ __forceinline__ u16 f2b(float f) {
  union { float f; unsigned int i; } v; v.f = f;
  unsigned int r = v.i + 0x7FFFu + ((v.i >> 16) & 1u);
  return (u16)(r >> 16);
}
__device__ __forceinline__ u16 f2b_trunc(float f) {
  union { float f; unsigned int i; } v; v.f = f;
  return (u16)(v.i >> 16);
}
__device__ __forceinline__ float silu_(float z) { return z / (1.f + exp2f(-LOG2E * z)); }

// ---------------- dtype detect ----------------
__global__ __launch_bounds__(128) void detect_k(const u16* __restrict__ xp, float* __restrict__ flag) {
  __shared__ int cnt[2];
  int t = threadIdx.x;
  if (t < 2) cnt[t] = 0;
  __syncthreads();
  u16 u = xp[t * 2];
  int e = (u >> 7) & 0xff;
  if (e != 0 && (e < 90 || e > 160)) atomicAdd(&cnt[0], 1);
  if (u == 0) atomicAdd(&cnt[1], 1);
  __syncthreads();
  if (t == 0) *flag = (cnt[0] > 16 || cnt[1] > 64) ? 1.f : 0.f;
}

// ---------------- input conversion ----------------

struct ConvArgs {
  const void* src[30];
  long dst[30];
  int end[30];
  int mode[30];
};

__global__ __launch_bounds__(256) void convert_all(ConvArgs a, float* __restrict__ wsF,
                                                   u16* __restrict__ wsH,
                                                   const float* __restrict__ flagp, int total) {
  const int flag = (*flagp > 0.5f);
  int gid = blockIdx.x * 256 + threadIdx.x;
  if (gid >= total) return;
  #pragma unroll 1
  for (int s = 0; s < 30; ++s) {
    if (gid < a.end[s]) {
      int idx = gid - (s ? a.end[s - 1] : 0);
      if (a.mode[s] == 0) {
        float v = flag ? ((const float*)a.src[s])[idx] : b2f(((const u16*)a.src[s])[idx]);
        wsF[a.dst[s] + idx] = v;
      } else {
        u16 h = flag ? f2b(((const float*)a.src[s])[idx]) : ((const u16*)a.src[s])[idx];
        wsH[a.dst[s] + idx] = h;
      }
      return;
    }
  }
}

// conv3 weight transform: fp32 W[o][I][3][3] -> bf16 Wt[I/32][tap][256o][32ch]
__global__ __launch_bounds__(256) void w3t(const float* __restrict__ Wsrc, u16* __restrict__ Wdst) {
  int idx = blockIdx.x * 256 + threadIdx.x;
  int ch = idx & 31;
  int o  = (idx >> 5) & 255;
  int tap = (idx >> 13) % 9;
  int c8 = (idx >> 13) / 9;
  int i = c8 * 32 + ch;
  Wdst[idx] = f2b(Wsrc[((long)o * 256 + i) * 9 + tap]);
}

// fp32 -> bf16 bulk convert (8 elems/thread)
__global__ __launch_bounds__(256) void cvtb(const float* __restrict__ src, u16* __restrict__ dst, int n8) {
  int i = blockIdx.x * 256 + threadIdx.x;
  if (i >= n8) return;
  float4 f0 = *(const float4*)(src + (long)i * 8);
  float4 f1 = *(const float4*)(src + (long)i * 8 + 4);
  union { u16 h[8]; uint4 q; } u;
  u.h[0]=f2b(f0.x); u.h[1]=f2b(f0.y); u.h[2]=f2b(f0.z); u.h[3]=f2b(f0.w);
  u.h[4]=f2b(f1.x); u.h[5]=f2b(f1.y); u.h[6]=f2b(f1.z); u.h[7]=f2b(f1.w);
  *(uint4*)(dst + (long)i * 8) = u.q;
}

// ---------------- CoordAtt ----------------

__global__ __launch_bounds__(256) void plane_means(const float* __restrict__ x, float* __restrict__ yin) {
  __shared__ float pl[4096];
  int bc = blockIdx.x, t = threadIdx.x;
  const float* xp = x + (long)bc * 4096;
  for (int j = 0; j < 16; ++j) { int id = j * 256 + t; pl[id] = xp[id]; }
  __syncthreads();
  if (t < 64) {
    float s = 0.f;
    for (int w = 0; w < 64; ++w) s += pl[t * 64 + w];
    yin[(long)bc * 128 + t] = s * (1.f / 64.f);
  } else if (t < 128) {
    int w = t - 64; float s = 0.f;
    for (int h = 0; h < 64; ++h) s += pl[h * 64 + w];
    yin[(long)bc * 128 + 64 + w] = s * (1.f / 64.f);
  }
}

__global__ __launch_bounds__(128) void ca_conv1(const float* __restrict__ yin, const float* __restrict__ w1,
                                                const float* __restrict__ b1, const float* __restrict__ bnp,
                                                float* __restrict__ ybn) {
  int b = blockIdx.x, p = threadIdx.x;
  float acc[8] = {0.f,0.f,0.f,0.f,0.f,0.f,0.f,0.f};
  for (int c = 0; c < 256; ++c) {
    float yv = yin[((long)b * 256 + c) * 128 + p];
    #pragma unroll
    for (int o = 0; o < 8; ++o) acc[o] += w1[o * 256 + c] * yv;
  }
  #pragma unroll
  for (int o = 0; o < 8; ++o) {
    float z = acc[o] + b1[o];
    float g = bnp[o], bt = bnp[8 + o], mn = bnp[16 + o], vr = bnp[24 + o];
    float s = g * rsqrtf(vr + EPSV);
    z = z * s + (bt - mn * s);
    float hs = fminf(fmaxf(z + 3.f, 0.f), 6.f) * (1.f / 6.f);
    ybn[((long)b * 8 + o) * 128 + p] = z * hs;
  }
}

__global__ __launch_bounds__(128) void ca_gate(const float* __restrict__ ybn,
    const float* __restrict__ wh, const float* __restrict__ bh,
    const float* __restrict__ ww, const float* __restrict__ bw,
    float* __restrict__ ah, float* __restrict__ aw_) {
  int c = blockIdx.x, b = blockIdx.y, t = threadIdx.x;
  if (t < 64) {
    float d = 0.f;
    #pragma unroll
    for (int o = 0; o < 8; ++o) d += wh[c * 8 + o] * ybn[((long)b * 8 + o) * 128 + t];
    d += bh[c];
    ah[((long)b * 256 + c) * 64 + t] = 1.f / (1.f + exp2f(-LOG2E * d));
  } else {
    int w = t - 64;
    float d = 0.f;
    #pragma unroll
    for (int o = 0; o < 8; ++o) d += ww[c * 8 + o] * ybn[((long)b * 8 + o) * 128 + 64 + w];
    d += bw[c];
    aw_[((long)b * 256 + c) * 64 + w] = 1.f / (1.f + exp2f(-LOG2E * d));
  }
}

// r (bf16 out) = x * a_h * a_w
__global__ __launch_bounds__(256) void apply_ca(const float* __restrict__ x, const float* __restrict__ ah,
                                                const float* __restrict__ aw_, u16* __restrict__ r) {
  int idx = blockIdx.x * 256 + threadIdx.x;
  int n = idx & 4095, bc = idx >> 12;
  int h = n >> 6, w = n & 63;
  r[idx] = f2b(x[idx] * ah[bc * 64 + h] * aw_[bc * 64 + w]);
}

// ---------------- MFMA 1x1 conv: bf16 in; OUTH=1 -> bf16 out, else fp32 ----------------

template<int ACT, int OUTH>
__global__ __launch_bounds__(256) void mfma_cbs(
    const u16* __restrict__ Wbf, long aBS,
    const u16* __restrict__ In, long bBS,
    void* __restrict__ Out, long oBS,
    int O, int K, int N,
    const float* __restrict__ bnp, const float* __restrict__ bias)
{
  __shared__ u16 As[64 * 40];
  __shared__ u16 Bs[128 * 40];
  __shared__ float albe[64][2];
  const int t = threadIdx.x;
  const int n0 = blockIdx.x * 128;
  const int o0 = blockIdx.y * 64;
  const int b  = blockIdx.z;
  const int w = t >> 6, l = t & 63, lq = l >> 4, lr = l & 15;
  const int wo = (w >> 1) * 32, wn = (w & 1) * 64;
  if (t < 64) {
    int o = o0 + t;
    float al = 1.f, be = 0.f;
    if (bnp) {
      float g = bnp[o], bt = bnp[O + o], mn = bnp[2 * O + o], vr = bnp[3 * O + o];
      al = g * rsqrtf(vr + EPSV); be = bt - mn * al;
    }
    if (bias) be += bias[o];
    albe[t][0] = al; albe[t][1] = be;
  }
  const u16* Ab = Wbf + (long)b * aBS;
  const u16* inb = In + (long)b * bBS + n0;
  const int ao = t >> 2, akq = (t & 3) * 8;
  const int bk = t >> 3, bc8 = t & 7;
  f32x4 acc[2][4] = {};
  for (int kc = 0; kc < K; kc += 32) {
    __syncthreads();
    *(uint4*)&As[ao * 40 + akq] = *(const uint4*)(Ab + (long)(o0 + ao) * K + kc + akq);
    const u16* src = inb + (long)(kc + bk) * N + bc8 * 16;
    union { uint4 q[2]; u16 h[16]; } tb;
    tb.q[0] = *(const uint4*)src;
    tb.q[1] = *(const uint4*)(src + 8);
    #pragma unroll
    for (int j = 0; j < 16; ++j) Bs[(bc8 * 16 + j) * 40 + bk] = tb.h[j];
    __syncthreads();
    bf16x8 af[2], bfv[4];
    #pragma unroll
    for (int i = 0; i < 2; ++i) af[i] = *(const bf16x8*)&As[(wo + i * 16 + lr) * 40 + lq * 8];
    #pragma unroll
    for (int j = 0; j < 4; ++j) bfv[j] = *(const bf16x8*)&Bs[(wn + j * 16 + lr) * 40 + lq * 8];
    #pragma unroll
    for (int i = 0; i < 2; ++i)
      #pragma unroll
      for (int j = 0; j < 4; ++j)
        acc[i][j] = __builtin_amdgcn_mfma_f32_16x16x32_bf16(af[i], bfv[j], acc[i][j], 0, 0, 0);
  }
  float* ob = (float*)Out + (long)b * oBS;
  u16* obh = (u16*)Out + (long)b * oBS;
  #pragma unroll
  for (int i = 0; i < 2; ++i) {
    #pragma unroll
    for (int r = 0; r < 4; ++r) {
      int ol = wo + i * 16 + lq * 4 + r;
      float al = albe[ol][0], be = albe[ol][1];
      #pragma unroll
      for (int j = 0; j < 4; ++j) {
        float vv = acc[i][j][r] * al + be;
        if (ACT) vv = silu_(vv);
        if (OUTH) obh[(long)(o0 + ol) * N + n0 + wn + j * 16 + lr] = f2b(vv);
        else      ob[(long)(o0 + ol) * N + n0 + wn + j * 16 + lr] = vv;
      }
    }
  }
}

// ---------------- MFMA 3x3 conv (implicit GEMM), bf16 in/out ----------------
__global__ __launch_bounds__(256) void conv3_mfma(
    const u16* __restrict__ Wt,
    const u16* __restrict__ In, long iBS,
    u16* __restrict__ Out, long oBS, int O, int I,
    const float* __restrict__ bnp)
{
  __shared__ u16 As[9 * 64 * 34];
  __shared__ u16 Bs[4 * 66 * 34];
  __shared__ float albe[64][2];
  const int t = threadIdx.x;
  const int h0 = blockIdx.x * 2;
  const int o0 = blockIdx.y * 64;
  const int b  = blockIdx.z;
  const int w = t >> 6, l = t & 63, lq = l >> 4, lr = l & 15;
  const int wo = (w >> 1) * 32, wn = (w & 1) * 64;
  if (t < 64) {
    int o = o0 + t;
    float g = bnp[o], bt = bnp[O + o], mn = bnp[2 * O + o], vr = bnp[3 * O + o];
    float al = g * rsqrtf(vr + EPSV);
    albe[t][0] = al; albe[t][1] = bt - mn * al;
  }
  {
    int r = t >> 6, cs = (t >> 5) & 1, ch = t & 31;
    Bs[(r * 66 + (cs ? 65 : 0)) * 34 + ch] = 0;
  }
  const u16* inb = In + (long)b * iBS;
  const int bch = t >> 3, bcg = (t & 7) * 8;
  f32x4 acc[2][4] = {};
  for (int c8 = 0; c8 < (I >> 5); ++c8) {
    __syncthreads();
    {
      const u16* wsrc = Wt + (long)c8 * 9 * 256 * 32;
      #pragma unroll
      for (int j = 0; j < 9; ++j) {
        int e = j * 2048 + t * 8;
        int tap = e >> 11, o = (e >> 5) & 63, ch0 = e & 31;
        uint4 vv = *(const uint4*)(wsrc + ((long)tap * 256 + o0 + o) * 32 + ch0);
        *(uint4*)&As[(tap * 64 + o) * 34 + ch0] = vv;
      }
    }
    {
      const u16* cbase = inb + (long)(c8 * 32 + bch) * 4096;
      #pragma unroll
      for (int r = 0; r < 4; ++r) {
        int row = h0 - 1 + r;
        union { uint4 q; u16 h[8]; } tb;
        if (row >= 0 && row < 64) {
          tb.q = *(const uint4*)(cbase + row * 64 + bcg);
        } else {
          tb.q = make_uint4(0, 0, 0, 0);
        }
        #pragma unroll
        for (int j2 = 0; j2 < 8; ++j2)
          Bs[(r * 66 + bcg + 1 + j2) * 34 + bch] = tb.h[j2];
      }
    }
    __syncthreads();
    #pragma unroll
    for (int dy = 0; dy < 3; ++dy) {
      #pragma unroll
      for (int dx = 0; dx < 3; ++dx) {
        const int tap = dy * 3 + dx;
        bf16x8 af0 = *(const bf16x8*)&As[(tap * 64 + wo + lr) * 34 + lq * 8];
        bf16x8 af1 = *(const bf16x8*)&As[(tap * 64 + wo + 16 + lr) * 34 + lq * 8];
        #pragma unroll
        for (int j = 0; j < 4; ++j) {
          int nb = wn + j * 16;
          int rowS = (nb >> 6) + dy;
          int colS = (nb & 63) + dx;
          bf16x8 bv = *(const bf16x8*)&Bs[(rowS * 66 + colS + lr) * 34 + lq * 8];
          acc[0][j] = __builtin_amdgcn_mfma_f32_16x16x32_bf16(af0, bv, acc[0][j], 0, 0, 0);
          acc[1][j] = __builtin_amdgcn_mfma_f32_16x16x32_bf16(af1, bv, acc[1][j], 0, 0, 0);
        }
      }
    }
  }
  u16* ob = Out + (long)b * oBS;
  const int n0 = h0 * 64;
  #pragma unroll
  for (int i = 0; i < 2; ++i) {
    #pragma unroll
    for (int r = 0; r < 4; ++r) {
      int ol = wo + i * 16 + lq * 4 + r;
      float al = albe[ol][0], be = albe[ol][1];
      #pragma unroll
      for (int j = 0; j < 4; ++j) {
        float vv = silu_(acc[i][j][r] * al + be);
        ob[(long)(o0 + ol) * 4096 + n0 + wn + j * 16 + lr] = f2b(vv);
      }
    }
  }
}

// ---------------- max pools (bf16) ----------------

__global__ __launch_bounds__(256) void hmax5(const u16* __restrict__ src, long sBS,
                                             u16* __restrict__ dst, long dBS) {
  int t = blockIdx.x * 256 + threadIdx.x;
  int b = blockIdx.y;
  int n = t & 4095, c = t >> 12;
  int w = n & 63;
  const u16* p = src + (long)b * sBS + (long)c * 4096 + (n - w);
  float m = b2f(p[w]);
  if (w >= 1) m = fmaxf(m, b2f(p[w - 1]));
  if (w >= 2) m = fmaxf(m, b2f(p[w - 2]));
  if (w <= 62) m = fmaxf(m, b2f(p[w + 1]));
  if (w <= 61) m = fmaxf(m, b2f(p[w + 2]));
  dst[(long)b * dBS + t] = f2b_trunc(m);
}

__global__ __launch_bounds__(256) void vmax5(const u16* __restrict__ src, long sBS,
                                             u16* __restrict__ dst, long dBS) {
  int t = blockIdx.x * 256 + threadIdx.x;
  int b = blockIdx.y;
  int n = t & 4095, c = t >> 12;
  int h = n >> 6, w = n & 63;
  const u16* p = src + (long)b * sBS + (long)c * 4096 + w;
  float m = b2f(p[h * 64]);
  if (h >= 1) m = fmaxf(m, b2f(p[(h - 1) * 64]));
  if (h >= 2) m = fmaxf(m, b2f(p[(h - 2) * 64]));
  if (h <= 62) m = fmaxf(m, b2f(p[(h + 1) * 64]));
  if (h <= 61) m = fmaxf(m, b2f(p[(h + 2) * 64]));
  dst[(long)b * dBS + t] = f2b_trunc(m);
}

// ---------------- bf16 transpose: (B,64,4096) -> (B,4096,64) ----------------
__global__ __launch_bounds__(256) void transpose_hh(const u16* __restrict__ in, u16* __restrict__ out) {
  __shared__ u16 tile[32][34];
  int b = blockIdx.z;
  int c0 = blockIdx.x * 32, r0 = blockIdx.y * 32;
  int tx = threadIdx.x & 31, ty = threadIdx.x >> 5;
  const u16* ib = in + (long)b * 262144;
  u16* ob = out + (long)b * 262144;
  #pragma unroll
  for (int i = 0; i < 4; ++i) {
    int r = r0 + ty + i * 8;
    tile[ty + i * 8][tx] = ib[(long)r * 4096 + c0 + tx];
  }
  __syncthreads();
  #pragma unroll
  for (int i = 0; i < 4; ++i) {
    int c = c0 + ty + i * 8;
    ob[(long)c * 64 + r0 + tx] = tile[tx][ty + i * 8];
  }
}

// ---------------- PAM row-max via MFMA (qkT: [b][4096][64]) ----------------
__global__ __launch_bounds__(256) void pam_qk_max(const u16* __restrict__ qkT, float* __restrict__ pmax) {
  __shared__ u16 Qs[32 * 40];
  __shared__ u16 Ks[64 * 40];
  __shared__ float red[4][32][17];
  const int t = threadIdx.x;
  const int b = blockIdx.z, ms = blockIdx.y, n0 = blockIdx.x * 32;
  const int w = t >> 6, l = t & 63, lq = l >> 4, lr = l & 15;
  const int wn = w & 1, wc = w >> 1;
  if (t < 128) {
    int row = t >> 2, cq = (t & 3) * 8;
    *(uint4*)&Qs[row * 40 + cq] = *(const uint4*)(qkT + ((long)b * 4096 + n0 + row) * 64 + cq);
  }
  __syncthreads();
  bf16x8 qf = *(const bf16x8*)&Qs[(wn * 16 + lr) * 40 + lq * 8];
  float mx4[4] = {-1e30f, -1e30f, -1e30f, -1e30f};
  const int krow = t >> 2, kcq = (t & 3) * 8;
  for (int it = 0; it < 16; ++it) {
    int m0 = ms * 1024 + it * 64;
    __syncthreads();
    *(uint4*)&Ks[krow * 40 + kcq] = *(const uint4*)(qkT + ((long)b * 4096 + m0 + krow) * 64 + 32 + kcq);
    __syncthreads();
    #pragma unroll
    for (int s = 0; s < 2; ++s) {
      int msub = wc * 2 + s;
      bf16x8 kf = *(const bf16x8*)&Ks[(msub * 16 + lr) * 40 + lq * 8];
      f32x4 S = {};
      S = __builtin_amdgcn_mfma_f32_16x16x32_bf16(qf, kf, S, 0, 0, 0);
      #pragma unroll
      for (int r = 0; r < 4; ++r) mx4[r] = fmaxf(mx4[r], S[r]);
    }
  }
  #pragma unroll
  for (int r = 0; r < 4; ++r) red[w][wn * 16 + lq * 4 + r][lr] = mx4[r];
  __syncthreads();
  if (t < 32) {
    int wbase = t >> 4;
    float M = -1e30f;
    #pragma unroll
    for (int j = 0; j < 2; ++j)
      #pragma unroll
      for (int l2 = 0; l2 < 16; ++l2)
        M = fmaxf(M, red[wbase + 2 * j][t][l2]);
    pmax[((long)ms * 2 + b) * 4096 + n0 + t] = M;
  }
}

__global__ __launch_bounds__(256) void pam_merge(const float* __restrict__ pmax, float* __restrict__ rmx) {
  int i = blockIdx.x * 256 + threadIdx.x;
  int b = i >> 12, n = i & 4095;
  float m = pmax[(long)b * 4096 + n];
  #pragma unroll
  for (int ms = 1; ms < 4; ++ms) m = fmaxf(m, pmax[((long)ms * 2 + b) * 4096 + n]);
  rmx[i] = m;
}

// ---------------- PAM attention: m-split x2, un-normalized partials ----------------
__global__ __launch_bounds__(512) void pam_attn(const u16* __restrict__ qkT,
    const u16* __restrict__ vb, const float* __restrict__ rowmax,
    float* __restrict__ Obase, float* __restrict__ Sbase) {
  __shared__ u16 Qs[32 * 40];
  __shared__ u16 Ks[64 * 40];
  __shared__ u16 Vs[256 * 72];
  __shared__ u16 Ps[32 * 72];
  __shared__ float rmL[32];
  __shared__ float srow[32];
  const int t = threadIdx.x;
  const int mh = blockIdx.y;
  const int b = blockIdx.z;
  const int n0 = blockIdx.x * 32;
  const int w = t >> 6, l = t & 63, lq = l >> 4, lr = l & 15;
  const int nf = w & 1;
  const int mf = w >> 1;
  const int cw = w * 32;
  float* O = Obase + (long)mh * 2097152;
  float* S = Sbase + (long)mh * 8192;
  if (t < 128) {
    int row = t >> 2, cq = (t & 3) * 8;
    *(uint4*)&Qs[row * 40 + cq] = *(const uint4*)(qkT + ((long)b * 4096 + n0 + row) * 64 + cq);
  }
  if (t < 32) { rmL[t] = rowmax[(long)b * 4096 + n0 + t] * LOG2E; srow[t] = 0.f; }
  __syncthreads();
  bf16x8 qf = *(const bf16x8*)&Qs[(nf * 16 + lr) * 40 + lq * 8];
  float rm4[4];
  #pragma unroll
  for (int r = 0; r < 4; ++r) rm4[r] = rmL[nf * 16 + lq * 4 + r];
  float sp[4] = {0.f, 0.f, 0.f, 0.f};
  f32x4 acc[2][2] = {};
  const int krow = t >> 3, kc4 = (t & 7) * 4;
  const int vcc = t >> 1, vm = (t & 1) * 32;
  const u16* kbase = qkT + ((long)b * 4096 + krow) * 64 + 32 + kc4;
  const u16* vbase = vb + ((long)b * 256 + vcc) * 4096 + vm;
  const int mEnd = mh * 2048 + 2048;
  for (int m0 = mh * 2048; m0 < mEnd; m0 += 64) {
    __syncthreads();
    *(uint2*)&Ks[krow * 40 + kc4] = *(const uint2*)(kbase + (long)m0 * 64);
    {
      const u16* src = vbase + m0;
      u16* dst = &Vs[vcc * 72 + vm];
      #pragma unroll
      for (int i = 0; i < 4; ++i) *(uint4*)(dst + i * 8) = *(const uint4*)(src + i * 8);
    }
    __syncthreads();
    {
      bf16x8 kf = *(const bf16x8*)&Ks[(mf * 16 + lr) * 40 + lq * 8];
      f32x4 Sv = {};
      Sv = __builtin_amdgcn_mfma_f32_16x16x32_bf16(qf, kf, Sv, 0, 0, 0);
      #pragma unroll
      for (int r = 0; r < 4; ++r) {
        float p = exp2f(Sv[r] * LOG2E - rm4[r]);
        sp[r] += p;
        Ps[(nf * 16 + lq * 4 + r) * 72 + mf * 16 + lr] = f2b_trunc(p);
      }
    }
    __syncthreads();
    #pragma unroll
    for (int ks = 0; ks < 2; ++ks) {
      bf16x8 pf0 = *(const bf16x8*)&Ps[lr * 72 + ks * 32 + lq * 8];
      bf16x8 pf1 = *(const bf16x8*)&Ps[(16 + lr) * 72 + ks * 32 + lq * 8];
      #pragma unroll
      for (int cf = 0; cf < 2; ++cf) {
        bf16x8 vf = *(const bf16x8*)&Vs[(cw + cf * 16 + lr) * 72 + ks * 32 + lq * 8];
        acc[cf][0] = __builtin_amdgcn_mfma_f32_16x16x32_bf16(vf, pf0, acc[cf][0], 0, 0, 0);
        acc[cf][1] = __builtin_amdgcn_mfma_f32_16x16x32_bf16(vf, pf1, acc[cf][1], 0, 0, 0);
      }
    }
  }
  #pragma unroll
  for (int r = 0; r < 4; ++r) {
    float s = sp[r];
    s += __shfl_xor(s, 1); s += __shfl_xor(s, 2);
    s += __shfl_xor(s, 4); s += __shfl_xor(s, 8);
    if (lr == 0) atomicAdd(&srow[nf * 16 + lq * 4 + r], s);
  }
  __syncthreads();
  if (t < 32) S[(long)b * 4096 + n0 + t] = srow[t];
  float* ob = O + (long)b * 1048576 + n0;
  #pragma unroll
  for (int cf = 0; cf < 2; ++cf) {
    #pragma unroll
    for (int r = 0; r < 4; ++r) {
      int c = cw + cf * 16 + lq * 4 + r;
      ob[(long)c * 4096 + lr]      = acc[cf][0][r];
      ob[(long)c * 4096 + 16 + lr] = acc[cf][1][r];
    }
  }
}

// ---------------- CAM ----------------

__global__ __launch_bounds__(256) void fillz(float* __restrict__ p, int n) {
  int i = blockIdx.x * 256 + threadIdx.x;
  if (i < n) p[i] = 0.f;
}

__global__ __launch_bounds__(256) void cam_e_mfma(const u16* __restrict__ resb, float* __restrict__ e) {
  __shared__ u16 As[64 * 40];
  __shared__ u16 Bs[128 * 40];
  const int t = threadIdx.x;
  const int d0 = blockIdx.x * 128;
  const int c0 = blockIdx.y * 64;
  const int bz = blockIdx.z;
  const int b = bz >> 3, ks = bz & 7;
  const int w = t >> 6, l = t & 63, lq = l >> 4, lr = l & 15;
  const int wo = (w >> 1) * 32, wn = (w & 1) * 64;
  const u16* fb = resb + (long)b * 1048576;
  const int ao = t >> 2, akq = (t & 3) * 8;
  const int bo = t >> 1, bkq = (t & 1) * 16;
  f32x4 acc[2][4] = {};
  for (int kc = ks * 512; kc < ks * 512 + 512; kc += 32) {
    __syncthreads();
    *(uint4*)&As[ao * 40 + akq] = *(const uint4*)(fb + (long)(c0 + ao) * 4096 + kc + akq);
    #pragma unroll
    for (int i = 0; i < 2; ++i)
      *(uint4*)&Bs[bo * 40 + bkq + i * 8] = *(const uint4*)(fb + (long)(d0 + bo) * 4096 + kc + bkq + i * 8);
    __syncthreads();
    bf16x8 af[2], bfv[4];
    #pragma unroll
    for (int i = 0; i < 2; ++i) af[i] = *(const bf16x8*)&As[(wo + i * 16 + lr) * 40 + lq * 8];
    #pragma unroll
    for (int j = 0; j < 4; ++j) bfv[j] = *(const bf16x8*)&Bs[(wn + j * 16 + lr) * 40 + lq * 8];
    #pragma unroll
    for (int i = 0; i < 2; ++i)
      #pragma unroll
      for (int j = 0; j < 4; ++j)
        acc[i][j] = __builtin_amdgcn_mfma_f32_16x16x32_bf16(af[i], bfv[j], acc[i][j], 0, 0, 0);
  }
  #pragma unroll
  for (int i = 0; i < 2; ++i)
    #pragma unroll
    for (int r = 0; r < 4; ++r) {
      int ol = wo + i * 16 + lq * 4 + r;
      #pragma unroll
      for (int j = 0; j < 4; ++j)
        atomicAdd(&e[((long)b << 16) + (long)(c0 + ol) * 256 + d0 + wn + j * 16 + lr], acc[i][j][r]);
    }
}

__global__ __launch_bounds__(256) void cam_softmax(const float* __restrict__ e, u16* __restrict__ attn) {
  __shared__ float red[256];
  int c = blockIdx.x, b = blockIdx.y, t = threadIdx.x;
  const float* row = e + ((long)b << 16) + (long)c * 256;
  float v = row[t];
  red[t] = v; __syncthreads();
  for (int s = 128; s > 0; s >>= 1) { if (t < s) red[t] = fminf(red[t], red[t + s]); __syncthreads(); }
  float emin = red[0]; __syncthreads();
  float ex = exp2f(LOG2E * (emin - v));
  red[t] = ex; __syncthreads();
  for (int s = 128; s > 0; s >>= 1) { if (t < s) red[t] += red[t + s]; __syncthreads(); }
  float inv = 1.f / red[0];
  attn[((long)b << 16) + (long)c * 256 + t] = f2b(ex * inv);
}

// ---------------- final combine (fuses PAM partial merge) ----------------

__global__ __launch_bounds__(256) void combine(const float* __restrict__ res, const float* __restrict__ O,
    const float* __restrict__ S, const float* __restrict__ cam, const float* __restrict__ gp,
    void* __restrict__ outp, const float* __restrict__ flagp) {
  int idx = blockIdx.x * 256 + threadIdx.x;
  int b = idx >> 20, n = idx & 4095;
  float g1 = gp[0], g2 = gp[1];
  float sden = S[(long)b * 4096 + n] + S[8192 + (long)b * 4096 + n];
  float pamv = (O[idx] + O[2097152 + idx]) / sden;
  float v = 3.f * res[idx] + g1 * pamv + g2 * cam[idx];
  if (*flagp > 0.5f) ((float*)outp)[idx] = v;
  else               ((u16*)outp)[idx] = f2b(v);
}

// ---------------- launch ----------------

extern "C" void kernel_launch(void* const* d_in, const int* in_sizes, int n_in,
                              void* d_out, int out_size, void* d_ws, size_t ws_size,
                              hipStream_t stream)
{
  (void)out_size; (void)ws_size; (void)n_in;
  float* ws = (float*)d_ws;
  const long CN = 1048576;   // 256*4096

  float* A  = ws;            // r bf16 -> res fp32
  float* Bp = ws + 2 * CN;   // xf fp32 -> s3out/pooltmp/s5out/resb bf16
  float* Cp = ws + 4 * CN;   // CoordAtt smalls -> s1out bf16 -> vb bf16
  float* D  = ws + 6 * CN;   // cat(8CN u16) -> y12 -> {attn smalls} -> cam; O0/O1 at +4CN
  const long WFo = 14 * CN;

  u16*   rB   = (u16*)A;
  float* res  = A;
  float* xf   = Bp;
  u16*   BpU  = (u16*)Bp;
  float* yin  = Cp;
  float* ybn  = Cp + 65536;
  float* ah   = Cp + 67584;
  float* aw_  = Cp + 100352;
  u16*   CpU  = (u16*)Cp;
  u16*   catU = (u16*)D;
  u16*   y12U = (u16*)D;
  float* D2   = D + 2 * CN;
  u16*   qkbU = (u16*)D2;
  u16*   qkTU = (u16*)(D2 + 262144);
  float* pmax = D2 + 524288;
  float* rmx  = D2 + 557056;
  float* e    = D2 + 565248;
  u16*   attnc= (u16*)(D2 + 696320);
  float* S0   = D2 + 761856;
  float* cam  = D;
  float* O0   = D + 4 * CN;

  ConvArgs ca;
  long fOff[30], hOff[30];
  long hcur = 0;
  float* flagp = ws + WFo;
  {
    long cum = 0, fcur = WFo + 4;
    for (int i = 0; i < 30; ++i) {
      ca.src[i] = d_in[i];
      int h = (i == 8 || i == 10 || i == 14 || i == 16 || i == 20 ||
               i == 22 || i == 24 || i == 26) ? 1 : 0;
      ca.mode[i] = h;
      if (i == 0) { ca.dst[i] = 2 * CN; fOff[i] = 2 * CN; }
      else if (h) { ca.dst[i] = hcur; hOff[i] = hcur; hcur += in_sizes[i]; }
      else        { ca.dst[i] = fcur; fOff[i] = fcur; fcur += in_sizes[i]; }
      cum += in_sizes[i];
      ca.end[i] = (int)cum;
    }
  }
  long fTotal = WFo + 4;
  for (int i = 1; i < 30; ++i) if (!ca.mode[i]) fTotal = (fOff[i] + in_sizes[i] > fTotal) ? fOff[i] + in_sizes[i] : fTotal;
  u16* wsH = (u16*)(ws + fTotal);
  u16* wt3a = wsH + hcur;
  u16* wt3b = wsH + hcur + 589824;
  int total = ca.end[29];

  detect_k<<<dim3(1), dim3(128), 0, stream>>>((const u16*)d_in[0], flagp);
  convert_all<<<dim3((total + 255) / 256), dim3(256), 0, stream>>>(ca, ws, wsH, flagp, total);

  float* ca_w1 = ws + fOff[1];
  float* ca_b1 = ws + fOff[2];
  float* ca_bn = ws + fOff[3];
  float* ca_wh = ws + fOff[4];
  float* ca_bh = ws + fOff[5];
  float* ca_ww = ws + fOff[6];
  float* ca_bw = ws + fOff[7];
  u16*   s1_w  = wsH + hOff[8];   float* s1_bn = ws + fOff[9];
  u16*   s2_w  = wsH + hOff[10];  float* s2_bn = ws + fOff[11];
  float* s3_wf = ws + fOff[12];   float* s3_bn = ws + fOff[13];
  u16*   s4_w  = wsH + hOff[14];  float* s4_bn = ws + fOff[15];
  u16*   s5_w  = wsH + hOff[16];  float* s5_bn = ws + fOff[17];
  float* s6_wf = ws + fOff[18];   float* s6_bn = ws + fOff[19];
  u16*   s7_w  = wsH + hOff[20];  float* s7_bn = ws + fOff[21];
  u16*   qk_w  = wsH + hOff[22];  float* qk_b  = ws + fOff[23];
  u16*   pv_w  = wsH + hOff[26];  float* pv_b  = ws + fOff[27];
  float* gammas = ws + fOff[28];

  w3t<<<dim3(2304), dim3(256), 0, stream>>>(s3_wf, wt3a);
  w3t<<<dim3(2304), dim3(256), 0, stream>>>(s6_wf, wt3b);

  // ---- CoordAtt ----
  plane_means<<<dim3(512), dim3(256), 0, stream>>>(xf, yin);
  ca_conv1<<<dim3(2), dim3(128), 0, stream>>>(yin, ca_w1, ca_b1, ca_bn, ybn);
  ca_gate<<<dim3(256, 2), dim3(128), 0, stream>>>(ybn, ca_wh, ca_bh, ca_ww, ca_bw, ah, aw_);
  apply_ca<<<dim3(8192), dim3(256), 0, stream>>>(xf, ah, aw_, rB);

  // ---- SPPCSPC (all bf16 activations) ----
  mfma_cbs<1,1><<<dim3(32, 4, 2), dim3(256), 0, stream>>>(s1_w, 0, rB, CN, CpU, CN, 256, 256, 4096, s1_bn, nullptr);
  conv3_mfma<<<dim3(32, 4, 2), dim3(256), 0, stream>>>(wt3a, CpU, CN, BpU, CN, 256, 256, s3_bn);
  mfma_cbs<1,1><<<dim3(32, 4, 2), dim3(256), 0, stream>>>(s4_w, 0, BpU, CN, catU, 4 * CN, 256, 256, 4096, s4_bn, nullptr);

  hmax5<<<dim3(4096, 2), dim3(256), 0, stream>>>(catU, 4 * CN, BpU, CN);
  vmax5<<<dim3(4096, 2), dim3(256), 0, stream>>>(BpU, CN, catU + CN, 4 * CN);
  hmax5<<<dim3(4096, 2), dim3(256), 0, stream>>>(catU + CN, 4 * CN, BpU, CN);
  vmax5<<<dim3(4096, 2), dim3(256), 0, stream>>>(BpU, CN, catU + 2 * CN, 4 * CN);
  hmax5<<<dim3(4096, 2), dim3(256), 0, stream>>>(catU + 2 * CN, 4 * CN, BpU, CN);
  vmax5<<<dim3(4096, 2), dim3(256), 0, stream>>>(BpU, CN, catU + 3 * CN, 4 * CN);

  mfma_cbs<1,1><<<dim3(32, 4, 2), dim3(256), 0, stream>>>(s5_w, 0, catU, 4 * CN, BpU, CN, 256, 1024, 4096, s5_bn, nullptr);
  conv3_mfma<<<dim3(32, 4, 2), dim3(256), 0, stream>>>(wt3b, BpU, CN, y12U, 2 * CN, 256, 256, s6_bn);
  mfma_cbs<1,1><<<dim3(32, 4, 2), dim3(256), 0, stream>>>(s2_w, 0, rB, CN, y12U + CN, 2 * CN, 256, 256, 4096, s2_bn, nullptr);
  mfma_cbs<1,0><<<dim3(32, 4, 2), dim3(256), 0, stream>>>(s7_w, 0, y12U, 2 * CN, res, CN, 256, 512, 4096, s7_bn, nullptr);

  // ---- PAM ----
  cvtb<<<dim3(1024), dim3(256), 0, stream>>>(res, BpU, 262144);   // resb
  mfma_cbs<0,1><<<dim3(32, 1, 2), dim3(256), 0, stream>>>(qk_w, 0, BpU, CN, qkbU, 262144, 64, 256, 4096, nullptr, qk_b);
  mfma_cbs<0,1><<<dim3(32, 4, 2), dim3(256), 0, stream>>>(pv_w, 0, BpU, CN, CpU, CN, 256, 256, 4096, nullptr, pv_b);
  transpose_hh<<<dim3(128, 2, 2), dim3(256), 0, stream>>>(qkbU, qkTU);

  pam_qk_max<<<dim3(128, 4, 2), dim3(256), 0, stream>>>(qkTU, pmax);
  pam_merge<<<dim3(32), dim3(256), 0, stream>>>(pmax, rmx);
  pam_attn<<<dim3(128, 2, 2), dim3(512), 0, stream>>>(qkTU, CpU, rmx, O0, S0);

  // ---- CAM ----
  fillz<<<dim3(512), dim3(256), 0, stream>>>(e, 131072);
  cam_e_mfma<<<dim3(2, 4, 16), dim3(256), 0, stream>>>(BpU, e);
  cam_softmax<<<dim3(256, 2), dim3(256), 0, stream>>>(e, attnc);
  mfma_cbs<0,0><<<dim3(32, 4, 2), dim3(256), 0, stream>>>(attnc, 65536, BpU, CN, cam, CN, 256, 256, 4096, nullptr, nullptr);

  // ---- combine ----
  combine<<<dim3(8192), dim3(256), 0, stream>>>(res, O0, S0, cam, gammas, d_out, flagp);
}